// Round 15
// baseline (136.926 us; speedup 1.0000x reference)
//
#include <hip/hip_runtime.h>
#include <hip/hip_bf16.h>

#define NN   2000
#define NE   32000
#define EMBD 768
#define NH   4
#define HID  384
#define NEG  0.2f
#define DCAP 128

#define GM 2000
#define GN 768
#define GK 1536
#define K1 768          // mm1/mmX K

typedef __bf16 bf16x8 __attribute__((ext_vector_type(8)));
typedef float  f32x4  __attribute__((ext_vector_type(4)));

__device__ inline float wsum(float v){
#pragma unroll
  for (int o = 32; o > 0; o >>= 1) v += __shfl_xor(v, o, 64);
  return v;
}
__device__ inline float wmax(float v){
#pragma unroll
  for (int o = 32; o > 0; o >>= 1) v = fmaxf(v, __shfl_xor(v, o, 64));
  return v;
}

__device__ inline unsigned short f2bf(float f){
  unsigned u = __float_as_uint(f);
  unsigned r = (u + 0x7FFFu + ((u >> 16) & 1u)) >> 16;
  return (unsigned short)r;
}
__device__ inline float bf2f(unsigned short h){
  return __uint_as_float(((unsigned)h) << 16);
}

__device__ inline void gload16(const void* g, void* l){
  __builtin_amdgcn_global_load_lds((const __attribute__((address_space(1))) void*)g,
                                   (__attribute__((address_space(3))) void*)l, 16, 0, 0);
}
__device__ inline float dot4(float4 a, float4 b){
  return a.x*b.x + a.y*b.y + a.z*b.z + a.w*b.w;
}

// ---- prepA: collapses | W2->Bt | W1->W1t | x_emb split | CSR cnt+scan ------
// blocks [0,384): collapses; [384,672): Bt; [672,960): W1t; [960,1094): Xe;
// block 1094: count+scan (concurrent with prep -> single-block cost hidden)
__global__ __launch_bounds__(256) void k_prepA(
    const float* __restrict__ We1, const float* __restrict__ ae1,
    const float* __restrict__ W2,  const float* __restrict__ as2,
    const float* __restrict__ ad2, const float* __restrict__ We2,
    const float* __restrict__ ae2, const float* __restrict__ W1,
    const float* __restrict__ x_emb, const int* __restrict__ dst,
    float* __restrict__ we_a1, float* __restrict__ wa_s2,
    float* __restrict__ wa_d2, float* __restrict__ we_a2,
    unsigned short* __restrict__ Bh, unsigned short* __restrict__ Bl,
    unsigned short* __restrict__ W1th, unsigned short* __restrict__ W1tl,
    unsigned short* __restrict__ Xeh, unsigned short* __restrict__ Xel,
    int* __restrict__ offsets, int* __restrict__ cursor){
  __shared__ __align__(16) float smem[64*65];
  int blk = blockIdx.x, t = threadIdx.x;
  if (blk < 384){
    int wid = blk*4 + (t >> 6);
    int lane = t & 63;
    bool lo32 = lane < 32;
    if (wid < 384){
      int kg = wid >> 2, h = wid & 3;
      int k0 = kg*8;
      const float4* ap = (const float4*)(ae1 + h*384);
      float4 a0 = ap[lane];
      float4 a1 = lo32 ? ap[64+lane] : make_float4(0,0,0,0);
      float res[8];
#pragma unroll
      for (int r = 0; r < 8; ++r){
        const float4* wr = (const float4*)(We1 + (size_t)(k0+r)*1536 + h*384);
        float s = dot4(wr[lane], a0);
        if (lo32) s += dot4(wr[64+lane], a1);
        res[r] = s;
      }
#pragma unroll
      for (int r = 0; r < 8; ++r) res[r] = wsum(res[r]);
      if (lane == 0){
#pragma unroll
        for (int r = 0; r < 8; ++r) we_a1[(k0+r)*4+h] = res[r];
      }
    } else if (wid < 768){
      int t2 = wid - 384;
      int kg = t2 >> 2, h = t2 & 3;
      int k0 = kg*4;
      const float4* s4 = (const float4*)(as2 + h*768);
      const float4* d4 = (const float4*)(ad2 + h*768);
      float4 sa[3], da[3];
#pragma unroll
      for (int i = 0; i < 3; ++i){ sa[i] = s4[i*64+lane]; da[i] = d4[i*64+lane]; }
      float r1[4], r2[4];
#pragma unroll
      for (int r = 0; r < 4; ++r){
        const float4* wr = (const float4*)(W2 + (size_t)(k0+r)*3072 + h*768);
        float s1 = 0.f, s2v = 0.f;
#pragma unroll
        for (int i = 0; i < 3; ++i){
          float4 w = wr[i*64+lane];
          s1 += dot4(w, sa[i]); s2v += dot4(w, da[i]);
        }
        r1[r] = s1; r2[r] = s2v;
      }
#pragma unroll
      for (int r = 0; r < 4; ++r){ r1[r] = wsum(r1[r]); r2[r] = wsum(r2[r]); }
      if (lane == 0){
#pragma unroll
        for (int r = 0; r < 4; ++r){ wa_s2[(k0+r)*4+h] = r1[r]; wa_d2[(k0+r)*4+h] = r2[r]; }
      }
    } else {
      int t2 = wid - 768;
      int kg = t2 >> 2, h = t2 & 3;
      int k0 = kg*4;
      const float4* ap = (const float4*)(ae2 + h*768);
      float4 aa[3];
#pragma unroll
      for (int i = 0; i < 3; ++i) aa[i] = ap[i*64+lane];
      float res[4];
#pragma unroll
      for (int r = 0; r < 4; ++r){
        const float4* wr = (const float4*)(We2 + (size_t)(k0+r)*3072 + h*768);
        float s = 0.f;
#pragma unroll
        for (int i = 0; i < 3; ++i) s += dot4(wr[i*64+lane], aa[i]);
        res[r] = s;
      }
#pragma unroll
      for (int r = 0; r < 4; ++r) res[r] = wsum(res[r]);
      if (lane == 0){
#pragma unroll
        for (int r = 0; r < 4; ++r) we_a2[(k0+r)*4+h] = res[r];
      }
    }
  } else if (blk < 672){
    // Bt[c][h*384+k'] = W2[k'][h*768+c], bf16 hi/lo
    float (*tile)[65] = (float(*)[65])smem;
    int idx = blk - 384;
    int bk = (idx % 24) * 64;
    int bc = (idx / 24) * 64;
    int cc = t & 63, kk4 = t >> 6;
#pragma unroll
    for (int i = 0; i < 16; ++i){
      int kk = kk4*16 + i;
      int k = bk + kk;
      int h = k / 384, kp = k - h*384;
      tile[kk][cc] = W2[(size_t)kp*3072 + h*768 + bc + cc];
    }
    __syncthreads();
    int kk2 = t & 63, cc4 = t >> 6;
#pragma unroll
    for (int i = 0; i < 16; ++i){
      int c2 = cc4*16 + i;
      float v = tile[kk2][c2];
      unsigned short hi = f2bf(v);
      unsigned short lo = f2bf(v - bf2f(hi));
      size_t o = (size_t)(bc + c2)*GK + bk + kk2;
      Bh[o] = hi; Bl[o] = lo;
    }
  } else if (blk < 960){
    // W1t[j][k] = W1[k][j]
    float (*tile)[65] = (float(*)[65])smem;
    int idx = blk - 672;
    int bkk = (idx % 12) * 64;
    int bcc = (idx / 12) * 64;
    int cc = t & 63, kk4 = t >> 6;
#pragma unroll
    for (int i = 0; i < 16; ++i){
      int kk = kk4*16 + i;
      tile[kk][cc] = W1[(size_t)(bkk+kk)*1536 + bcc + cc];
    }
    __syncthreads();
    int kk2 = t & 63, cc4 = t >> 6;
#pragma unroll
    for (int i = 0; i < 16; ++i){
      int c2 = cc4*16 + i;
      float v = tile[kk2][c2];
      unsigned short hi = f2bf(v);
      unsigned short lo = f2bf(v - bf2f(hi));
      size_t o = (size_t)(bcc + c2)*768 + bkk + kk2;
      W1th[o] = hi; W1tl[o] = lo;
    }
  } else if (blk < 1094){
    int i = (blk - 960)*256 + t;          // < 178*768/4 = 34176
    if (i < 34176){
      float4 v = ((const float4*)x_emb)[i];
      unsigned short h0 = f2bf(v.x), h1 = f2bf(v.y), h2 = f2bf(v.z), h3 = f2bf(v.w);
      ushort4 hh; hh.x = h0; hh.y = h1; hh.z = h2; hh.w = h3;
      ushort4 ll; ll.x = f2bf(v.x - bf2f(h0)); ll.y = f2bf(v.y - bf2f(h1));
      ll.z = f2bf(v.z - bf2f(h2)); ll.w = f2bf(v.w - bf2f(h3));
      ((ushort4*)Xeh)[i] = hh;
      ((ushort4*)Xel)[i] = ll;
    }
  } else {
    // CSR count + scan (one block, hidden behind the 1094 prep blocks)
    int* cnt = (int*)smem;           // 2000 ints
    int* s2  = ((int*)smem) + 2048;  // 256 ints
    for (int i = t; i < NN; i += 256) cnt[i] = 0;
    __syncthreads();
    for (int e = t; e < NE; e += 256) atomicAdd(&cnt[dst[e]], 1);
    __syncthreads();
    int base8 = t*8;
    int loc = 0;
#pragma unroll
    for (int i = 0; i < 8; ++i){ int idx = base8+i; if (idx < NN) loc += cnt[idx]; }
    s2[t] = loc;
    __syncthreads();
    for (int off = 1; off < 256; off <<= 1){
      int v = (t >= off) ? s2[t-off] : 0;
      __syncthreads();
      s2[t] += v;
      __syncthreads();
    }
    int run = (t > 0) ? s2[t-1] : 0;
#pragma unroll
    for (int i = 0; i < 8; ++i){
      int idx = base8+i;
      if (idx < NN){ offsets[idx] = run; cursor[idx] = run; run += cnt[idx]; }
    }
    if (t == 255) offsets[NN] = s2[255];
  }
}

__global__ void k_fill(const int* __restrict__ dst, int* __restrict__ cursor,
                       int* __restrict__ csr){
  int e = blockIdx.x * blockDim.x + threadIdx.x;
  if (e < NE){
    int p = atomicAdd(&cursor[dst[e]], 1);
    csr[p] = e;
  }
}

// ---- k_mmX: xh1 = Xe @ W1t^T  (f32 out, bf16 3-product MFMA) ---------------
__global__ __launch_bounds__(256) void k_mmX(const unsigned short* __restrict__ Ah,
                                             const unsigned short* __restrict__ Al,
                                             const unsigned short* __restrict__ Bh,
                                             const unsigned short* __restrict__ Bl,
                                             float* __restrict__ xh1){
  __shared__ __align__(16) unsigned short lds[2][4][64][64];
  int b = blockIdx.x;
  int bm = b / 24, bn = b % 24;
  int wave = threadIdx.x >> 6, lane = threadIdx.x & 63;
  int wm = wave >> 1, wn = wave & 1;
  int rl = lane & 15, kq = lane >> 4;

  int rt   = lane >> 3;
  int kswz = ((lane & 7) ^ rt) * 8;
  const unsigned short* sbase;
  int rowbase;
  if (wave == 0){ sbase = Ah; rowbase = bm*64; }
  else if (wave == 1){ sbase = Al; rowbase = bm*64; }
  else if (wave == 2){ sbase = Bh; rowbase = bn*64; }
  else { sbase = Bl; rowbase = bn*64; }
  bool isA = wave < 2;

  f32x4 acc[2][2] = {};

#pragma unroll
  for (int i = 0; i < 8; ++i){
    int row = rowbase + i*8 + rt;
    if (isA) row = (row < 178) ? row : 177;
    gload16(sbase + (size_t)row*768 + kswz, &lds[0][wave][i*8][0]);
  }
  __syncthreads();

  for (int t = 0; t < 12; ++t){
    int cur = t & 1;
    if (t < 11){
      int k0 = (t+1)*64;
#pragma unroll
      for (int i = 0; i < 8; ++i){
        int row = rowbase + i*8 + rt;
        if (isA) row = (row < 178) ? row : 177;
        gload16(sbase + (size_t)row*768 + k0 + kswz, &lds[cur^1][wave][i*8][0]);
      }
    }
#pragma unroll
    for (int ks = 0; ks < 2; ++ks){
      bf16x8 ah[2], al2[2], bh2[2], bl2[2];
#pragma unroll
      for (int i = 0; i < 2; ++i){
        int r = wm*32 + i*16 + rl;
        int sl = (ks*4 + kq) ^ (r & 7);
        ah[i]  = *(const bf16x8*)&lds[cur][0][r][sl*8];
        al2[i] = *(const bf16x8*)&lds[cur][1][r][sl*8];
      }
#pragma unroll
      for (int j = 0; j < 2; ++j){
        int cdx = wn*32 + j*16 + rl;
        int sl = (ks*4 + kq) ^ (cdx & 7);
        bh2[j] = *(const bf16x8*)&lds[cur][2][cdx][sl*8];
        bl2[j] = *(const bf16x8*)&lds[cur][3][cdx][sl*8];
      }
#pragma unroll
      for (int i = 0; i < 2; ++i){
#pragma unroll
        for (int j = 0; j < 2; ++j){
          acc[i][j] = __builtin_amdgcn_mfma_f32_16x16x32_bf16(ah[i],  bh2[j], acc[i][j], 0, 0, 0);
          acc[i][j] = __builtin_amdgcn_mfma_f32_16x16x32_bf16(ah[i],  bl2[j], acc[i][j], 0, 0, 0);
          acc[i][j] = __builtin_amdgcn_mfma_f32_16x16x32_bf16(al2[i], bh2[j], acc[i][j], 0, 0, 0);
        }
      }
    }
    __syncthreads();
  }

#pragma unroll
  for (int i = 0; i < 2; ++i){
#pragma unroll
    for (int j = 0; j < 2; ++j){
      int col = bn*64 + wn*32 + j*16 + rl;
#pragma unroll
      for (int r = 0; r < 4; ++r){
        int row = bm*64 + wm*32 + i*16 + kq*4 + r;
        if (row < 178) xh1[(size_t)row*1536 + col] = acc[i][j][r];
      }
    }
  }
}

// ---- prepB: XHt bf16 build + xa dots + ew dots + pad zero ------------------
__global__ __launch_bounds__(256) void k_prepB(
    const float* __restrict__ xh1,
    const float* __restrict__ as1, const float* __restrict__ ad1,
    const float* __restrict__ e_emb,
    const float* __restrict__ we_a1, const float* __restrict__ we_a2,
    unsigned short* __restrict__ XHh, unsigned short* __restrict__ XHl,
    float* __restrict__ xa_s1, float* __restrict__ xa_d1,
    float* __restrict__ ew1, float* __restrict__ ew2){
  int blk = blockIdx.x, t = threadIdx.x;
  if (blk < 178){
    int tok = blk;
    for (int i = t; i < 1536; i += 256){
      float v = xh1[(size_t)tok*1536 + i];
      int h = i / 384, c = i - h*384;
      size_t off = (size_t)c*K1 + h*192 + tok;
      unsigned short hi = f2bf(v);
      XHh[off] = hi; XHl[off] = f2bf(v - bf2f(hi));
    }
  } else if (blk < 356){
    int r = blk - 178;
    int h = t >> 6, lane = t & 63;
    const float4* p0 = (const float4*)(xh1 + (size_t)r*1536 + h*384);
    const float4* s4 = (const float4*)(as1 + h*384);
    const float4* d4 = (const float4*)(ad1 + h*384);
    float s1, s2;
    {
      float4 u = p0[lane], sa = s4[lane], da = d4[lane];
      s1 = dot4(u, sa); s2 = dot4(u, da);
    }
    if (lane < 32){
      float4 u = p0[64+lane], sa = s4[64+lane], da = d4[64+lane];
      s1 += dot4(u, sa); s2 += dot4(u, da);
    }
    s1 = wsum(s1); s2 = wsum(s2);
    if (lane == 0){ xa_s1[r*4+h] = s1; xa_d1[r*4+h] = s2; }
  } else if (blk < 392){
    int id = (blk - 356)*4 + (t >> 6);
    int lane = t & 63;
    const float* wv = (id < 72) ? we_a1 : we_a2;
    float* o = (id < 72) ? ew1 : ew2;
    int id2 = (id < 72) ? id : (id - 72);
    int r = id2 >> 2, h = id2 & 3;
    const float* ar = e_emb + (size_t)r*EMBD;
    float acc = 0.f;
    for (int k = lane; k < EMBD; k += 64) acc += ar[k] * wv[k*4+h];
    acc = wsum(acc);
    if (lane == 0) o[r*4+h] = acc;
  } else {
    int i = (blk - 392)*256 + t;               // < 384*4*14 = 21504
    if (i < 21504){
      int c = i / 56, rem = i - c*56;
      int h = rem / 14, tp = 178 + rem - h*14;
      size_t off = (size_t)c*K1 + h*192 + tp;
      XHh[off] = 0; XHl[off] = 0;
    }
  }
}

// ---- layer-1 softmax + token-coefficient build -> Q bf16 hi/lo -------------
__global__ __launch_bounds__(256) void k_gat1sm(const int* __restrict__ offsets,
                      int* __restrict__ csr, const int* __restrict__ srcv,
                      const int* __restrict__ x, const int* __restrict__ ea,
                      const float* __restrict__ xa_s1, const float* __restrict__ xa_d1,
                      const float* __restrict__ ew1, float* __restrict__ spill,
                      unsigned short* __restrict__ Qh, unsigned short* __restrict__ Ql){
  __shared__ float wts[DCAP][5];
  __shared__ int   sE[DCAP];
  __shared__ int   sA[DCAP], sB[DCAP];
  __shared__ float coef[K1];
  int n = blockIdx.x, t = threadIdx.x;
  int w = t >> 6, lane = t & 63;
  int lo = offsets[n], hi = offsets[n+1];
  int deg = hi - lo;
  bool big = deg > DCAP;

  if (!big){
    if (deg <= 64){
      // single-wave shfl bitonic sort (no block barriers)
      if (w == 0){
        int v = (lane < deg) ? csr[lo+lane] : 0x7fffffff;
#pragma unroll
        for (int k = 2; k <= 64; k <<= 1){
#pragma unroll
          for (int j2 = k >> 1; j2 > 0; j2 >>= 1){
            int o = __shfl_xor(v, j2, 64);
            bool lower = (lane & j2) == 0;
            bool asc   = (lane & k) == 0;
            v = (lower == asc) ? min(v, o) : max(v, o);
          }
        }
        sE[lane] = v;
        if (lane < deg) csr[lo+lane] = v;
      }
    } else {
      int m = 1; while (m < deg) m <<= 1;
      for (int i = t; i < m; i += 256) sE[i] = (i < deg) ? csr[lo+i] : 0x7fffffff;
      __syncthreads();
      for (int k = 2; k <= m; k <<= 1){
        for (int j2 = k >> 1; j2 > 0; j2 >>= 1){
          for (int i = t; i < m; i += 256){
            int ixj = i ^ j2;
            if (ixj > i){
              int a = sE[i], b = sE[ixj];
              bool up = ((i & k) == 0);
              if ((a > b) == up){ sE[i] = b; sE[ixj] = a; }
            }
          }
          __syncthreads();
        }
      }
      for (int i = t; i < deg; i += 256) csr[lo+i] = sE[i];
    }
  } else {
    if (t == 0){
      for (int i = lo+1; i < hi; ++i){
        int v = csr[i], j = i-1;
        while (j >= lo && csr[j] > v){ csr[j+1] = csr[j]; --j; }
        csr[j+1] = v;
      }
    }
  }
  for (int i = t; i < K1; i += 256) coef[i] = 0.f;
  __syncthreads();

  int xn0 = x[2*n], xn1 = x[2*n+1];
  float ad_n = xa_d1[xn0*4+w] + xa_d1[xn1*4+w];
  float as_n = xa_s1[xn0*4+w] + xa_s1[xn1*4+w];
  float mx = -3.4e38f, sae = 0.f;
  float wlv;
  if (!big){
    for (int j = lane; j < deg; j += 64){
      int e = sE[j]; int s = srcv[e];
      int a = x[2*s], b = x[2*s+1];
      if (w == 0){ sA[j] = a; sB[j] = b; }
      float ae = ew1[ea[2*e]*4+w] + ew1[ea[2*e+1]*4+w];
      float al = (xa_s1[a*4+w] + xa_s1[b*4+w]) + ad_n + ae;
      al = (al > 0.f) ? al : NEG * al;
      wts[j][w] = al;
      sae += ae; mx = fmaxf(mx, al);
    }
    mx = wmax(mx); sae = wsum(sae);
    float all_ = as_n + ad_n + sae / fmaxf((float)deg, 1.f);
    all_ = (all_ > 0.f) ? all_ : NEG * all_;
    mx = fmaxf(mx, all_);
    float den = 0.f;
    for (int j = lane; j < deg; j += 64){
      float xx = expf(wts[j][w] - mx);
      wts[j][w] = xx; den += xx;
    }
    den = wsum(den);
    float exl = expf(all_ - mx);
    den += exl;
    float inv = 1.f / den;
    for (int j = lane; j < deg; j += 64) wts[j][w] *= inv;
    wlv = exl * inv;
  } else {
    for (int p = lo + lane; p < hi; p += 64){
      int e = csr[p]; int s = srcv[e];
      int a = x[2*s], b = x[2*s+1];
      float ae = ew1[ea[2*e]*4+w] + ew1[ea[2*e+1]*4+w];
      float al = (xa_s1[a*4+w] + xa_s1[b*4+w]) + ad_n + ae;
      al = (al > 0.f) ? al : NEG * al;
      spill[e*4 + w] = al;
      sae += ae; mx = fmaxf(mx, al);
    }
    mx = wmax(mx); sae = wsum(sae);
    float all_ = as_n + ad_n + sae / fmaxf((float)deg, 1.f);
    all_ = (all_ > 0.f) ? all_ : NEG * all_;
    mx = fmaxf(mx, all_);
    float den = 0.f;
    for (int p = lo + lane; p < hi; p += 64){
      int e = csr[p];
      float xx = expf(spill[e*4 + w] - mx);
      spill[e*4 + w] = xx; den += xx;
    }
    den = wsum(den);
    float exl = expf(all_ - mx);
    den += exl;
    float inv = 1.f / den;
    for (int p = lo + lane; p < hi; p += 64) spill[csr[p]*4 + w] *= inv;
    wlv = exl * inv;
  }
  __syncthreads();

  // deterministic coefficient scatter: lane 0 of warp w owns head-w slice
  if (lane == 0){
    float* cf = coef + w*192;
    if (!big){
      for (int j = 0; j < deg; ++j){
        float wj = wts[j][w];
        cf[sA[j]] += wj; cf[sB[j]] += wj;
      }
    } else {
      for (int p = lo; p < hi; ++p){
        int e = csr[p]; int s = srcv[e];
        float wj = spill[e*4 + w];
        cf[x[2*s]] += wj; cf[x[2*s+1]] += wj;
      }
    }
    cf[xn0] += wlv; cf[xn1] += wlv;
  }
  __syncthreads();

  for (int i = t; i < K1; i += 256){
    float v = coef[i];
    unsigned short hi16 = f2bf(v);
    Qh[(size_t)n*K1 + i] = hi16;
    Ql[(size_t)n*K1 + i] = f2bf(v - bf2f(hi16));
  }
}

// ---- mm1: hact = relu(0.25*(Q @ XHt^T) + b1), bf16 3-product MFMA ----------
__global__ __launch_bounds__(256) void k_mm1(const unsigned short* __restrict__ Qh,
                                             const unsigned short* __restrict__ Ql,
                                             const unsigned short* __restrict__ XHh,
                                             const unsigned short* __restrict__ XHl,
                                             const float* __restrict__ b1,
                                             float* __restrict__ hact){
  __shared__ __align__(16) unsigned short lds[2][4][64][64];
  int b = blockIdx.x;
  int xcd = b & 7, idx = b >> 3;            // idx in [0,24)
  int bm = xcd*4 + idx/6, bn = idx % 6;
  int wave = threadIdx.x >> 6, lane = threadIdx.x & 63;
  int wm = wave >> 1, wn = wave & 1;
  int rl = lane & 15, kq = lane >> 4;

  int rt   = lane >> 3;
  int kswz = ((lane & 7) ^ rt) * 8;
  const unsigned short* sbase;
  int rowbase;
  if (wave == 0){ sbase = Qh; rowbase = bm*64; }
  else if (wave == 1){ sbase = Ql; rowbase = bm*64; }
  else if (wave == 2){ sbase = XHh; rowbase = bn*64; }
  else { sbase = XHl; rowbase = bn*64; }
  bool isA = wave < 2;

  f32x4 acc[2][2] = {};

#pragma unroll
  for (int i = 0; i < 8; ++i){
    int row = rowbase + i*8 + rt;
    if (isA) row = (row < GM) ? row : (GM-1);
    gload16(sbase + (size_t)row*K1 + kswz, &lds[0][wave][i*8][0]);
  }
  __syncthreads();

  for (int t = 0; t < 12; ++t){
    int cur = t & 1;
    if (t < 11){
      int k0 = (t+1)*64;
#pragma unroll
      for (int i = 0; i < 8; ++i){
        int row = rowbase + i*8 + rt;
        if (isA) row = (row < GM) ? row : (GM-1);
        gload16(sbase + (size_t)row*K1 + k0 + kswz, &lds[cur^1][wave][i*8][0]);
      }
    }
#pragma unroll
    for (int ks = 0; ks < 2; ++ks){
      bf16x8 ah[2], al2[2], bh2[2], bl2[2];
#pragma unroll
      for (int i = 0; i < 2; ++i){
        int r = wm*32 + i*16 + rl;
        int sl = (ks*4 + kq) ^ (r & 7);
        ah[i]  = *(const bf16x8*)&lds[cur][0][r][sl*8];
        al2[i] = *(const bf16x8*)&lds[cur][1][r][sl*8];
      }
#pragma unroll
      for (int j = 0; j < 2; ++j){
        int cdx = wn*32 + j*16 + rl;
        int sl = (ks*4 + kq) ^ (cdx & 7);
        bh2[j] = *(const bf16x8*)&lds[cur][2][cdx][sl*8];
        bl2[j] = *(const bf16x8*)&lds[cur][3][cdx][sl*8];
      }
#pragma unroll
      for (int i = 0; i < 2; ++i){
#pragma unroll
        for (int j = 0; j < 2; ++j){
          acc[i][j] = __builtin_amdgcn_mfma_f32_16x16x32_bf16(ah[i],  bh2[j], acc[i][j], 0, 0, 0);
          acc[i][j] = __builtin_amdgcn_mfma_f32_16x16x32_bf16(ah[i],  bl2[j], acc[i][j], 0, 0, 0);
          acc[i][j] = __builtin_amdgcn_mfma_f32_16x16x32_bf16(al2[i], bh2[j], acc[i][j], 0, 0, 0);
        }
      }
    }
    __syncthreads();
  }

#pragma unroll
  for (int i = 0; i < 2; ++i){
#pragma unroll
    for (int j = 0; j < 2; ++j){
      int col = bn*64 + wn*32 + j*16 + rl;
      float bb = b1[col];
#pragma unroll
      for (int r = 0; r < 4; ++r){
        int row = bm*64 + wm*32 + i*16 + kq*4 + r;
        if (row < GM) hact[(size_t)row*HID + col] = fmaxf(0.25f*acc[i][j][r] + bb, 0.f);
      }
    }
  }
}

// ---- k_dots: asrc2/adst2 = hact row-dots with wa_s2/wa_d2 ------------------
__global__ __launch_bounds__(256) void k_dots(const float* __restrict__ hact,
                      const float* __restrict__ wa_s2, const float* __restrict__ wa_d2,
                      float* __restrict__ asrc2, float* __restrict__ adst2){
  int w = threadIdx.x >> 6, lane = threadIdx.x & 63;
  int n = blockIdx.x*4 + w;
  float pr[8] = {};
#pragma unroll
  for (int i = 0; i < 6; ++i){
    int c = i*64 + lane;
    float v = hact[(size_t)n*HID + c];
#pragma unroll
    for (int h = 0; h < 4; ++h){
      pr[h]   += v * wa_s2[c*4+h];
      pr[4+h] += v * wa_d2[c*4+h];
    }
  }
#pragma unroll
  for (int o = 32; o > 0; o >>= 1){
#pragma unroll
    for (int q = 0; q < 8; ++q) pr[q] += __shfl_xor(pr[q], o, 64);
  }
  if (lane == 0){
#pragma unroll
    for (int h = 0; h < 4; ++h){ asrc2[n*4+h] = pr[h]; adst2[n*4+h] = pr[4+h]; }
  }
}

// ---- layer-2 fused: on-the-fly alphas + softmax + pipelined agg -> G -------
__global__ __launch_bounds__(384) void k_gat2(const int* __restrict__ offsets,
                      const int* __restrict__ csr, const int* __restrict__ srcv,
                      const int* __restrict__ ea,
                      const float* __restrict__ asrc, const float* __restrict__ adst,
                      const float* __restrict__ ew2,
                      const float* __restrict__ hact, float* __restrict__ spill,
                      unsigned short* __restrict__ Gh, unsigned short* __restrict__ Gl){
  __shared__ float wts[DCAP][5];
  __shared__ int   ssrc[DCAP];
  __shared__ float wl[4];
  int n = blockIdx.x, t = threadIdx.x;
  int w = t >> 6, lane = t & 63;
  int lo = offsets[n], hi = offsets[n+1];
  int deg = hi - lo;
  bool big = deg > DCAP;
  if (w < 4){
    float ad_n = adst[n*NH + w];
    float as_n = asrc[n*NH + w];
    float mx = -3.4e38f, sae = 0.f;
    if (!big){
      for (int p = lo + lane; p < hi; p += 64){
        int e = csr[p]; int s = srcv[e];
        if (w == 0) ssrc[p - lo] = s;
        float ae = ew2[ea[2*e]*4+w] + ew2[ea[2*e+1]*4+w];
        float al = asrc[s*NH + w] + ad_n + ae;
        al = (al > 0.f) ? al : NEG * al;
        wts[p - lo][w] = al;
        sae += ae; mx = fmaxf(mx, al);
      }
      mx = wmax(mx); sae = wsum(sae);
      float all_ = as_n + ad_n + sae / fmaxf((float)deg, 1.f);
      all_ = (all_ > 0.f) ? all_ : NEG * all_;
      mx = fmaxf(mx, all_);
      float den = 0.f;
      for (int p = lo + lane; p < hi; p += 64){
        float xx = expf(wts[p - lo][w] - mx);
        wts[p - lo][w] = xx; den += xx;
      }
      den = wsum(den);
      float exl = expf(all_ - mx);
      den += exl;
      float inv = 1.f / den;
      for (int p = lo + lane; p < hi; p += 64) wts[p - lo][w] *= inv;
      if (lane == 0) wl[w] = exl * inv;
    } else {
      for (int p = lo + lane; p < hi; p += 64){
        int e = csr[p];
        float ae = ew2[ea[2*e]*4+w] + ew2[ea[2*e+1]*4+w];
        float al = asrc[srcv[e]*NH + w] + ad_n + ae;
        al = (al > 0.f) ? al : NEG * al;
        spill[e*4 + w] = al;
        sae += ae; mx = fmaxf(mx, al);
      }
      mx = wmax(mx); sae = wsum(sae);
      float all_ = as_n + ad_n + sae / fmaxf((float)deg, 1.f);
      all_ = (all_ > 0.f) ? all_ : NEG * all_;
      mx = fmaxf(mx, all_);
      float den = 0.f;
      for (int p = lo + lane; p < hi; p += 64){
        int e = csr[p];
        float xx = expf(spill[e*4 + w] - mx);
        spill[e*4 + w] = xx; den += xx;
      }
      den = wsum(den);
      float exl = expf(all_ - mx);
      den += exl;
      float inv = 1.f / den;
      for (int p = lo + lane; p < hi; p += 64) spill[csr[p]*4 + w] *= inv;
      if (lane == 0) wl[w] = exl * inv;
    }
  }
  __syncthreads();

  int c = t;
  float a0 = 0.f, a1 = 0.f, a2 = 0.f, a3 = 0.f;
  if (!big){
    float vnext = 0.f;
    if (deg > 0) vnext = hact[(size_t)ssrc[0]*HID + c];
    for (int j = 0; j < deg; ++j){
      float vc = vnext;
      if (j+1 < deg) vnext = hact[(size_t)ssrc[j+1]*HID + c];
      float w0=wts[j][0], w1=wts[j][1], w2=wts[j][2], w3=wts[j][3];
      a0 += w0*vc; a1 += w1*vc; a2 += w2*vc; a3 += w3*vc;
    }
  } else {
    for (int j = 0; j < deg; ++j){
      int e = csr[lo+j]; int s = srcv[e];
      float w0 = spill[e*4+0], w1 = spill[e*4+1], w2 = spill[e*4+2], w3 = spill[e*4+3];
      float vc = hact[(size_t)s*HID + c];
      a0 += w0*vc; a1 += w1*vc; a2 += w2*vc; a3 += w3*vc;
    }
  }
  {
    float vc = hact[(size_t)n*HID + c];
    a0 += wl[0]*vc; a1 += wl[1]*vc; a2 += wl[2]*vc; a3 += wl[3]*vc;
  }
  size_t base = (size_t)n*GK + c;
  float vv[4] = {a0, a1, a2, a3};
#pragma unroll
  for (int h = 0; h < 4; ++h){
    unsigned short hi16 = f2bf(vv[h]);
    unsigned short lo16 = f2bf(vv[h] - bf2f(hi16));
    Gh[base + h*384] = hi16;
    Gl[base + h*384] = lo16;
  }
}

// ---- layer-2 MFMA GEMM: LDS-staged, double-buffered, XOR-swizzled ----------
__global__ __launch_bounds__(256) void k_mm2(const unsigned short* __restrict__ Gh,
                                             const unsigned short* __restrict__ Gl,
                                             const unsigned short* __restrict__ Bh,
                                             const unsigned short* __restrict__ Bl,
                                             const float* __restrict__ b2,
                                             float* __restrict__ out){
  __shared__ __align__(16) unsigned short lds[2][4][64][64];
  int b = blockIdx.x;
  int xcd = b & 7, idx = b >> 3;
  int bm = xcd*4 + idx/12, bn = idx % 12;
  int wave = threadIdx.x >> 6, lane = threadIdx.x & 63;
  int wm = wave >> 1, wn = wave & 1;
  int rl = lane & 15, kq = lane >> 4;

  int rt   = lane >> 3;
  int kswz = ((lane & 7) ^ rt) * 8;
  const unsigned short* sbase;
  int rowbase;
  if (wave == 0){ sbase = Gh; rowbase = bm*64; }
  else if (wave == 1){ sbase = Gl; rowbase = bm*64; }
  else if (wave == 2){ sbase = Bh; rowbase = bn*64; }
  else { sbase = Bl; rowbase = bn*64; }
  bool isA = wave < 2;

  f32x4 acc[2][2] = {};

#pragma unroll
  for (int i = 0; i < 8; ++i){
    int row = rowbase + i*8 + rt;
    if (isA) row = (row < GM) ? row : (GM-1);
    gload16(sbase + (size_t)row*GK + kswz, &lds[0][wave][i*8][0]);
  }
  __syncthreads();

  for (int t = 0; t < 24; ++t){
    int cur = t & 1;
    if (t < 23){
      int k0 = (t+1)*64;
#pragma unroll
      for (int i = 0; i < 8; ++i){
        int row = rowbase + i*8 + rt;
        if (isA) row = (row < GM) ? row : (GM-1);
        gload16(sbase + (size_t)row*GK + k0 + kswz, &lds[cur^1][wave][i*8][0]);
      }
    }
#pragma unroll
    for (int ks = 0; ks < 2; ++ks){
      bf16x8 ah[2], al2[2], bh2[2], bl2[2];
#pragma unroll
      for (int i = 0; i < 2; ++i){
        int r = wm*32 + i*16 + rl;
        int sl = (ks*4 + kq) ^ (r & 7);
        ah[i]  = *(const bf16x8*)&lds[cur][0][r][sl*8];
        al2[i] = *(const bf16x8*)&lds[cur][1][r][sl*8];
      }
#pragma unroll
      for (int j = 0; j < 2; ++j){
        int cdx = wn*32 + j*16 + rl;
        int sl = (ks*4 + kq) ^ (cdx & 7);
        bh2[j] = *(const bf16x8*)&lds[cur][2][cdx][sl*8];
        bl2[j] = *(const bf16x8*)&lds[cur][3][cdx][sl*8];
      }
#pragma unroll
      for (int i = 0; i < 2; ++i){
#pragma unroll
        for (int j = 0; j < 2; ++j){
          acc[i][j] = __builtin_amdgcn_mfma_f32_16x16x32_bf16(ah[i],  bh2[j], acc[i][j], 0, 0, 0);
          acc[i][j] = __builtin_amdgcn_mfma_f32_16x16x32_bf16(ah[i],  bl2[j], acc[i][j], 0, 0, 0);
          acc[i][j] = __builtin_amdgcn_mfma_f32_16x16x32_bf16(al2[i], bh2[j], acc[i][j], 0, 0, 0);
        }
      }
    }
    __syncthreads();
  }

#pragma unroll
  for (int i = 0; i < 2; ++i){
#pragma unroll
    for (int j = 0; j < 2; ++j){
      int col = bn*64 + wn*32 + j*16 + rl;
      float bb = b2[col];
#pragma unroll
      for (int r = 0; r < 4; ++r){
        int row = bm*64 + wm*32 + i*16 + kq*4 + r;
        if (row < GM) out[(size_t)row*GN + col] = 0.25f*acc[i][j][r] + bb;
      }
    }
  }
}

// ---------------------------------------------------------------------------
extern "C" void kernel_launch(void* const* d_in, const int* in_sizes, int n_in,
                              void* d_out, int out_size, void* d_ws, size_t ws_size,
                              hipStream_t stream){
  const int*   x     = (const int*)d_in[0];
  const int*   ei    = (const int*)d_in[1];
  const int*   ea    = (const int*)d_in[2];
  const float* x_emb = (const float*)d_in[3];
  const float* e_emb = (const float*)d_in[4];
  const float* W1    = (const float*)d_in[5];
  const float* as1   = (const float*)d_in[6];
  const float* ad1   = (const float*)d_in[7];
  const float* We1   = (const float*)d_in[8];
  const float* ae1   = (const float*)d_in[9];
  const float* b1    = (const float*)d_in[10];
  const float* W2    = (const float*)d_in[11];
  const float* as2   = (const float*)d_in[12];
  const float* ad2   = (const float*)d_in[13];
  const float* We2   = (const float*)d_in[14];
  const float* ae2   = (const float*)d_in[15];
  const float* b2    = (const float*)d_in[16];
  const int* srcv = ei;
  const int* dstv = ei + NE;
  float* out = (float*)d_out;

  char* p = (char*)d_ws;
  auto take = [&](size_t n){ void* q = (void*)p; p += (n + 255) & ~(size_t)255; return q; };
  int*   cursor  = (int*)take(NN*4);
  int*   offsets = (int*)take((NN+1)*4);
  int*   csr     = (int*)take(NE*4);
  float* we_a1   = (float*)take(EMBD*NH*4);
  float* wa_s2   = (float*)take(HID*NH*4);
  float* wa_d2   = (float*)take(HID*NH*4);
  float* we_a2   = (float*)take(EMBD*NH*4);
  float* xa_s1   = (float*)take(178*NH*4);
  float* xa_d1   = (float*)take(178*NH*4);
  float* ew1     = (float*)take(18*NH*4);
  float* ew2     = (float*)take(18*NH*4);
  float* xh1     = (float*)take((size_t)178*1536*4);
  unsigned short* Xeh  = (unsigned short*)take((size_t)178*768*2);
  unsigned short* Xel  = (unsigned short*)take((size_t)178*768*2);
  unsigned short* W1th = (unsigned short*)take((size_t)1536*768*2);
  unsigned short* W1tl = (unsigned short*)take((size_t)1536*768*2);
  unsigned short* XHh  = (unsigned short*)take((size_t)HID*K1*2);
  unsigned short* XHl  = (unsigned short*)take((size_t)HID*K1*2);
  unsigned short* Qh   = (unsigned short*)take((size_t)NN*K1*2);
  unsigned short* Ql   = (unsigned short*)take((size_t)NN*K1*2);
  unsigned short* Bth  = (unsigned short*)take((size_t)GN*GK*2);
  unsigned short* Btl  = (unsigned short*)take((size_t)GN*GK*2);
  unsigned short* Gh   = (unsigned short*)take((size_t)GM*GK*2);
  unsigned short* Gl   = (unsigned short*)take((size_t)GM*GK*2);
  float* spill   = (float*)take((size_t)NE*NH*4);
  float* hact    = (float*)take((size_t)NN*HID*4);
  float* asrc2   = (float*)take(NN*NH*4);
  float* adst2   = (float*)take(NN*NH*4);

  // prep + CSR count/scan fused (cnt block hidden behind 1094 prep blocks)
  k_prepA<<<1095, 256, 0, stream>>>(We1, ae1, W2, as2, ad2, We2, ae2, W1,
                                    x_emb, dstv, we_a1, wa_s2, wa_d2, we_a2,
                                    Bth, Btl, W1th, W1tl, Xeh, Xel,
                                    offsets, cursor);
  k_fill<<<(NE+255)/256, 256, 0, stream>>>(dstv, cursor, csr);

  // xh1 via MFMA, then prepB
  k_mmX<<<72, 256, 0, stream>>>(Xeh, Xel, W1th, W1tl, xh1);
  k_prepB<<<476, 256, 0, stream>>>(xh1, as1, ad1, e_emb, we_a1, we_a2,
                                   XHh, XHl, xa_s1, xa_d1, ew1, ew2);

  // layer 1: softmax + token-coefficient build -> Q; hact via MFMA; dots
  k_gat1sm<<<NN, 256, 0, stream>>>(offsets, csr, srcv, x, ea, xa_s1, xa_d1,
                                   ew1, spill, Qh, Ql);
  k_mm1<<<192, 256, 0, stream>>>(Qh, Ql, XHh, XHl, b1, hact);
  k_dots<<<500, 256, 0, stream>>>(hact, wa_s2, wa_d2, asrc2, adst2);

  // layer 2 fused agg-first -> G (bf16 hi/lo)
  k_gat2<<<NN, 384, 0, stream>>>(offsets, csr, srcv, ea, asrc2, adst2, ew2,
                                 hact, spill, Gh, Gl);

  // out = 0.25*(G @ Bt^T) + b2 via LDS-staged bf16 3-product MFMA
  k_mm2<<<384, 256, 0, stream>>>(Gh, Gl, Bth, Btl, b2, out);
}

// Round 16
// 122.557 us; speedup vs baseline: 1.1172x; 1.1172x over previous
//
#include <hip/hip_runtime.h>
#include <hip/hip_bf16.h>

#define NN   2000
#define NE   32000
#define EMBD 768
#define NH   4
#define HID  384
#define NEG  0.2f
#define DCAP 128

#define GM 2000
#define GN 768
#define GK 1536
#define K1 768          // mm1/mmX K

typedef __bf16 bf16x8 __attribute__((ext_vector_type(8)));
typedef float  f32x4  __attribute__((ext_vector_type(4)));

__device__ inline float wsum(float v){
#pragma unroll
  for (int o = 32; o > 0; o >>= 1) v += __shfl_xor(v, o, 64);
  return v;
}
__device__ inline float wmax(float v){
#pragma unroll
  for (int o = 32; o > 0; o >>= 1) v = fmaxf(v, __shfl_xor(v, o, 64));
  return v;
}

__device__ inline unsigned short f2bf(float f){
  unsigned u = __float_as_uint(f);
  unsigned r = (u + 0x7FFFu + ((u >> 16) & 1u)) >> 16;
  return (unsigned short)r;
}
__device__ inline float bf2f(unsigned short h){
  return __uint_as_float(((unsigned)h) << 16);
}

__device__ inline void gload16(const void* g, void* l){
  __builtin_amdgcn_global_load_lds((const __attribute__((address_space(1))) void*)g,
                                   (__attribute__((address_space(3))) void*)l, 16, 0, 0);
}
__device__ inline float dot4(float4 a, float4 b){
  return a.x*b.x + a.y*b.y + a.z*b.z + a.w*b.w;
}

// ---- CSR: zero+count+scan fused (single block, 1024 threads) ---------------
__global__ __launch_bounds__(1024) void k_cnt(const int* __restrict__ dst,
                                              int* __restrict__ offsets,
                                              int* __restrict__ cursor){
  __shared__ int cnt[NN];
  __shared__ int s[1024];
  int t = threadIdx.x;
  for (int i = t; i < NN; i += 1024) cnt[i] = 0;
  __syncthreads();
  for (int e = t; e < NE; e += 1024) atomicAdd(&cnt[dst[e]], 1);
  __syncthreads();
  int a = (2*t   < NN) ? cnt[2*t  ] : 0;
  int b = (2*t+1 < NN) ? cnt[2*t+1] : 0;
  s[t] = a + b;
  __syncthreads();
  for (int off = 1; off < 1024; off <<= 1){
    int v = (t >= off) ? s[t-off] : 0;
    __syncthreads();
    s[t] += v;
    __syncthreads();
  }
  int base = (t > 0) ? s[t-1] : 0;
  if (2*t < NN){ offsets[2*t] = base; cursor[2*t] = base; }
  if (2*t+1 < NN){ offsets[2*t+1] = base + a; cursor[2*t+1] = base + a; }
  if (2*t == NN) offsets[NN] = base;
}

__global__ void k_fill(const int* __restrict__ dst, int* __restrict__ cursor,
                       int* __restrict__ csr){
  int e = blockIdx.x * blockDim.x + threadIdx.x;
  if (e < NE){
    int p = atomicAdd(&cursor[dst[e]], 1);
    csr[p] = e;
  }
}

// ---- prep1: row-batched collapses ------------------------------------------
__global__ __launch_bounds__(256) void k_prep1(
    const float* __restrict__ We1, const float* __restrict__ ae1,
    const float* __restrict__ W2,  const float* __restrict__ as2,
    const float* __restrict__ ad2, const float* __restrict__ We2,
    const float* __restrict__ ae2,
    float* __restrict__ we_a1, float* __restrict__ wa_s2,
    float* __restrict__ wa_d2, float* __restrict__ we_a2){
  int wid = blockIdx.x*4 + (threadIdx.x >> 6);
  int lane = threadIdx.x & 63;
  bool lo32 = lane < 32;
  if (wid < 384){
    int kg = wid >> 2, h = wid & 3;
    int k0 = kg*8;
    const float4* ap = (const float4*)(ae1 + h*384);
    float4 a0 = ap[lane];
    float4 a1 = lo32 ? ap[64+lane] : make_float4(0,0,0,0);
    float res[8];
#pragma unroll
    for (int r = 0; r < 8; ++r){
      const float4* wr = (const float4*)(We1 + (size_t)(k0+r)*1536 + h*384);
      float s = dot4(wr[lane], a0);
      if (lo32) s += dot4(wr[64+lane], a1);
      res[r] = s;
    }
#pragma unroll
    for (int r = 0; r < 8; ++r) res[r] = wsum(res[r]);
    if (lane == 0){
#pragma unroll
      for (int r = 0; r < 8; ++r) we_a1[(k0+r)*4+h] = res[r];
    }
  } else if (wid < 768){
    int t2 = wid - 384;
    int kg = t2 >> 2, h = t2 & 3;
    int k0 = kg*4;
    const float4* s4 = (const float4*)(as2 + h*768);
    const float4* d4 = (const float4*)(ad2 + h*768);
    float4 sa[3], da[3];
#pragma unroll
    for (int i = 0; i < 3; ++i){ sa[i] = s4[i*64+lane]; da[i] = d4[i*64+lane]; }
    float r1[4], r2[4];
#pragma unroll
    for (int r = 0; r < 4; ++r){
      const float4* wr = (const float4*)(W2 + (size_t)(k0+r)*3072 + h*768);
      float s1 = 0.f, s2 = 0.f;
#pragma unroll
      for (int i = 0; i < 3; ++i){
        float4 w = wr[i*64+lane];
        s1 += dot4(w, sa[i]); s2 += dot4(w, da[i]);
      }
      r1[r] = s1; r2[r] = s2;
    }
#pragma unroll
    for (int r = 0; r < 4; ++r){ r1[r] = wsum(r1[r]); r2[r] = wsum(r2[r]); }
    if (lane == 0){
#pragma unroll
      for (int r = 0; r < 4; ++r){ wa_s2[(k0+r)*4+h] = r1[r]; wa_d2[(k0+r)*4+h] = r2[r]; }
    }
  } else {
    int t2 = wid - 768;
    int kg = t2 >> 2, h = t2 & 3;
    int k0 = kg*4;
    const float4* ap = (const float4*)(ae2 + h*768);
    float4 aa[3];
#pragma unroll
    for (int i = 0; i < 3; ++i) aa[i] = ap[i*64+lane];
    float res[4];
#pragma unroll
    for (int r = 0; r < 4; ++r){
      const float4* wr = (const float4*)(We2 + (size_t)(k0+r)*3072 + h*768);
      float s = 0.f;
#pragma unroll
      for (int i = 0; i < 3; ++i) s += dot4(wr[i*64+lane], aa[i]);
      res[r] = s;
    }
#pragma unroll
    for (int r = 0; r < 4; ++r) res[r] = wsum(res[r]);
    if (lane == 0){
#pragma unroll
      for (int r = 0; r < 4; ++r) we_a2[(k0+r)*4+h] = res[r];
    }
  }
}

// ---- k_tr: W2->Bt hi/lo [0,288) | W1->W1t hi/lo [288,576) | x_emb split ----
__global__ __launch_bounds__(256) void k_tr(const float* __restrict__ W2,
                                            const float* __restrict__ W1,
                                            const float* __restrict__ x_emb,
                                            unsigned short* __restrict__ Bh,
                                            unsigned short* __restrict__ Bl,
                                            unsigned short* __restrict__ W1th,
                                            unsigned short* __restrict__ W1tl,
                                            unsigned short* __restrict__ Xeh,
                                            unsigned short* __restrict__ Xel){
  __shared__ float tile[64][65];
  int blk = blockIdx.x, t = threadIdx.x;
  if (blk < 288){
    int bk = (blk % 24) * 64;
    int bc = (blk / 24) * 64;
    int cc = t & 63, kk4 = t >> 6;
#pragma unroll
    for (int i = 0; i < 16; ++i){
      int kk = kk4*16 + i;
      int k = bk + kk;
      int h = k / 384, kp = k - h*384;
      tile[kk][cc] = W2[(size_t)kp*3072 + h*768 + bc + cc];
    }
    __syncthreads();
    int kk2 = t & 63, cc4 = t >> 6;
#pragma unroll
    for (int i = 0; i < 16; ++i){
      int c2 = cc4*16 + i;
      float v = tile[kk2][c2];
      unsigned short hi = f2bf(v);
      unsigned short lo = f2bf(v - bf2f(hi));
      size_t o = (size_t)(bc + c2)*GK + bk + kk2;
      Bh[o] = hi; Bl[o] = lo;
    }
  } else if (blk < 576){
    int idx = blk - 288;
    int bkk = (idx % 12) * 64;
    int bcc = (idx / 12) * 64;
    int cc = t & 63, kk4 = t >> 6;
#pragma unroll
    for (int i = 0; i < 16; ++i){
      int kk = kk4*16 + i;
      tile[kk][cc] = W1[(size_t)(bkk+kk)*1536 + bcc + cc];
    }
    __syncthreads();
    int kk2 = t & 63, cc4 = t >> 6;
#pragma unroll
    for (int i = 0; i < 16; ++i){
      int c2 = cc4*16 + i;
      float v = tile[kk2][c2];
      unsigned short hi = f2bf(v);
      unsigned short lo = f2bf(v - bf2f(hi));
      size_t o = (size_t)(bcc + c2)*768 + bkk + kk2;
      W1th[o] = hi; W1tl[o] = lo;
    }
  } else {
    int i = (blk - 576)*256 + t;          // < 178*768/4 = 34176
    if (i < 34176){
      float4 v = ((const float4*)x_emb)[i];
      unsigned short h0 = f2bf(v.x), h1 = f2bf(v.y), h2 = f2bf(v.z), h3 = f2bf(v.w);
      ushort4 hh; hh.x = h0; hh.y = h1; hh.z = h2; hh.w = h3;
      ushort4 ll; ll.x = f2bf(v.x - bf2f(h0)); ll.y = f2bf(v.y - bf2f(h1));
      ll.z = f2bf(v.z - bf2f(h2)); ll.w = f2bf(v.w - bf2f(h3));
      ((ushort4*)Xeh)[i] = hh;
      ((ushort4*)Xel)[i] = ll;
    }
  }
}

// ---- k_mmX: xh1 = Xe @ W1t^T  (f32 out, bf16 3-product MFMA) ---------------
__global__ __launch_bounds__(256) void k_mmX(const unsigned short* __restrict__ Ah,
                                             const unsigned short* __restrict__ Al,
                                             const unsigned short* __restrict__ Bh,
                                             const unsigned short* __restrict__ Bl,
                                             float* __restrict__ xh1){
  __shared__ __align__(16) unsigned short lds[2][4][64][64];
  int b = blockIdx.x;
  int bm = b / 24, bn = b % 24;
  int wave = threadIdx.x >> 6, lane = threadIdx.x & 63;
  int wm = wave >> 1, wn = wave & 1;
  int rl = lane & 15, kq = lane >> 4;

  int rt   = lane >> 3;
  int kswz = ((lane & 7) ^ rt) * 8;
  const unsigned short* sbase;
  int rowbase;
  if (wave == 0){ sbase = Ah; rowbase = bm*64; }
  else if (wave == 1){ sbase = Al; rowbase = bm*64; }
  else if (wave == 2){ sbase = Bh; rowbase = bn*64; }
  else { sbase = Bl; rowbase = bn*64; }
  bool isA = wave < 2;

  f32x4 acc[2][2] = {};

#pragma unroll
  for (int i = 0; i < 8; ++i){
    int row = rowbase + i*8 + rt;
    if (isA) row = (row < 178) ? row : 177;
    gload16(sbase + (size_t)row*768 + kswz, &lds[0][wave][i*8][0]);
  }
  __syncthreads();

  for (int t = 0; t < 12; ++t){
    int cur = t & 1;
    if (t < 11){
      int k0 = (t+1)*64;
#pragma unroll
      for (int i = 0; i < 8; ++i){
        int row = rowbase + i*8 + rt;
        if (isA) row = (row < 178) ? row : 177;
        gload16(sbase + (size_t)row*768 + k0 + kswz, &lds[cur^1][wave][i*8][0]);
      }
    }
#pragma unroll
    for (int ks = 0; ks < 2; ++ks){
      bf16x8 ah[2], al2[2], bh2[2], bl2[2];
#pragma unroll
      for (int i = 0; i < 2; ++i){
        int r = wm*32 + i*16 + rl;
        int sl = (ks*4 + kq) ^ (r & 7);
        ah[i]  = *(const bf16x8*)&lds[cur][0][r][sl*8];
        al2[i] = *(const bf16x8*)&lds[cur][1][r][sl*8];
      }
#pragma unroll
      for (int j = 0; j < 2; ++j){
        int cdx = wn*32 + j*16 + rl;
        int sl = (ks*4 + kq) ^ (cdx & 7);
        bh2[j] = *(const bf16x8*)&lds[cur][2][cdx][sl*8];
        bl2[j] = *(const bf16x8*)&lds[cur][3][cdx][sl*8];
      }
#pragma unroll
      for (int i = 0; i < 2; ++i){
#pragma unroll
        for (int j = 0; j < 2; ++j){
          acc[i][j] = __builtin_amdgcn_mfma_f32_16x16x32_bf16(ah[i],  bh2[j], acc[i][j], 0, 0, 0);
          acc[i][j] = __builtin_amdgcn_mfma_f32_16x16x32_bf16(ah[i],  bl2[j], acc[i][j], 0, 0, 0);
          acc[i][j] = __builtin_amdgcn_mfma_f32_16x16x32_bf16(al2[i], bh2[j], acc[i][j], 0, 0, 0);
        }
      }
    }
    __syncthreads();
  }

#pragma unroll
  for (int i = 0; i < 2; ++i){
#pragma unroll
    for (int j = 0; j < 2; ++j){
      int col = bn*64 + wn*32 + j*16 + rl;
#pragma unroll
      for (int r = 0; r < 4; ++r){
        int row = bm*64 + wm*32 + i*16 + kq*4 + r;
        if (row < 178) xh1[(size_t)row*1536 + col] = acc[i][j][r];
      }
    }
  }
}

// ---- prepB: XHt bf16 build + xa dots + ew dots + pad zero ------------------
__global__ __launch_bounds__(256) void k_prepB(
    const float* __restrict__ xh1,
    const float* __restrict__ as1, const float* __restrict__ ad1,
    const float* __restrict__ e_emb,
    const float* __restrict__ we_a1, const float* __restrict__ we_a2,
    unsigned short* __restrict__ XHh, unsigned short* __restrict__ XHl,
    float* __restrict__ xa_s1, float* __restrict__ xa_d1,
    float* __restrict__ ew1, float* __restrict__ ew2){
  int blk = blockIdx.x, t = threadIdx.x;
  if (blk < 178){
    int tok = blk;
    for (int i = t; i < 1536; i += 256){
      float v = xh1[(size_t)tok*1536 + i];
      int h = i / 384, c = i - h*384;
      size_t off = (size_t)c*K1 + h*192 + tok;
      unsigned short hi = f2bf(v);
      XHh[off] = hi; XHl[off] = f2bf(v - bf2f(hi));
    }
  } else if (blk < 356){
    int r = blk - 178;
    int h = t >> 6, lane = t & 63;
    const float4* p0 = (const float4*)(xh1 + (size_t)r*1536 + h*384);
    const float4* s4 = (const float4*)(as1 + h*384);
    const float4* d4 = (const float4*)(ad1 + h*384);
    float s1, s2;
    {
      float4 u = p0[lane], sa = s4[lane], da = d4[lane];
      s1 = dot4(u, sa); s2 = dot4(u, da);
    }
    if (lane < 32){
      float4 u = p0[64+lane], sa = s4[64+lane], da = d4[64+lane];
      s1 += dot4(u, sa); s2 += dot4(u, da);
    }
    s1 = wsum(s1); s2 = wsum(s2);
    if (lane == 0){ xa_s1[r*4+h] = s1; xa_d1[r*4+h] = s2; }
  } else if (blk < 392){
    int id = (blk - 356)*4 + (t >> 6);
    int lane = t & 63;
    const float* wv = (id < 72) ? we_a1 : we_a2;
    float* o = (id < 72) ? ew1 : ew2;
    int id2 = (id < 72) ? id : (id - 72);
    int r = id2 >> 2, h = id2 & 3;
    const float* ar = e_emb + (size_t)r*EMBD;
    float acc = 0.f;
    for (int k = lane; k < EMBD; k += 64) acc += ar[k] * wv[k*4+h];
    acc = wsum(acc);
    if (lane == 0) o[r*4+h] = acc;
  } else {
    int i = (blk - 392)*256 + t;               // < 384*4*14 = 21504
    if (i < 21504){
      int c = i / 56, rem = i - c*56;
      int h = rem / 14, tp = 178 + rem - h*14;
      size_t off = (size_t)c*K1 + h*192 + tp;
      XHh[off] = 0; XHl[off] = 0;
    }
  }
}

// ---- layer-1 softmax + token-coefficient build -> Q bf16 hi/lo -------------
__global__ __launch_bounds__(256) void k_gat1sm(const int* __restrict__ offsets,
                      int* __restrict__ csr, const int* __restrict__ srcv,
                      const int* __restrict__ x, const int* __restrict__ ea,
                      const float* __restrict__ xa_s1, const float* __restrict__ xa_d1,
                      const float* __restrict__ ew1, float* __restrict__ spill,
                      unsigned short* __restrict__ Qh, unsigned short* __restrict__ Ql){
  __shared__ float wts[DCAP][5];
  __shared__ int   sE[DCAP];
  __shared__ int   sA[DCAP], sB[DCAP];
  __shared__ float coef[K1];
  int n = blockIdx.x, t = threadIdx.x;
  int w = t >> 6, lane = t & 63;
  int lo = offsets[n], hi = offsets[n+1];
  int deg = hi - lo;
  bool big = deg > DCAP;

  if (!big){
    if (deg <= 64){
      // single-wave shfl bitonic sort (no block barriers)
      if (w == 0){
        int v = (lane < deg) ? csr[lo+lane] : 0x7fffffff;
#pragma unroll
        for (int k = 2; k <= 64; k <<= 1){
#pragma unroll
          for (int j2 = k >> 1; j2 > 0; j2 >>= 1){
            int o = __shfl_xor(v, j2, 64);
            bool lower = (lane & j2) == 0;
            bool asc   = (lane & k) == 0;
            v = (lower == asc) ? min(v, o) : max(v, o);
          }
        }
        sE[lane] = v;
        if (lane < deg) csr[lo+lane] = v;
      }
    } else {
      int m = 1; while (m < deg) m <<= 1;
      for (int i = t; i < m; i += 256) sE[i] = (i < deg) ? csr[lo+i] : 0x7fffffff;
      __syncthreads();
      for (int k = 2; k <= m; k <<= 1){
        for (int j2 = k >> 1; j2 > 0; j2 >>= 1){
          for (int i = t; i < m; i += 256){
            int ixj = i ^ j2;
            if (ixj > i){
              int a = sE[i], b = sE[ixj];
              bool up = ((i & k) == 0);
              if ((a > b) == up){ sE[i] = b; sE[ixj] = a; }
            }
          }
          __syncthreads();
        }
      }
      for (int i = t; i < deg; i += 256) csr[lo+i] = sE[i];
    }
  } else {
    if (t == 0){
      for (int i = lo+1; i < hi; ++i){
        int v = csr[i], j = i-1;
        while (j >= lo && csr[j] > v){ csr[j+1] = csr[j]; --j; }
        csr[j+1] = v;
      }
    }
  }
  for (int i = t; i < K1; i += 256) coef[i] = 0.f;
  __syncthreads();

  int xn0 = x[2*n], xn1 = x[2*n+1];
  float ad_n = xa_d1[xn0*4+w] + xa_d1[xn1*4+w];
  float as_n = xa_s1[xn0*4+w] + xa_s1[xn1*4+w];
  float mx = -3.4e38f, sae = 0.f;
  float wlv;
  if (!big){
    for (int j = lane; j < deg; j += 64){
      int e = sE[j]; int s = srcv[e];
      int a = x[2*s], b = x[2*s+1];
      if (w == 0){ sA[j] = a; sB[j] = b; }
      float ae = ew1[ea[2*e]*4+w] + ew1[ea[2*e+1]*4+w];
      float al = (xa_s1[a*4+w] + xa_s1[b*4+w]) + ad_n + ae;
      al = (al > 0.f) ? al : NEG * al;
      wts[j][w] = al;
      sae += ae; mx = fmaxf(mx, al);
    }
    mx = wmax(mx); sae = wsum(sae);
    float all_ = as_n + ad_n + sae / fmaxf((float)deg, 1.f);
    all_ = (all_ > 0.f) ? all_ : NEG * all_;
    mx = fmaxf(mx, all_);
    float den = 0.f;
    for (int j = lane; j < deg; j += 64){
      float xx = expf(wts[j][w] - mx);
      wts[j][w] = xx; den += xx;
    }
    den = wsum(den);
    float exl = expf(all_ - mx);
    den += exl;
    float inv = 1.f / den;
    for (int j = lane; j < deg; j += 64) wts[j][w] *= inv;
    wlv = exl * inv;
  } else {
    for (int p = lo + lane; p < hi; p += 64){
      int e = csr[p]; int s = srcv[e];
      int a = x[2*s], b = x[2*s+1];
      float ae = ew1[ea[2*e]*4+w] + ew1[ea[2*e+1]*4+w];
      float al = (xa_s1[a*4+w] + xa_s1[b*4+w]) + ad_n + ae;
      al = (al > 0.f) ? al : NEG * al;
      spill[e*4 + w] = al;
      sae += ae; mx = fmaxf(mx, al);
    }
    mx = wmax(mx); sae = wsum(sae);
    float all_ = as_n + ad_n + sae / fmaxf((float)deg, 1.f);
    all_ = (all_ > 0.f) ? all_ : NEG * all_;
    mx = fmaxf(mx, all_);
    float den = 0.f;
    for (int p = lo + lane; p < hi; p += 64){
      int e = csr[p];
      float xx = expf(spill[e*4 + w] - mx);
      spill[e*4 + w] = xx; den += xx;
    }
    den = wsum(den);
    float exl = expf(all_ - mx);
    den += exl;
    float inv = 1.f / den;
    for (int p = lo + lane; p < hi; p += 64) spill[csr[p]*4 + w] *= inv;
    wlv = exl * inv;
  }
  __syncthreads();

  // deterministic coefficient scatter: lane 0 of warp w owns head-w slice
  if (lane == 0){
    float* cf = coef + w*192;
    if (!big){
      for (int j = 0; j < deg; ++j){
        float wj = wts[j][w];
        cf[sA[j]] += wj; cf[sB[j]] += wj;
      }
    } else {
      for (int p = lo; p < hi; ++p){
        int e = csr[p]; int s = srcv[e];
        float wj = spill[e*4 + w];
        cf[x[2*s]] += wj; cf[x[2*s+1]] += wj;
      }
    }
    cf[xn0] += wlv; cf[xn1] += wlv;
  }
  __syncthreads();

  for (int i = t; i < K1; i += 256){
    float v = coef[i];
    unsigned short hi16 = f2bf(v);
    Qh[(size_t)n*K1 + i] = hi16;
    Ql[(size_t)n*K1 + i] = f2bf(v - bf2f(hi16));
  }
}

// ---- mm1: hact = relu(0.25*(Q @ XHt^T) + b1), bf16 3-product MFMA ----------
__global__ __launch_bounds__(256) void k_mm1(const unsigned short* __restrict__ Qh,
                                             const unsigned short* __restrict__ Ql,
                                             const unsigned short* __restrict__ XHh,
                                             const unsigned short* __restrict__ XHl,
                                             const float* __restrict__ b1,
                                             float* __restrict__ hact){
  __shared__ __align__(16) unsigned short lds[2][4][64][64];
  int b = blockIdx.x;
  int xcd = b & 7, idx = b >> 3;            // idx in [0,24)
  int bm = xcd*4 + idx/6, bn = idx % 6;
  int wave = threadIdx.x >> 6, lane = threadIdx.x & 63;
  int wm = wave >> 1, wn = wave & 1;
  int rl = lane & 15, kq = lane >> 4;

  int rt   = lane >> 3;
  int kswz = ((lane & 7) ^ rt) * 8;
  const unsigned short* sbase;
  int rowbase;
  if (wave == 0){ sbase = Qh; rowbase = bm*64; }
  else if (wave == 1){ sbase = Ql; rowbase = bm*64; }
  else if (wave == 2){ sbase = XHh; rowbase = bn*64; }
  else { sbase = XHl; rowbase = bn*64; }
  bool isA = wave < 2;

  f32x4 acc[2][2] = {};

#pragma unroll
  for (int i = 0; i < 8; ++i){
    int row = rowbase + i*8 + rt;
    if (isA) row = (row < GM) ? row : (GM-1);
    gload16(sbase + (size_t)row*K1 + kswz, &lds[0][wave][i*8][0]);
  }
  __syncthreads();

  for (int t = 0; t < 12; ++t){
    int cur = t & 1;
    if (t < 11){
      int k0 = (t+1)*64;
#pragma unroll
      for (int i = 0; i < 8; ++i){
        int row = rowbase + i*8 + rt;
        if (isA) row = (row < GM) ? row : (GM-1);
        gload16(sbase + (size_t)row*K1 + k0 + kswz, &lds[cur^1][wave][i*8][0]);
      }
    }
#pragma unroll
    for (int ks = 0; ks < 2; ++ks){
      bf16x8 ah[2], al2[2], bh2[2], bl2[2];
#pragma unroll
      for (int i = 0; i < 2; ++i){
        int r = wm*32 + i*16 + rl;
        int sl = (ks*4 + kq) ^ (r & 7);
        ah[i]  = *(const bf16x8*)&lds[cur][0][r][sl*8];
        al2[i] = *(const bf16x8*)&lds[cur][1][r][sl*8];
      }
#pragma unroll
      for (int j = 0; j < 2; ++j){
        int cdx = wn*32 + j*16 + rl;
        int sl = (ks*4 + kq) ^ (cdx & 7);
        bh2[j] = *(const bf16x8*)&lds[cur][2][cdx][sl*8];
        bl2[j] = *(const bf16x8*)&lds[cur][3][cdx][sl*8];
      }
#pragma unroll
      for (int i = 0; i < 2; ++i){
#pragma unroll
        for (int j = 0; j < 2; ++j){
          acc[i][j] = __builtin_amdgcn_mfma_f32_16x16x32_bf16(ah[i],  bh2[j], acc[i][j], 0, 0, 0);
          acc[i][j] = __builtin_amdgcn_mfma_f32_16x16x32_bf16(ah[i],  bl2[j], acc[i][j], 0, 0, 0);
          acc[i][j] = __builtin_amdgcn_mfma_f32_16x16x32_bf16(al2[i], bh2[j], acc[i][j], 0, 0, 0);
        }
      }
    }
    __syncthreads();
  }

#pragma unroll
  for (int i = 0; i < 2; ++i){
#pragma unroll
    for (int j = 0; j < 2; ++j){
      int col = bn*64 + wn*32 + j*16 + rl;
      float bb = b1[col];
#pragma unroll
      for (int r = 0; r < 4; ++r){
        int row = bm*64 + wm*32 + i*16 + kq*4 + r;
        if (row < GM) hact[(size_t)row*HID + col] = fmaxf(0.25f*acc[i][j][r] + bb, 0.f);
      }
    }
  }
}

// ---- k_dots: asrc2/adst2 = hact row-dots with wa_s2/wa_d2 ------------------
__global__ __launch_bounds__(256) void k_dots(const float* __restrict__ hact,
                      const float* __restrict__ wa_s2, const float* __restrict__ wa_d2,
                      float* __restrict__ asrc2, float* __restrict__ adst2){
  int w = threadIdx.x >> 6, lane = threadIdx.x & 63;
  int n = blockIdx.x*4 + w;
  float pr[8] = {};
#pragma unroll
  for (int i = 0; i < 6; ++i){
    int c = i*64 + lane;
    float v = hact[(size_t)n*HID + c];
#pragma unroll
    for (int h = 0; h < 4; ++h){
      pr[h]   += v * wa_s2[c*4+h];
      pr[4+h] += v * wa_d2[c*4+h];
    }
  }
#pragma unroll
  for (int o = 32; o > 0; o >>= 1){
#pragma unroll
    for (int q = 0; q < 8; ++q) pr[q] += __shfl_xor(pr[q], o, 64);
  }
  if (lane == 0){
#pragma unroll
    for (int h = 0; h < 4; ++h){ asrc2[n*4+h] = pr[h]; adst2[n*4+h] = pr[4+h]; }
  }
}

// ---- layer-2 fused: on-the-fly alphas + softmax + pipelined agg -> G -------
__global__ __launch_bounds__(384) void k_gat2(const int* __restrict__ offsets,
                      const int* __restrict__ csr, const int* __restrict__ srcv,
                      const int* __restrict__ ea,
                      const float* __restrict__ asrc, const float* __restrict__ adst,
                      const float* __restrict__ ew2,
                      const float* __restrict__ hact, float* __restrict__ spill,
                      unsigned short* __restrict__ Gh, unsigned short* __restrict__ Gl){
  __shared__ float wts[DCAP][5];
  __shared__ int   ssrc[DCAP];
  __shared__ float wl[4];
  int n = blockIdx.x, t = threadIdx.x;
  int w = t >> 6, lane = t & 63;
  int lo = offsets[n], hi = offsets[n+1];
  int deg = hi - lo;
  bool big = deg > DCAP;
  if (w < 4){
    float ad_n = adst[n*NH + w];
    float as_n = asrc[n*NH + w];
    float mx = -3.4e38f, sae = 0.f;
    if (!big){
      for (int p = lo + lane; p < hi; p += 64){
        int e = csr[p]; int s = srcv[e];
        if (w == 0) ssrc[p - lo] = s;
        float ae = ew2[ea[2*e]*4+w] + ew2[ea[2*e+1]*4+w];
        float al = asrc[s*NH + w] + ad_n + ae;
        al = (al > 0.f) ? al : NEG * al;
        wts[p - lo][w] = al;
        sae += ae; mx = fmaxf(mx, al);
      }
      mx = wmax(mx); sae = wsum(sae);
      float all_ = as_n + ad_n + sae / fmaxf((float)deg, 1.f);
      all_ = (all_ > 0.f) ? all_ : NEG * all_;
      mx = fmaxf(mx, all_);
      float den = 0.f;
      for (int p = lo + lane; p < hi; p += 64){
        float xx = expf(wts[p - lo][w] - mx);
        wts[p - lo][w] = xx; den += xx;
      }
      den = wsum(den);
      float exl = expf(all_ - mx);
      den += exl;
      float inv = 1.f / den;
      for (int p = lo + lane; p < hi; p += 64) wts[p - lo][w] *= inv;
      if (lane == 0) wl[w] = exl * inv;
    } else {
      for (int p = lo + lane; p < hi; p += 64){
        int e = csr[p];
        float ae = ew2[ea[2*e]*4+w] + ew2[ea[2*e+1]*4+w];
        float al = asrc[srcv[e]*NH + w] + ad_n + ae;
        al = (al > 0.f) ? al : NEG * al;
        spill[e*4 + w] = al;
        sae += ae; mx = fmaxf(mx, al);
      }
      mx = wmax(mx); sae = wsum(sae);
      float all_ = as_n + ad_n + sae / fmaxf((float)deg, 1.f);
      all_ = (all_ > 0.f) ? all_ : NEG * all_;
      mx = fmaxf(mx, all_);
      float den = 0.f;
      for (int p = lo + lane; p < hi; p += 64){
        int e = csr[p];
        float xx = expf(spill[e*4 + w] - mx);
        spill[e*4 + w] = xx; den += xx;
      }
      den = wsum(den);
      float exl = expf(all_ - mx);
      den += exl;
      float inv = 1.f / den;
      for (int p = lo + lane; p < hi; p += 64) spill[csr[p]*4 + w] *= inv;
      if (lane == 0) wl[w] = exl * inv;
    }
  }
  __syncthreads();

  int c = t;
  float a0 = 0.f, a1 = 0.f, a2 = 0.f, a3 = 0.f;
  if (!big){
    float vnext = 0.f;
    if (deg > 0) vnext = hact[(size_t)ssrc[0]*HID + c];
    for (int j = 0; j < deg; ++j){
      float vc = vnext;
      if (j+1 < deg) vnext = hact[(size_t)ssrc[j+1]*HID + c];
      float w0=wts[j][0], w1=wts[j][1], w2=wts[j][2], w3=wts[j][3];
      a0 += w0*vc; a1 += w1*vc; a2 += w2*vc; a3 += w3*vc;
    }
  } else {
    for (int j = 0; j < deg; ++j){
      int e = csr[lo+j]; int s = srcv[e];
      float w0 = spill[e*4+0], w1 = spill[e*4+1], w2 = spill[e*4+2], w3 = spill[e*4+3];
      float vc = hact[(size_t)s*HID + c];
      a0 += w0*vc; a1 += w1*vc; a2 += w2*vc; a3 += w3*vc;
    }
  }
  {
    float vc = hact[(size_t)n*HID + c];
    a0 += wl[0]*vc; a1 += wl[1]*vc; a2 += wl[2]*vc; a3 += wl[3]*vc;
  }
  size_t base = (size_t)n*GK + c;
  float vv[4] = {a0, a1, a2, a3};
#pragma unroll
  for (int h = 0; h < 4; ++h){
    unsigned short hi16 = f2bf(vv[h]);
    unsigned short lo16 = f2bf(vv[h] - bf2f(hi16));
    Gh[base + h*384] = hi16;
    Gl[base + h*384] = lo16;
  }
}

// ---- layer-2 MFMA GEMM: LDS-staged, double-buffered, XOR-swizzled ----------
__global__ __launch_bounds__(256) void k_mm2(const unsigned short* __restrict__ Gh,
                                             const unsigned short* __restrict__ Gl,
                                             const unsigned short* __restrict__ Bh,
                                             const unsigned short* __restrict__ Bl,
                                             const float* __restrict__ b2,
                                             float* __restrict__ out){
  __shared__ __align__(16) unsigned short lds[2][4][64][64];
  int b = blockIdx.x;
  int xcd = b & 7, idx = b >> 3;
  int bm = xcd*4 + idx/12, bn = idx % 12;
  int wave = threadIdx.x >> 6, lane = threadIdx.x & 63;
  int wm = wave >> 1, wn = wave & 1;
  int rl = lane & 15, kq = lane >> 4;

  int rt   = lane >> 3;
  int kswz = ((lane & 7) ^ rt) * 8;
  const unsigned short* sbase;
  int rowbase;
  if (wave == 0){ sbase = Gh; rowbase = bm*64; }
  else if (wave == 1){ sbase = Gl; rowbase = bm*64; }
  else if (wave == 2){ sbase = Bh; rowbase = bn*64; }
  else { sbase = Bl; rowbase = bn*64; }
  bool isA = wave < 2;

  f32x4 acc[2][2] = {};

#pragma unroll
  for (int i = 0; i < 8; ++i){
    int row = rowbase + i*8 + rt;
    if (isA) row = (row < GM) ? row : (GM-1);
    gload16(sbase + (size_t)row*GK + kswz, &lds[0][wave][i*8][0]);
  }
  __syncthreads();

  for (int t = 0; t < 24; ++t){
    int cur = t & 1;
    if (t < 23){
      int k0 = (t+1)*64;
#pragma unroll
      for (int i = 0; i < 8; ++i){
        int row = rowbase + i*8 + rt;
        if (isA) row = (row < GM) ? row : (GM-1);
        gload16(sbase + (size_t)row*GK + k0 + kswz, &lds[cur^1][wave][i*8][0]);
      }
    }
#pragma unroll
    for (int ks = 0; ks < 2; ++ks){
      bf16x8 ah[2], al2[2], bh2[2], bl2[2];
#pragma unroll
      for (int i = 0; i < 2; ++i){
        int r = wm*32 + i*16 + rl;
        int sl = (ks*4 + kq) ^ (r & 7);
        ah[i]  = *(const bf16x8*)&lds[cur][0][r][sl*8];
        al2[i] = *(const bf16x8*)&lds[cur][1][r][sl*8];
      }
#pragma unroll
      for (int j = 0; j < 2; ++j){
        int cdx = wn*32 + j*16 + rl;
        int sl = (ks*4 + kq) ^ (cdx & 7);
        bh2[j] = *(const bf16x8*)&lds[cur][2][cdx][sl*8];
        bl2[j] = *(const bf16x8*)&lds[cur][3][cdx][sl*8];
      }
#pragma unroll
      for (int i = 0; i < 2; ++i){
#pragma unroll
        for (int j = 0; j < 2; ++j){
          acc[i][j] = __builtin_amdgcn_mfma_f32_16x16x32_bf16(ah[i],  bh2[j], acc[i][j], 0, 0, 0);
          acc[i][j] = __builtin_amdgcn_mfma_f32_16x16x32_bf16(ah[i],  bl2[j], acc[i][j], 0, 0, 0);
          acc[i][j] = __builtin_amdgcn_mfma_f32_16x16x32_bf16(al2[i], bh2[j], acc[i][j], 0, 0, 0);
        }
      }
    }
    __syncthreads();
  }

#pragma unroll
  for (int i = 0; i < 2; ++i){
#pragma unroll
    for (int j = 0; j < 2; ++j){
      int col = bn*64 + wn*32 + j*16 + rl;
      float bb = b2[col];
#pragma unroll
      for (int r = 0; r < 4; ++r){
        int row = bm*64 + wm*32 + i*16 + kq*4 + r;
        if (row < GM) out[(size_t)row*GN + col] = 0.25f*acc[i][j][r] + bb;
      }
    }
  }
}

// ---------------------------------------------------------------------------
extern "C" void kernel_launch(void* const* d_in, const int* in_sizes, int n_in,
                              void* d_out, int out_size, void* d_ws, size_t ws_size,
                              hipStream_t stream){
  const int*   x     = (const int*)d_in[0];
  const int*   ei    = (const int*)d_in[1];
  const int*   ea    = (const int*)d_in[2];
  const float* x_emb = (const float*)d_in[3];
  const float* e_emb = (const float*)d_in[4];
  const float* W1    = (const float*)d_in[5];
  const float* as1   = (const float*)d_in[6];
  const float* ad1   = (const float*)d_in[7];
  const float* We1   = (const float*)d_in[8];
  const float* ae1   = (const float*)d_in[9];
  const float* b1    = (const float*)d_in[10];
  const float* W2    = (const float*)d_in[11];
  const float* as2   = (const float*)d_in[12];
  const float* ad2   = (const float*)d_in[13];
  const float* We2   = (const float*)d_in[14];
  const float* ae2   = (const float*)d_in[15];
  const float* b2    = (const float*)d_in[16];
  const int* srcv = ei;
  const int* dstv = ei + NE;
  float* out = (float*)d_out;

  char* p = (char*)d_ws;
  auto take = [&](size_t n){ void* q = (void*)p; p += (n + 255) & ~(size_t)255; return q; };
  int*   cursor  = (int*)take(NN*4);
  int*   offsets = (int*)take((NN+1)*4);
  int*   csr     = (int*)take(NE*4);
  float* we_a1   = (float*)take(EMBD*NH*4);
  float* wa_s2   = (float*)take(HID*NH*4);
  float* wa_d2   = (float*)take(HID*NH*4);
  float* we_a2   = (float*)take(EMBD*NH*4);
  float* xa_s1   = (float*)take(178*NH*4);
  float* xa_d1   = (float*)take(178*NH*4);
  float* ew1     = (float*)take(18*NH*4);
  float* ew2     = (float*)take(18*NH*4);
  float* xh1     = (float*)take((size_t)178*1536*4);
  unsigned short* Xeh  = (unsigned short*)take((size_t)178*768*2);
  unsigned short* Xel  = (unsigned short*)take((size_t)178*768*2);
  unsigned short* W1th = (unsigned short*)take((size_t)1536*768*2);
  unsigned short* W1tl = (unsigned short*)take((size_t)1536*768*2);
  unsigned short* XHh  = (unsigned short*)take((size_t)HID*K1*2);
  unsigned short* XHl  = (unsigned short*)take((size_t)HID*K1*2);
  unsigned short* Qh   = (unsigned short*)take((size_t)NN*K1*2);
  unsigned short* Ql   = (unsigned short*)take((size_t)NN*K1*2);
  unsigned short* Bth  = (unsigned short*)take((size_t)GN*GK*2);
  unsigned short* Btl  = (unsigned short*)take((size_t)GN*GK*2);
  unsigned short* Gh   = (unsigned short*)take((size_t)GM*GK*2);
  unsigned short* Gl   = (unsigned short*)take((size_t)GM*GK*2);
  float* spill   = (float*)take((size_t)NE*NH*4);
  float* hact    = (float*)take((size_t)NN*HID*4);
  float* asrc2   = (float*)take(NN*NH*4);
  float* adst2   = (float*)take(NN*NH*4);

  // CSR: fused count/scan (1 block, 1024 thr) + parallel fill
  k_cnt<<<1, 1024, 0, stream>>>(dstv, offsets, cursor);
  k_fill<<<(NE+255)/256, 256, 0, stream>>>(dstv, cursor, csr);

  // prep: collapses; transposes+splits; xh1 via MFMA; prepB
  k_prep1<<<384, 256, 0, stream>>>(We1, ae1, W2, as2, ad2, We2, ae2,
                                   we_a1, wa_s2, wa_d2, we_a2);
  k_tr<<<710, 256, 0, stream>>>(W2, W1, x_emb, Bth, Btl, W1th, W1tl, Xeh, Xel);
  k_mmX<<<72, 256, 0, stream>>>(Xeh, Xel, W1th, W1tl, xh1);
  k_prepB<<<476, 256, 0, stream>>>(xh1, as1, ad1, e_emb, we_a1, we_a2,
                                   XHh, XHl, xa_s1, xa_d1, ew1, ew2);

  // layer 1: softmax + token-coefficient build -> Q; hact via MFMA; dots
  k_gat1sm<<<NN, 256, 0, stream>>>(offsets, csr, srcv, x, ea, xa_s1, xa_d1,
                                   ew1, spill, Qh, Ql);
  k_mm1<<<192, 256, 0, stream>>>(Qh, Ql, XHh, XHl, b1, hact);
  k_dots<<<500, 256, 0, stream>>>(hact, wa_s2, wa_d2, asrc2, adst2);

  // layer 2 fused agg-first -> G (bf16 hi/lo)
  k_gat2<<<NN, 384, 0, stream>>>(offsets, csr, srcv, ea, asrc2, adst2, ew2,
                                 hact, spill, Gh, Gl);

  // out = 0.25*(G @ Bt^T) + b2 via LDS-staged bf16 3-product MFMA
  k_mm2<<<384, 256, 0, stream>>>(Gh, Gl, Bth, Btl, b2, out);
}

// Round 17
// 119.931 us; speedup vs baseline: 1.1417x; 1.0219x over previous
//
#include <hip/hip_runtime.h>
#include <hip/hip_bf16.h>

#define NN   2000
#define NE   32000
#define EMBD 768
#define NH   4
#define HID  384
#define NEG  0.2f
#define DCAP 128

#define GM 2000
#define GN 768
#define GK 1536
#define K1 768          // mm1/mmX K

typedef __bf16 bf16x8 __attribute__((ext_vector_type(8)));
typedef float  f32x4  __attribute__((ext_vector_type(4)));

__device__ inline float wsum(float v){
#pragma unroll
  for (int o = 32; o > 0; o >>= 1) v += __shfl_xor(v, o, 64);
  return v;
}
__device__ inline float wmax(float v){
#pragma unroll
  for (int o = 32; o > 0; o >>= 1) v = fmaxf(v, __shfl_xor(v, o, 64));
  return v;
}

__device__ inline unsigned short f2bf(float f){
  unsigned u = __float_as_uint(f);
  unsigned r = (u + 0x7FFFu + ((u >> 16) & 1u)) >> 16;
  return (unsigned short)r;
}
__device__ inline float bf2f(unsigned short h){
  return __uint_as_float(((unsigned)h) << 16);
}

__device__ inline void gload16(const void* g, void* l){
  __builtin_amdgcn_global_load_lds((const __attribute__((address_space(1))) void*)g,
                                   (__attribute__((address_space(3))) void*)l, 16, 0, 0);
}
__device__ inline float dot4(float4 a, float4 b){
  return a.x*b.x + a.y*b.y + a.z*b.z + a.w*b.w;
}

// ---- CSR: zero+count+scan fused (single block, 1024 threads) ---------------
__global__ __launch_bounds__(1024) void k_cnt(const int* __restrict__ dst,
                                              int* __restrict__ offsets,
                                              int* __restrict__ cursor){
  __shared__ int cnt[NN];
  __shared__ int s[1024];
  int t = threadIdx.x;
  for (int i = t; i < NN; i += 1024) cnt[i] = 0;
  __syncthreads();
  for (int e = t; e < NE; e += 1024) atomicAdd(&cnt[dst[e]], 1);
  __syncthreads();
  int a = (2*t   < NN) ? cnt[2*t  ] : 0;
  int b = (2*t+1 < NN) ? cnt[2*t+1] : 0;
  s[t] = a + b;
  __syncthreads();
  for (int off = 1; off < 1024; off <<= 1){
    int v = (t >= off) ? s[t-off] : 0;
    __syncthreads();
    s[t] += v;
    __syncthreads();
  }
  int base = (t > 0) ? s[t-1] : 0;
  if (2*t < NN){ offsets[2*t] = base; cursor[2*t] = base; }
  if (2*t+1 < NN){ offsets[2*t+1] = base + a; cursor[2*t+1] = base + a; }
  if (2*t == NN) offsets[NN] = base;
}

__global__ void k_fill(const int* __restrict__ dst, int* __restrict__ cursor,
                       int* __restrict__ csr){
  int e = blockIdx.x * blockDim.x + threadIdx.x;
  if (e < NE){
    int p = atomicAdd(&cursor[dst[e]], 1);
    csr[p] = e;
  }
}

// ---- prepA: row-batched collapses [0,384) | W2->Bt [384,672) |
//             W1->W1t [672,960) | x_emb split [960,1094) ---------------------
__global__ __launch_bounds__(256) void k_prepA(
    const float* __restrict__ We1, const float* __restrict__ ae1,
    const float* __restrict__ W2,  const float* __restrict__ as2,
    const float* __restrict__ ad2, const float* __restrict__ We2,
    const float* __restrict__ ae2, const float* __restrict__ W1,
    const float* __restrict__ x_emb,
    float* __restrict__ we_a1, float* __restrict__ wa_s2,
    float* __restrict__ wa_d2, float* __restrict__ we_a2,
    unsigned short* __restrict__ Bh, unsigned short* __restrict__ Bl,
    unsigned short* __restrict__ W1th, unsigned short* __restrict__ W1tl,
    unsigned short* __restrict__ Xeh, unsigned short* __restrict__ Xel){
  __shared__ __align__(16) float tile[64][65];
  int blk = blockIdx.x, t = threadIdx.x;
  if (blk < 384){
    int wid = blk*4 + (t >> 6);
    int lane = t & 63;
    bool lo32 = lane < 32;
    if (wid < 384){
      int kg = wid >> 2, h = wid & 3;
      int k0 = kg*8;
      const float4* ap = (const float4*)(ae1 + h*384);
      float4 a0 = ap[lane];
      float4 a1 = lo32 ? ap[64+lane] : make_float4(0,0,0,0);
      float res[8];
#pragma unroll
      for (int r = 0; r < 8; ++r){
        const float4* wr = (const float4*)(We1 + (size_t)(k0+r)*1536 + h*384);
        float s = dot4(wr[lane], a0);
        if (lo32) s += dot4(wr[64+lane], a1);
        res[r] = s;
      }
#pragma unroll
      for (int r = 0; r < 8; ++r) res[r] = wsum(res[r]);
      if (lane == 0){
#pragma unroll
        for (int r = 0; r < 8; ++r) we_a1[(k0+r)*4+h] = res[r];
      }
    } else if (wid < 768){
      int t2 = wid - 384;
      int kg = t2 >> 2, h = t2 & 3;
      int k0 = kg*4;
      const float4* s4 = (const float4*)(as2 + h*768);
      const float4* d4 = (const float4*)(ad2 + h*768);
      float4 sa[3], da[3];
#pragma unroll
      for (int i = 0; i < 3; ++i){ sa[i] = s4[i*64+lane]; da[i] = d4[i*64+lane]; }
      float r1[4], r2[4];
#pragma unroll
      for (int r = 0; r < 4; ++r){
        const float4* wr = (const float4*)(W2 + (size_t)(k0+r)*3072 + h*768);
        float s1 = 0.f, s2 = 0.f;
#pragma unroll
        for (int i = 0; i < 3; ++i){
          float4 w = wr[i*64+lane];
          s1 += dot4(w, sa[i]); s2 += dot4(w, da[i]);
        }
        r1[r] = s1; r2[r] = s2;
      }
#pragma unroll
      for (int r = 0; r < 4; ++r){ r1[r] = wsum(r1[r]); r2[r] = wsum(r2[r]); }
      if (lane == 0){
#pragma unroll
        for (int r = 0; r < 4; ++r){ wa_s2[(k0+r)*4+h] = r1[r]; wa_d2[(k0+r)*4+h] = r2[r]; }
      }
    } else {
      int t2 = wid - 768;
      int kg = t2 >> 2, h = t2 & 3;
      int k0 = kg*4;
      const float4* ap = (const float4*)(ae2 + h*768);
      float4 aa[3];
#pragma unroll
      for (int i = 0; i < 3; ++i) aa[i] = ap[i*64+lane];
      float res[4];
#pragma unroll
      for (int r = 0; r < 4; ++r){
        const float4* wr = (const float4*)(We2 + (size_t)(k0+r)*3072 + h*768);
        float s = 0.f;
#pragma unroll
        for (int i = 0; i < 3; ++i) s += dot4(wr[i*64+lane], aa[i]);
        res[r] = s;
      }
#pragma unroll
      for (int r = 0; r < 4; ++r) res[r] = wsum(res[r]);
      if (lane == 0){
#pragma unroll
        for (int r = 0; r < 4; ++r) we_a2[(k0+r)*4+h] = res[r];
      }
    }
  } else if (blk < 672){
    int idx = blk - 384;
    int bk = (idx % 24) * 64;
    int bc = (idx / 24) * 64;
    int cc = t & 63, kk4 = t >> 6;
#pragma unroll
    for (int i = 0; i < 16; ++i){
      int kk = kk4*16 + i;
      int k = bk + kk;
      int h = k / 384, kp = k - h*384;
      tile[kk][cc] = W2[(size_t)kp*3072 + h*768 + bc + cc];
    }
    __syncthreads();
    int kk2 = t & 63, cc4 = t >> 6;
#pragma unroll
    for (int i = 0; i < 16; ++i){
      int c2 = cc4*16 + i;
      float v = tile[kk2][c2];
      unsigned short hi = f2bf(v);
      unsigned short lo = f2bf(v - bf2f(hi));
      size_t o = (size_t)(bc + c2)*GK + bk + kk2;
      Bh[o] = hi; Bl[o] = lo;
    }
  } else if (blk < 960){
    int idx = blk - 672;
    int bkk = (idx % 12) * 64;
    int bcc = (idx / 12) * 64;
    int cc = t & 63, kk4 = t >> 6;
#pragma unroll
    for (int i = 0; i < 16; ++i){
      int kk = kk4*16 + i;
      tile[kk][cc] = W1[(size_t)(bkk+kk)*1536 + bcc + cc];
    }
    __syncthreads();
    int kk2 = t & 63, cc4 = t >> 6;
#pragma unroll
    for (int i = 0; i < 16; ++i){
      int c2 = cc4*16 + i;
      float v = tile[kk2][c2];
      unsigned short hi = f2bf(v);
      unsigned short lo = f2bf(v - bf2f(hi));
      size_t o = (size_t)(bcc + c2)*768 + bkk + kk2;
      W1th[o] = hi; W1tl[o] = lo;
    }
  } else {
    int i = (blk - 960)*256 + t;          // < 178*768/4 = 34176
    if (i < 34176){
      float4 v = ((const float4*)x_emb)[i];
      unsigned short h0 = f2bf(v.x), h1 = f2bf(v.y), h2 = f2bf(v.z), h3 = f2bf(v.w);
      ushort4 hh; hh.x = h0; hh.y = h1; hh.z = h2; hh.w = h3;
      ushort4 ll; ll.x = f2bf(v.x - bf2f(h0)); ll.y = f2bf(v.y - bf2f(h1));
      ll.z = f2bf(v.z - bf2f(h2)); ll.w = f2bf(v.w - bf2f(h3));
      ((ushort4*)Xeh)[i] = hh;
      ((ushort4*)Xel)[i] = ll;
    }
  }
}

// ---- k_mmX: xh1 = Xe @ W1t^T  (f32 out, bf16 3-product MFMA) ---------------
__global__ __launch_bounds__(256) void k_mmX(const unsigned short* __restrict__ Ah,
                                             const unsigned short* __restrict__ Al,
                                             const unsigned short* __restrict__ Bh,
                                             const unsigned short* __restrict__ Bl,
                                             float* __restrict__ xh1){
  __shared__ __align__(16) unsigned short lds[2][4][64][64];
  int b = blockIdx.x;
  int bm = b / 24, bn = b % 24;
  int wave = threadIdx.x >> 6, lane = threadIdx.x & 63;
  int wm = wave >> 1, wn = wave & 1;
  int rl = lane & 15, kq = lane >> 4;

  int rt   = lane >> 3;
  int kswz = ((lane & 7) ^ rt) * 8;
  const unsigned short* sbase;
  int rowbase;
  if (wave == 0){ sbase = Ah; rowbase = bm*64; }
  else if (wave == 1){ sbase = Al; rowbase = bm*64; }
  else if (wave == 2){ sbase = Bh; rowbase = bn*64; }
  else { sbase = Bl; rowbase = bn*64; }
  bool isA = wave < 2;

  f32x4 acc[2][2] = {};

#pragma unroll
  for (int i = 0; i < 8; ++i){
    int row = rowbase + i*8 + rt;
    if (isA) row = (row < 178) ? row : 177;
    gload16(sbase + (size_t)row*768 + kswz, &lds[0][wave][i*8][0]);
  }
  __syncthreads();

  for (int t = 0; t < 12; ++t){
    int cur = t & 1;
    if (t < 11){
      int k0 = (t+1)*64;
#pragma unroll
      for (int i = 0; i < 8; ++i){
        int row = rowbase + i*8 + rt;
        if (isA) row = (row < 178) ? row : 177;
        gload16(sbase + (size_t)row*768 + k0 + kswz, &lds[cur^1][wave][i*8][0]);
      }
    }
#pragma unroll
    for (int ks = 0; ks < 2; ++ks){
      bf16x8 ah[2], al2[2], bh2[2], bl2[2];
#pragma unroll
      for (int i = 0; i < 2; ++i){
        int r = wm*32 + i*16 + rl;
        int sl = (ks*4 + kq) ^ (r & 7);
        ah[i]  = *(const bf16x8*)&lds[cur][0][r][sl*8];
        al2[i] = *(const bf16x8*)&lds[cur][1][r][sl*8];
      }
#pragma unroll
      for (int j = 0; j < 2; ++j){
        int cdx = wn*32 + j*16 + rl;
        int sl = (ks*4 + kq) ^ (cdx & 7);
        bh2[j] = *(const bf16x8*)&lds[cur][2][cdx][sl*8];
        bl2[j] = *(const bf16x8*)&lds[cur][3][cdx][sl*8];
      }
#pragma unroll
      for (int i = 0; i < 2; ++i){
#pragma unroll
        for (int j = 0; j < 2; ++j){
          acc[i][j] = __builtin_amdgcn_mfma_f32_16x16x32_bf16(ah[i],  bh2[j], acc[i][j], 0, 0, 0);
          acc[i][j] = __builtin_amdgcn_mfma_f32_16x16x32_bf16(ah[i],  bl2[j], acc[i][j], 0, 0, 0);
          acc[i][j] = __builtin_amdgcn_mfma_f32_16x16x32_bf16(al2[i], bh2[j], acc[i][j], 0, 0, 0);
        }
      }
    }
    __syncthreads();
  }

#pragma unroll
  for (int i = 0; i < 2; ++i){
#pragma unroll
    for (int j = 0; j < 2; ++j){
      int col = bn*64 + wn*32 + j*16 + rl;
#pragma unroll
      for (int r = 0; r < 4; ++r){
        int row = bm*64 + wm*32 + i*16 + kq*4 + r;
        if (row < 178) xh1[(size_t)row*1536 + col] = acc[i][j][r];
      }
    }
  }
}

// ---- prepB: XHt bf16 build + xa dots + ew dots + pad zero ------------------
__global__ __launch_bounds__(256) void k_prepB(
    const float* __restrict__ xh1,
    const float* __restrict__ as1, const float* __restrict__ ad1,
    const float* __restrict__ e_emb,
    const float* __restrict__ we_a1, const float* __restrict__ we_a2,
    unsigned short* __restrict__ XHh, unsigned short* __restrict__ XHl,
    float* __restrict__ xa_s1, float* __restrict__ xa_d1,
    float* __restrict__ ew1, float* __restrict__ ew2){
  int blk = blockIdx.x, t = threadIdx.x;
  if (blk < 178){
    int tok = blk;
    for (int i = t; i < 1536; i += 256){
      float v = xh1[(size_t)tok*1536 + i];
      int h = i / 384, c = i - h*384;
      size_t off = (size_t)c*K1 + h*192 + tok;
      unsigned short hi = f2bf(v);
      XHh[off] = hi; XHl[off] = f2bf(v - bf2f(hi));
    }
  } else if (blk < 356){
    int r = blk - 178;
    int h = t >> 6, lane = t & 63;
    const float4* p0 = (const float4*)(xh1 + (size_t)r*1536 + h*384);
    const float4* s4 = (const float4*)(as1 + h*384);
    const float4* d4 = (const float4*)(ad1 + h*384);
    float s1, s2;
    {
      float4 u = p0[lane], sa = s4[lane], da = d4[lane];
      s1 = dot4(u, sa); s2 = dot4(u, da);
    }
    if (lane < 32){
      float4 u = p0[64+lane], sa = s4[64+lane], da = d4[64+lane];
      s1 += dot4(u, sa); s2 += dot4(u, da);
    }
    s1 = wsum(s1); s2 = wsum(s2);
    if (lane == 0){ xa_s1[r*4+h] = s1; xa_d1[r*4+h] = s2; }
  } else if (blk < 392){
    int id = (blk - 356)*4 + (t >> 6);
    int lane = t & 63;
    const float* wv = (id < 72) ? we_a1 : we_a2;
    float* o = (id < 72) ? ew1 : ew2;
    int id2 = (id < 72) ? id : (id - 72);
    int r = id2 >> 2, h = id2 & 3;
    const float* ar = e_emb + (size_t)r*EMBD;
    float acc = 0.f;
    for (int k = lane; k < EMBD; k += 64) acc += ar[k] * wv[k*4+h];
    acc = wsum(acc);
    if (lane == 0) o[r*4+h] = acc;
  } else {
    int i = (blk - 392)*256 + t;               // < 384*4*14 = 21504
    if (i < 21504){
      int c = i / 56, rem = i - c*56;
      int h = rem / 14, tp = 178 + rem - h*14;
      size_t off = (size_t)c*K1 + h*192 + tp;
      XHh[off] = 0; XHl[off] = 0;
    }
  }
}

// ---- layer-1 softmax + token-coefficient build -> Q bf16 hi/lo -------------
__global__ __launch_bounds__(256) void k_gat1sm(const int* __restrict__ offsets,
                      int* __restrict__ csr, const int* __restrict__ srcv,
                      const int* __restrict__ x, const int* __restrict__ ea,
                      const float* __restrict__ xa_s1, const float* __restrict__ xa_d1,
                      const float* __restrict__ ew1, float* __restrict__ spill,
                      unsigned short* __restrict__ Qh, unsigned short* __restrict__ Ql){
  __shared__ float wts[DCAP][5];
  __shared__ int   sE[DCAP];
  __shared__ int   sA[DCAP], sB[DCAP];
  __shared__ float coef[K1];
  int n = blockIdx.x, t = threadIdx.x;
  int w = t >> 6, lane = t & 63;
  int lo = offsets[n], hi = offsets[n+1];
  int deg = hi - lo;
  bool big = deg > DCAP;

  if (!big){
    if (deg <= 64){
      if (w == 0){
        int v = (lane < deg) ? csr[lo+lane] : 0x7fffffff;
#pragma unroll
        for (int k = 2; k <= 64; k <<= 1){
#pragma unroll
          for (int j2 = k >> 1; j2 > 0; j2 >>= 1){
            int o = __shfl_xor(v, j2, 64);
            bool lower = (lane & j2) == 0;
            bool asc   = (lane & k) == 0;
            v = (lower == asc) ? min(v, o) : max(v, o);
          }
        }
        sE[lane] = v;
        if (lane < deg) csr[lo+lane] = v;
      }
    } else {
      int m = 1; while (m < deg) m <<= 1;
      for (int i = t; i < m; i += 256) sE[i] = (i < deg) ? csr[lo+i] : 0x7fffffff;
      __syncthreads();
      for (int k = 2; k <= m; k <<= 1){
        for (int j2 = k >> 1; j2 > 0; j2 >>= 1){
          for (int i = t; i < m; i += 256){
            int ixj = i ^ j2;
            if (ixj > i){
              int a = sE[i], b = sE[ixj];
              bool up = ((i & k) == 0);
              if ((a > b) == up){ sE[i] = b; sE[ixj] = a; }
            }
          }
          __syncthreads();
        }
      }
      for (int i = t; i < deg; i += 256) csr[lo+i] = sE[i];
    }
  } else {
    if (t == 0){
      for (int i = lo+1; i < hi; ++i){
        int v = csr[i], j = i-1;
        while (j >= lo && csr[j] > v){ csr[j+1] = csr[j]; --j; }
        csr[j+1] = v;
      }
    }
  }
  for (int i = t; i < K1; i += 256) coef[i] = 0.f;
  __syncthreads();

  int xn0 = x[2*n], xn1 = x[2*n+1];
  float ad_n = xa_d1[xn0*4+w] + xa_d1[xn1*4+w];
  float as_n = xa_s1[xn0*4+w] + xa_s1[xn1*4+w];
  float mx = -3.4e38f, sae = 0.f;
  float wlv;
  if (!big){
    for (int j = lane; j < deg; j += 64){
      int e = sE[j]; int s = srcv[e];
      int a = x[2*s], b = x[2*s+1];
      if (w == 0){ sA[j] = a; sB[j] = b; }
      float ae = ew1[ea[2*e]*4+w] + ew1[ea[2*e+1]*4+w];
      float al = (xa_s1[a*4+w] + xa_s1[b*4+w]) + ad_n + ae;
      al = (al > 0.f) ? al : NEG * al;
      wts[j][w] = al;
      sae += ae; mx = fmaxf(mx, al);
    }
    mx = wmax(mx); sae = wsum(sae);
    float all_ = as_n + ad_n + sae / fmaxf((float)deg, 1.f);
    all_ = (all_ > 0.f) ? all_ : NEG * all_;
    mx = fmaxf(mx, all_);
    float den = 0.f;
    for (int j = lane; j < deg; j += 64){
      float xx = expf(wts[j][w] - mx);
      wts[j][w] = xx; den += xx;
    }
    den = wsum(den);
    float exl = expf(all_ - mx);
    den += exl;
    float inv = 1.f / den;
    for (int j = lane; j < deg; j += 64) wts[j][w] *= inv;
    wlv = exl * inv;
  } else {
    for (int p = lo + lane; p < hi; p += 64){
      int e = csr[p]; int s = srcv[e];
      int a = x[2*s], b = x[2*s+1];
      float ae = ew1[ea[2*e]*4+w] + ew1[ea[2*e+1]*4+w];
      float al = (xa_s1[a*4+w] + xa_s1[b*4+w]) + ad_n + ae;
      al = (al > 0.f) ? al : NEG * al;
      spill[e*4 + w] = al;
      sae += ae; mx = fmaxf(mx, al);
    }
    mx = wmax(mx); sae = wsum(sae);
    float all_ = as_n + ad_n + sae / fmaxf((float)deg, 1.f);
    all_ = (all_ > 0.f) ? all_ : NEG * all_;
    mx = fmaxf(mx, all_);
    float den = 0.f;
    for (int p = lo + lane; p < hi; p += 64){
      int e = csr[p];
      float xx = expf(spill[e*4 + w] - mx);
      spill[e*4 + w] = xx; den += xx;
    }
    den = wsum(den);
    float exl = expf(all_ - mx);
    den += exl;
    float inv = 1.f / den;
    for (int p = lo + lane; p < hi; p += 64) spill[csr[p]*4 + w] *= inv;
    wlv = exl * inv;
  }
  __syncthreads();

  // deterministic coefficient scatter: lane 0 of warp w owns head-w slice
  if (lane == 0){
    float* cf = coef + w*192;
    if (!big){
      for (int j = 0; j < deg; ++j){
        float wj = wts[j][w];
        cf[sA[j]] += wj; cf[sB[j]] += wj;
      }
    } else {
      for (int p = lo; p < hi; ++p){
        int e = csr[p]; int s = srcv[e];
        float wj = spill[e*4 + w];
        cf[x[2*s]] += wj; cf[x[2*s+1]] += wj;
      }
    }
    cf[xn0] += wlv; cf[xn1] += wlv;
  }
  __syncthreads();

  for (int i = t; i < K1; i += 256){
    float v = coef[i];
    unsigned short hi16 = f2bf(v);
    Qh[(size_t)n*K1 + i] = hi16;
    Ql[(size_t)n*K1 + i] = f2bf(v - bf2f(hi16));
  }
}

// ---- mm1: hact = relu(0.25*(Q @ XHt^T) + b1), bf16 3-product MFMA ----------
__global__ __launch_bounds__(256) void k_mm1(const unsigned short* __restrict__ Qh,
                                             const unsigned short* __restrict__ Ql,
                                             const unsigned short* __restrict__ XHh,
                                             const unsigned short* __restrict__ XHl,
                                             const float* __restrict__ b1,
                                             float* __restrict__ hact){
  __shared__ __align__(16) unsigned short lds[2][4][64][64];
  int b = blockIdx.x;
  int xcd = b & 7, idx = b >> 3;            // idx in [0,24)
  int bm = xcd*4 + idx/6, bn = idx % 6;
  int wave = threadIdx.x >> 6, lane = threadIdx.x & 63;
  int wm = wave >> 1, wn = wave & 1;
  int rl = lane & 15, kq = lane >> 4;

  int rt   = lane >> 3;
  int kswz = ((lane & 7) ^ rt) * 8;
  const unsigned short* sbase;
  int rowbase;
  if (wave == 0){ sbase = Qh; rowbase = bm*64; }
  else if (wave == 1){ sbase = Ql; rowbase = bm*64; }
  else if (wave == 2){ sbase = XHh; rowbase = bn*64; }
  else { sbase = XHl; rowbase = bn*64; }
  bool isA = wave < 2;

  f32x4 acc[2][2] = {};

#pragma unroll
  for (int i = 0; i < 8; ++i){
    int row = rowbase + i*8 + rt;
    if (isA) row = (row < GM) ? row : (GM-1);
    gload16(sbase + (size_t)row*K1 + kswz, &lds[0][wave][i*8][0]);
  }
  __syncthreads();

  for (int t = 0; t < 12; ++t){
    int cur = t & 1;
    if (t < 11){
      int k0 = (t+1)*64;
#pragma unroll
      for (int i = 0; i < 8; ++i){
        int row = rowbase + i*8 + rt;
        if (isA) row = (row < GM) ? row : (GM-1);
        gload16(sbase + (size_t)row*K1 + k0 + kswz, &lds[cur^1][wave][i*8][0]);
      }
    }
#pragma unroll
    for (int ks = 0; ks < 2; ++ks){
      bf16x8 ah[2], al2[2], bh2[2], bl2[2];
#pragma unroll
      for (int i = 0; i < 2; ++i){
        int r = wm*32 + i*16 + rl;
        int sl = (ks*4 + kq) ^ (r & 7);
        ah[i]  = *(const bf16x8*)&lds[cur][0][r][sl*8];
        al2[i] = *(const bf16x8*)&lds[cur][1][r][sl*8];
      }
#pragma unroll
      for (int j = 0; j < 2; ++j){
        int cdx = wn*32 + j*16 + rl;
        int sl = (ks*4 + kq) ^ (cdx & 7);
        bh2[j] = *(const bf16x8*)&lds[cur][2][cdx][sl*8];
        bl2[j] = *(const bf16x8*)&lds[cur][3][cdx][sl*8];
      }
#pragma unroll
      for (int i = 0; i < 2; ++i){
#pragma unroll
        for (int j = 0; j < 2; ++j){
          acc[i][j] = __builtin_amdgcn_mfma_f32_16x16x32_bf16(ah[i],  bh2[j], acc[i][j], 0, 0, 0);
          acc[i][j] = __builtin_amdgcn_mfma_f32_16x16x32_bf16(ah[i],  bl2[j], acc[i][j], 0, 0, 0);
          acc[i][j] = __builtin_amdgcn_mfma_f32_16x16x32_bf16(al2[i], bh2[j], acc[i][j], 0, 0, 0);
        }
      }
    }
    __syncthreads();
  }

#pragma unroll
  for (int i = 0; i < 2; ++i){
#pragma unroll
    for (int j = 0; j < 2; ++j){
      int col = bn*64 + wn*32 + j*16 + rl;
      float bb = b1[col];
#pragma unroll
      for (int r = 0; r < 4; ++r){
        int row = bm*64 + wm*32 + i*16 + kq*4 + r;
        if (row < GM) hact[(size_t)row*HID + col] = fmaxf(0.25f*acc[i][j][r] + bb, 0.f);
      }
    }
  }
}

// ---- k_dots: asrc2/adst2 = hact row-dots with wa_s2/wa_d2 ------------------
__global__ __launch_bounds__(256) void k_dots(const float* __restrict__ hact,
                      const float* __restrict__ wa_s2, const float* __restrict__ wa_d2,
                      float* __restrict__ asrc2, float* __restrict__ adst2){
  int w = threadIdx.x >> 6, lane = threadIdx.x & 63;
  int n = blockIdx.x*4 + w;
  float pr[8] = {};
#pragma unroll
  for (int i = 0; i < 6; ++i){
    int c = i*64 + lane;
    float v = hact[(size_t)n*HID + c];
#pragma unroll
    for (int h = 0; h < 4; ++h){
      pr[h]   += v * wa_s2[c*4+h];
      pr[4+h] += v * wa_d2[c*4+h];
    }
  }
#pragma unroll
  for (int o = 32; o > 0; o >>= 1){
#pragma unroll
    for (int q = 0; q < 8; ++q) pr[q] += __shfl_xor(pr[q], o, 64);
  }
  if (lane == 0){
#pragma unroll
    for (int h = 0; h < 4; ++h){ asrc2[n*4+h] = pr[h]; adst2[n*4+h] = pr[4+h]; }
  }
}

// ---- layer-2 fused: on-the-fly alphas + softmax + pipelined agg -> G -------
__global__ __launch_bounds__(384) void k_gat2(const int* __restrict__ offsets,
                      const int* __restrict__ csr, const int* __restrict__ srcv,
                      const int* __restrict__ ea,
                      const float* __restrict__ asrc, const float* __restrict__ adst,
                      const float* __restrict__ ew2,
                      const float* __restrict__ hact, float* __restrict__ spill,
                      unsigned short* __restrict__ Gh, unsigned short* __restrict__ Gl){
  __shared__ float wts[DCAP][5];
  __shared__ int   ssrc[DCAP];
  __shared__ float wl[4];
  int n = blockIdx.x, t = threadIdx.x;
  int w = t >> 6, lane = t & 63;
  int lo = offsets[n], hi = offsets[n+1];
  int deg = hi - lo;
  bool big = deg > DCAP;
  if (w < 4){
    float ad_n = adst[n*NH + w];
    float as_n = asrc[n*NH + w];
    float mx = -3.4e38f, sae = 0.f;
    if (!big){
      for (int p = lo + lane; p < hi; p += 64){
        int e = csr[p]; int s = srcv[e];
        if (w == 0) ssrc[p - lo] = s;
        float ae = ew2[ea[2*e]*4+w] + ew2[ea[2*e+1]*4+w];
        float al = asrc[s*NH + w] + ad_n + ae;
        al = (al > 0.f) ? al : NEG * al;
        wts[p - lo][w] = al;
        sae += ae; mx = fmaxf(mx, al);
      }
      mx = wmax(mx); sae = wsum(sae);
      float all_ = as_n + ad_n + sae / fmaxf((float)deg, 1.f);
      all_ = (all_ > 0.f) ? all_ : NEG * all_;
      mx = fmaxf(mx, all_);
      float den = 0.f;
      for (int p = lo + lane; p < hi; p += 64){
        float xx = expf(wts[p - lo][w] - mx);
        wts[p - lo][w] = xx; den += xx;
      }
      den = wsum(den);
      float exl = expf(all_ - mx);
      den += exl;
      float inv = 1.f / den;
      for (int p = lo + lane; p < hi; p += 64) wts[p - lo][w] *= inv;
      if (lane == 0) wl[w] = exl * inv;
    } else {
      for (int p = lo + lane; p < hi; p += 64){
        int e = csr[p];
        float ae = ew2[ea[2*e]*4+w] + ew2[ea[2*e+1]*4+w];
        float al = asrc[srcv[e]*NH + w] + ad_n + ae;
        al = (al > 0.f) ? al : NEG * al;
        spill[e*4 + w] = al;
        sae += ae; mx = fmaxf(mx, al);
      }
      mx = wmax(mx); sae = wsum(sae);
      float all_ = as_n + ad_n + sae / fmaxf((float)deg, 1.f);
      all_ = (all_ > 0.f) ? all_ : NEG * all_;
      mx = fmaxf(mx, all_);
      float den = 0.f;
      for (int p = lo + lane; p < hi; p += 64){
        int e = csr[p];
        float xx = expf(spill[e*4 + w] - mx);
        spill[e*4 + w] = xx; den += xx;
      }
      den = wsum(den);
      float exl = expf(all_ - mx);
      den += exl;
      float inv = 1.f / den;
      for (int p = lo + lane; p < hi; p += 64) spill[csr[p]*4 + w] *= inv;
      if (lane == 0) wl[w] = exl * inv;
    }
  }
  __syncthreads();

  int c = t;
  float a0 = 0.f, a1 = 0.f, a2 = 0.f, a3 = 0.f;
  if (!big){
    float vnext = 0.f;
    if (deg > 0) vnext = hact[(size_t)ssrc[0]*HID + c];
    for (int j = 0; j < deg; ++j){
      float vc = vnext;
      if (j+1 < deg) vnext = hact[(size_t)ssrc[j+1]*HID + c];
      float w0=wts[j][0], w1=wts[j][1], w2=wts[j][2], w3=wts[j][3];
      a0 += w0*vc; a1 += w1*vc; a2 += w2*vc; a3 += w3*vc;
    }
  } else {
    for (int j = 0; j < deg; ++j){
      int e = csr[lo+j]; int s = srcv[e];
      float w0 = spill[e*4+0], w1 = spill[e*4+1], w2 = spill[e*4+2], w3 = spill[e*4+3];
      float vc = hact[(size_t)s*HID + c];
      a0 += w0*vc; a1 += w1*vc; a2 += w2*vc; a3 += w3*vc;
    }
  }
  {
    float vc = hact[(size_t)n*HID + c];
    a0 += wl[0]*vc; a1 += wl[1]*vc; a2 += wl[2]*vc; a3 += wl[3]*vc;
  }
  size_t base = (size_t)n*GK + c;
  float vv[4] = {a0, a1, a2, a3};
#pragma unroll
  for (int h = 0; h < 4; ++h){
    unsigned short hi16 = f2bf(vv[h]);
    unsigned short lo16 = f2bf(vv[h] - bf2f(hi16));
    Gh[base + h*384] = hi16;
    Gl[base + h*384] = lo16;
  }
}

// ---- layer-2 MFMA GEMM: LDS-staged, double-buffered, XOR-swizzled ----------
__global__ __launch_bounds__(256) void k_mm2(const unsigned short* __restrict__ Gh,
                                             const unsigned short* __restrict__ Gl,
                                             const unsigned short* __restrict__ Bh,
                                             const unsigned short* __restrict__ Bl,
                                             const float* __restrict__ b2,
                                             float* __restrict__ out){
  __shared__ __align__(16) unsigned short lds[2][4][64][64];
  int b = blockIdx.x;
  int xcd = b & 7, idx = b >> 3;
  int bm = xcd*4 + idx/12, bn = idx % 12;
  int wave = threadIdx.x >> 6, lane = threadIdx.x & 63;
  int wm = wave >> 1, wn = wave & 1;
  int rl = lane & 15, kq = lane >> 4;

  int rt   = lane >> 3;
  int kswz = ((lane & 7) ^ rt) * 8;
  const unsigned short* sbase;
  int rowbase;
  if (wave == 0){ sbase = Gh; rowbase = bm*64; }
  else if (wave == 1){ sbase = Gl; rowbase = bm*64; }
  else if (wave == 2){ sbase = Bh; rowbase = bn*64; }
  else { sbase = Bl; rowbase = bn*64; }
  bool isA = wave < 2;

  f32x4 acc[2][2] = {};

#pragma unroll
  for (int i = 0; i < 8; ++i){
    int row = rowbase + i*8 + rt;
    if (isA) row = (row < GM) ? row : (GM-1);
    gload16(sbase + (size_t)row*GK + kswz, &lds[0][wave][i*8][0]);
  }
  __syncthreads();

  for (int t = 0; t < 24; ++t){
    int cur = t & 1;
    if (t < 23){
      int k0 = (t+1)*64;
#pragma unroll
      for (int i = 0; i < 8; ++i){
        int row = rowbase + i*8 + rt;
        if (isA) row = (row < GM) ? row : (GM-1);
        gload16(sbase + (size_t)row*GK + k0 + kswz, &lds[cur^1][wave][i*8][0]);
      }
    }
#pragma unroll
    for (int ks = 0; ks < 2; ++ks){
      bf16x8 ah[2], al2[2], bh2[2], bl2[2];
#pragma unroll
      for (int i = 0; i < 2; ++i){
        int r = wm*32 + i*16 + rl;
        int sl = (ks*4 + kq) ^ (r & 7);
        ah[i]  = *(const bf16x8*)&lds[cur][0][r][sl*8];
        al2[i] = *(const bf16x8*)&lds[cur][1][r][sl*8];
      }
#pragma unroll
      for (int j = 0; j < 2; ++j){
        int cdx = wn*32 + j*16 + rl;
        int sl = (ks*4 + kq) ^ (cdx & 7);
        bh2[j] = *(const bf16x8*)&lds[cur][2][cdx][sl*8];
        bl2[j] = *(const bf16x8*)&lds[cur][3][cdx][sl*8];
      }
#pragma unroll
      for (int i = 0; i < 2; ++i){
#pragma unroll
        for (int j = 0; j < 2; ++j){
          acc[i][j] = __builtin_amdgcn_mfma_f32_16x16x32_bf16(ah[i],  bh2[j], acc[i][j], 0, 0, 0);
          acc[i][j] = __builtin_amdgcn_mfma_f32_16x16x32_bf16(ah[i],  bl2[j], acc[i][j], 0, 0, 0);
          acc[i][j] = __builtin_amdgcn_mfma_f32_16x16x32_bf16(al2[i], bh2[j], acc[i][j], 0, 0, 0);
        }
      }
    }
    __syncthreads();
  }

#pragma unroll
  for (int i = 0; i < 2; ++i){
#pragma unroll
    for (int j = 0; j < 2; ++j){
      int col = bn*64 + wn*32 + j*16 + rl;
      float bb = b2[col];
#pragma unroll
      for (int r = 0; r < 4; ++r){
        int row = bm*64 + wm*32 + i*16 + kq*4 + r;
        if (row < GM) out[(size_t)row*GN + col] = 0.25f*acc[i][j][r] + bb;
      }
    }
  }
}

// ---------------------------------------------------------------------------
extern "C" void kernel_launch(void* const* d_in, const int* in_sizes, int n_in,
                              void* d_out, int out_size, void* d_ws, size_t ws_size,
                              hipStream_t stream){
  const int*   x     = (const int*)d_in[0];
  const int*   ei    = (const int*)d_in[1];
  const int*   ea    = (const int*)d_in[2];
  const float* x_emb = (const float*)d_in[3];
  const float* e_emb = (const float*)d_in[4];
  const float* W1    = (const float*)d_in[5];
  const float* as1   = (const float*)d_in[6];
  const float* ad1   = (const float*)d_in[7];
  const float* We1   = (const float*)d_in[8];
  const float* ae1   = (const float*)d_in[9];
  const float* b1    = (const float*)d_in[10];
  const float* W2    = (const float*)d_in[11];
  const float* as2   = (const float*)d_in[12];
  const float* ad2   = (const float*)d_in[13];
  const float* We2   = (const float*)d_in[14];
  const float* ae2   = (const float*)d_in[15];
  const float* b2    = (const float*)d_in[16];
  const int* srcv = ei;
  const int* dstv = ei + NE;
  float* out = (float*)d_out;

  char* p = (char*)d_ws;
  auto take = [&](size_t n){ void* q = (void*)p; p += (n + 255) & ~(size_t)255; return q; };
  int*   cursor  = (int*)take(NN*4);
  int*   offsets = (int*)take((NN+1)*4);
  int*   csr     = (int*)take(NE*4);
  float* we_a1   = (float*)take(EMBD*NH*4);
  float* wa_s2   = (float*)take(HID*NH*4);
  float* wa_d2   = (float*)take(HID*NH*4);
  float* we_a2   = (float*)take(EMBD*NH*4);
  float* xa_s1   = (float*)take(178*NH*4);
  float* xa_d1   = (float*)take(178*NH*4);
  float* ew1     = (float*)take(18*NH*4);
  float* ew2     = (float*)take(18*NH*4);
  float* xh1     = (float*)take((size_t)178*1536*4);
  unsigned short* Xeh  = (unsigned short*)take((size_t)178*768*2);
  unsigned short* Xel  = (unsigned short*)take((size_t)178*768*2);
  unsigned short* W1th = (unsigned short*)take((size_t)1536*768*2);
  unsigned short* W1tl = (unsigned short*)take((size_t)1536*768*2);
  unsigned short* XHh  = (unsigned short*)take((size_t)HID*K1*2);
  unsigned short* XHl  = (unsigned short*)take((size_t)HID*K1*2);
  unsigned short* Qh   = (unsigned short*)take((size_t)NN*K1*2);
  unsigned short* Ql   = (unsigned short*)take((size_t)NN*K1*2);
  unsigned short* Bth  = (unsigned short*)take((size_t)GN*GK*2);
  unsigned short* Btl  = (unsigned short*)take((size_t)GN*GK*2);
  unsigned short* Gh   = (unsigned short*)take((size_t)GM*GK*2);
  unsigned short* Gl   = (unsigned short*)take((size_t)GM*GK*2);
  float* spill   = (float*)take((size_t)NE*NH*4);
  float* hact    = (float*)take((size_t)NN*HID*4);
  float* asrc2   = (float*)take(NN*NH*4);
  float* adst2   = (float*)take(NN*NH*4);

  // CSR: fused count/scan (1 block, 1024 thr) + parallel fill
  k_cnt<<<1, 1024, 0, stream>>>(dstv, offsets, cursor);
  k_fill<<<(NE+255)/256, 256, 0, stream>>>(dstv, cursor, csr);

  // prep: collapses + transposes + splits (fused, all-uniform roles)
  k_prepA<<<1094, 256, 0, stream>>>(We1, ae1, W2, as2, ad2, We2, ae2, W1,
                                    x_emb, we_a1, wa_s2, wa_d2, we_a2,
                                    Bth, Btl, W1th, W1tl, Xeh, Xel);
  k_mmX<<<72, 256, 0, stream>>>(Xeh, Xel, W1th, W1tl, xh1);
  k_prepB<<<476, 256, 0, stream>>>(xh1, as1, ad1, e_emb, we_a1, we_a2,
                                   XHh, XHl, xa_s1, xa_d1, ew1, ew2);

  // layer 1: softmax + token-coefficient build -> Q; hact via MFMA; dots
  k_gat1sm<<<NN, 256, 0, stream>>>(offsets, csr, srcv, x, ea, xa_s1, xa_d1,
                                   ew1, spill, Qh, Ql);
  k_mm1<<<192, 256, 0, stream>>>(Qh, Ql, XHh, XHl, b1, hact);
  k_dots<<<500, 256, 0, stream>>>(hact, wa_s2, wa_d2, asrc2, adst2);

  // layer 2 fused agg-first -> G (bf16 hi/lo)
  k_gat2<<<NN, 384, 0, stream>>>(offsets, csr, srcv, ea, asrc2, adst2, ew2,
                                 hact, spill, Gh, Gl);

  // out = 0.25*(G @ Bt^T) + b2 via LDS-staged bf16 3-product MFMA
  k_mm2<<<384, 256, 0, stream>>>(Gh, Gl, Bth, Btl, b2, out);
}

// Round 18
// 117.007 us; speedup vs baseline: 1.1702x; 1.0250x over previous
//
#include <hip/hip_runtime.h>
#include <hip/hip_bf16.h>

#define NN   2000
#define NE   32000
#define EMBD 768
#define NH   4
#define HID  384
#define NEG  0.2f
#define DCAP 128

#define GM 2000
#define GN 768
#define GK 1536
#define K1 768          // mm1/mmX K

typedef __bf16 bf16x8 __attribute__((ext_vector_type(8)));
typedef float  f32x4  __attribute__((ext_vector_type(4)));

__device__ inline float wsum(float v){
#pragma unroll
  for (int o = 32; o > 0; o >>= 1) v += __shfl_xor(v, o, 64);
  return v;
}
__device__ inline float wmax(float v){
#pragma unroll
  for (int o = 32; o > 0; o >>= 1) v = fmaxf(v, __shfl_xor(v, o, 64));
  return v;
}

__device__ inline unsigned short f2bf(float f){
  unsigned u = __float_as_uint(f);
  unsigned r = (u + 0x7FFFu + ((u >> 16) & 1u)) >> 16;
  return (unsigned short)r;
}
__device__ inline float bf2f(unsigned short h){
  return __uint_as_float(((unsigned)h) << 16);
}

__device__ inline void gload16(const void* g, void* l){
  __builtin_amdgcn_global_load_lds((const __attribute__((address_space(1))) void*)g,
                                   (__attribute__((address_space(3))) void*)l, 16, 0, 0);
}
__device__ inline float dot4(float4 a, float4 b){
  return a.x*b.x + a.y*b.y + a.z*b.z + a.w*b.w;
}

// ---- CSR: zero+count+scan fused (single block, 1024 threads) ---------------
__global__ __launch_bounds__(1024) void k_cnt(const int* __restrict__ dst,
                                              int* __restrict__ offsets,
                                              int* __restrict__ cursor){
  __shared__ int cnt[NN];
  __shared__ int s[1024];
  int t = threadIdx.x;
  for (int i = t; i < NN; i += 1024) cnt[i] = 0;
  __syncthreads();
  for (int e = t; e < NE; e += 1024) atomicAdd(&cnt[dst[e]], 1);
  __syncthreads();
  int a = (2*t   < NN) ? cnt[2*t  ] : 0;
  int b = (2*t+1 < NN) ? cnt[2*t+1] : 0;
  s[t] = a + b;
  __syncthreads();
  for (int off = 1; off < 1024; off <<= 1){
    int v = (t >= off) ? s[t-off] : 0;
    __syncthreads();
    s[t] += v;
    __syncthreads();
  }
  int base = (t > 0) ? s[t-1] : 0;
  if (2*t < NN){ offsets[2*t] = base; cursor[2*t] = base; }
  if (2*t+1 < NN){ offsets[2*t+1] = base + a; cursor[2*t+1] = base + a; }
  if (2*t == NN) offsets[NN] = base;
}

// ---- prepA: collapses [0,384) | W2->Bt [384,672) | W1->W1t [672,960) |
//             x_emb split [960,1094) | CSR fill [1094,1219) -----------------
// (fill role is parallel + uniform; depends on k_cnt which runs before)
__global__ __launch_bounds__(256) void k_prepA(
    const float* __restrict__ We1, const float* __restrict__ ae1,
    const float* __restrict__ W2,  const float* __restrict__ as2,
    const float* __restrict__ ad2, const float* __restrict__ We2,
    const float* __restrict__ ae2, const float* __restrict__ W1,
    const float* __restrict__ x_emb, const int* __restrict__ dst,
    float* __restrict__ we_a1, float* __restrict__ wa_s2,
    float* __restrict__ wa_d2, float* __restrict__ we_a2,
    unsigned short* __restrict__ Bh, unsigned short* __restrict__ Bl,
    unsigned short* __restrict__ W1th, unsigned short* __restrict__ W1tl,
    unsigned short* __restrict__ Xeh, unsigned short* __restrict__ Xel,
    int* __restrict__ cursor, int* __restrict__ csr){
  __shared__ __align__(16) float tile[64][65];
  int blk = blockIdx.x, t = threadIdx.x;
  if (blk < 384){
    int wid = blk*4 + (t >> 6);
    int lane = t & 63;
    bool lo32 = lane < 32;
    if (wid < 384){
      int kg = wid >> 2, h = wid & 3;
      int k0 = kg*8;
      const float4* ap = (const float4*)(ae1 + h*384);
      float4 a0 = ap[lane];
      float4 a1 = lo32 ? ap[64+lane] : make_float4(0,0,0,0);
      float res[8];
#pragma unroll
      for (int r = 0; r < 8; ++r){
        const float4* wr = (const float4*)(We1 + (size_t)(k0+r)*1536 + h*384);
        float s = dot4(wr[lane], a0);
        if (lo32) s += dot4(wr[64+lane], a1);
        res[r] = s;
      }
#pragma unroll
      for (int r = 0; r < 8; ++r) res[r] = wsum(res[r]);
      if (lane == 0){
#pragma unroll
        for (int r = 0; r < 8; ++r) we_a1[(k0+r)*4+h] = res[r];
      }
    } else if (wid < 768){
      int t2 = wid - 384;
      int kg = t2 >> 2, h = t2 & 3;
      int k0 = kg*4;
      const float4* s4 = (const float4*)(as2 + h*768);
      const float4* d4 = (const float4*)(ad2 + h*768);
      float4 sa[3], da[3];
#pragma unroll
      for (int i = 0; i < 3; ++i){ sa[i] = s4[i*64+lane]; da[i] = d4[i*64+lane]; }
      float r1[4], r2[4];
#pragma unroll
      for (int r = 0; r < 4; ++r){
        const float4* wr = (const float4*)(W2 + (size_t)(k0+r)*3072 + h*768);
        float s1 = 0.f, s2 = 0.f;
#pragma unroll
        for (int i = 0; i < 3; ++i){
          float4 w = wr[i*64+lane];
          s1 += dot4(w, sa[i]); s2 += dot4(w, da[i]);
        }
        r1[r] = s1; r2[r] = s2;
      }
#pragma unroll
      for (int r = 0; r < 4; ++r){ r1[r] = wsum(r1[r]); r2[r] = wsum(r2[r]); }
      if (lane == 0){
#pragma unroll
        for (int r = 0; r < 4; ++r){ wa_s2[(k0+r)*4+h] = r1[r]; wa_d2[(k0+r)*4+h] = r2[r]; }
      }
    } else {
      int t2 = wid - 768;
      int kg = t2 >> 2, h = t2 & 3;
      int k0 = kg*4;
      const float4* ap = (const float4*)(ae2 + h*768);
      float4 aa[3];
#pragma unroll
      for (int i = 0; i < 3; ++i) aa[i] = ap[i*64+lane];
      float res[4];
#pragma unroll
      for (int r = 0; r < 4; ++r){
        const float4* wr = (const float4*)(We2 + (size_t)(k0+r)*3072 + h*768);
        float s = 0.f;
#pragma unroll
        for (int i = 0; i < 3; ++i) s += dot4(wr[i*64+lane], aa[i]);
        res[r] = s;
      }
#pragma unroll
      for (int r = 0; r < 4; ++r) res[r] = wsum(res[r]);
      if (lane == 0){
#pragma unroll
        for (int r = 0; r < 4; ++r) we_a2[(k0+r)*4+h] = res[r];
      }
    }
  } else if (blk < 672){
    int idx = blk - 384;
    int bk = (idx % 24) * 64;
    int bc = (idx / 24) * 64;
    int cc = t & 63, kk4 = t >> 6;
#pragma unroll
    for (int i = 0; i < 16; ++i){
      int kk = kk4*16 + i;
      int k = bk + kk;
      int h = k / 384, kp = k - h*384;
      tile[kk][cc] = W2[(size_t)kp*3072 + h*768 + bc + cc];
    }
    __syncthreads();
    int kk2 = t & 63, cc4 = t >> 6;
#pragma unroll
    for (int i = 0; i < 16; ++i){
      int c2 = cc4*16 + i;
      float v = tile[kk2][c2];
      unsigned short hi = f2bf(v);
      unsigned short lo = f2bf(v - bf2f(hi));
      size_t o = (size_t)(bc + c2)*GK + bk + kk2;
      Bh[o] = hi; Bl[o] = lo;
    }
  } else if (blk < 960){
    int idx = blk - 672;
    int bkk = (idx % 12) * 64;
    int bcc = (idx / 12) * 64;
    int cc = t & 63, kk4 = t >> 6;
#pragma unroll
    for (int i = 0; i < 16; ++i){
      int kk = kk4*16 + i;
      tile[kk][cc] = W1[(size_t)(bkk+kk)*1536 + bcc + cc];
    }
    __syncthreads();
    int kk2 = t & 63, cc4 = t >> 6;
#pragma unroll
    for (int i = 0; i < 16; ++i){
      int c2 = cc4*16 + i;
      float v = tile[kk2][c2];
      unsigned short hi = f2bf(v);
      unsigned short lo = f2bf(v - bf2f(hi));
      size_t o = (size_t)(bcc + c2)*768 + bkk + kk2;
      W1th[o] = hi; W1tl[o] = lo;
    }
  } else if (blk < 1094){
    int i = (blk - 960)*256 + t;          // < 178*768/4 = 34176
    if (i < 34176){
      float4 v = ((const float4*)x_emb)[i];
      unsigned short h0 = f2bf(v.x), h1 = f2bf(v.y), h2 = f2bf(v.z), h3 = f2bf(v.w);
      ushort4 hh; hh.x = h0; hh.y = h1; hh.z = h2; hh.w = h3;
      ushort4 ll; ll.x = f2bf(v.x - bf2f(h0)); ll.y = f2bf(v.y - bf2f(h1));
      ll.z = f2bf(v.z - bf2f(h2)); ll.w = f2bf(v.w - bf2f(h3));
      ((ushort4*)Xeh)[i] = hh;
      ((ushort4*)Xel)[i] = ll;
    }
  } else {
    // CSR fill (parallel role; cursor valid since k_cnt completed earlier)
    int e = (blk - 1094)*256 + t;
    if (e < NE){
      int pz = atomicAdd(&cursor[dst[e]], 1);
      csr[pz] = e;
    }
  }
}

// ---- k_mmX: xh1 = Xe @ W1t^T  (f32 out, bf16 3-product MFMA) ---------------
__global__ __launch_bounds__(256) void k_mmX(const unsigned short* __restrict__ Ah,
                                             const unsigned short* __restrict__ Al,
                                             const unsigned short* __restrict__ Bh,
                                             const unsigned short* __restrict__ Bl,
                                             float* __restrict__ xh1){
  __shared__ __align__(16) unsigned short lds[2][4][64][64];
  int b = blockIdx.x;
  int bm = b / 24, bn = b % 24;
  int wave = threadIdx.x >> 6, lane = threadIdx.x & 63;
  int wm = wave >> 1, wn = wave & 1;
  int rl = lane & 15, kq = lane >> 4;

  int rt   = lane >> 3;
  int kswz = ((lane & 7) ^ rt) * 8;
  const unsigned short* sbase;
  int rowbase;
  if (wave == 0){ sbase = Ah; rowbase = bm*64; }
  else if (wave == 1){ sbase = Al; rowbase = bm*64; }
  else if (wave == 2){ sbase = Bh; rowbase = bn*64; }
  else { sbase = Bl; rowbase = bn*64; }
  bool isA = wave < 2;

  f32x4 acc[2][2] = {};

#pragma unroll
  for (int i = 0; i < 8; ++i){
    int row = rowbase + i*8 + rt;
    if (isA) row = (row < 178) ? row : 177;
    gload16(sbase + (size_t)row*768 + kswz, &lds[0][wave][i*8][0]);
  }
  __syncthreads();

  for (int t = 0; t < 12; ++t){
    int cur = t & 1;
    if (t < 11){
      int k0 = (t+1)*64;
#pragma unroll
      for (int i = 0; i < 8; ++i){
        int row = rowbase + i*8 + rt;
        if (isA) row = (row < 178) ? row : 177;
        gload16(sbase + (size_t)row*768 + k0 + kswz, &lds[cur^1][wave][i*8][0]);
      }
    }
#pragma unroll
    for (int ks = 0; ks < 2; ++ks){
      bf16x8 ah[2], al2[2], bh2[2], bl2[2];
#pragma unroll
      for (int i = 0; i < 2; ++i){
        int r = wm*32 + i*16 + rl;
        int sl = (ks*4 + kq) ^ (r & 7);
        ah[i]  = *(const bf16x8*)&lds[cur][0][r][sl*8];
        al2[i] = *(const bf16x8*)&lds[cur][1][r][sl*8];
      }
#pragma unroll
      for (int j = 0; j < 2; ++j){
        int cdx = wn*32 + j*16 + rl;
        int sl = (ks*4 + kq) ^ (cdx & 7);
        bh2[j] = *(const bf16x8*)&lds[cur][2][cdx][sl*8];
        bl2[j] = *(const bf16x8*)&lds[cur][3][cdx][sl*8];
      }
#pragma unroll
      for (int i = 0; i < 2; ++i){
#pragma unroll
        for (int j = 0; j < 2; ++j){
          acc[i][j] = __builtin_amdgcn_mfma_f32_16x16x32_bf16(ah[i],  bh2[j], acc[i][j], 0, 0, 0);
          acc[i][j] = __builtin_amdgcn_mfma_f32_16x16x32_bf16(ah[i],  bl2[j], acc[i][j], 0, 0, 0);
          acc[i][j] = __builtin_amdgcn_mfma_f32_16x16x32_bf16(al2[i], bh2[j], acc[i][j], 0, 0, 0);
        }
      }
    }
    __syncthreads();
  }

#pragma unroll
  for (int i = 0; i < 2; ++i){
#pragma unroll
    for (int j = 0; j < 2; ++j){
      int col = bn*64 + wn*32 + j*16 + rl;
#pragma unroll
      for (int r = 0; r < 4; ++r){
        int row = bm*64 + wm*32 + i*16 + kq*4 + r;
        if (row < 178) xh1[(size_t)row*1536 + col] = acc[i][j][r];
      }
    }
  }
}

// ---- prepB: XHt bf16 build + xa dots + ew dots + pad zero ------------------
__global__ __launch_bounds__(256) void k_prepB(
    const float* __restrict__ xh1,
    const float* __restrict__ as1, const float* __restrict__ ad1,
    const float* __restrict__ e_emb,
    const float* __restrict__ we_a1, const float* __restrict__ we_a2,
    unsigned short* __restrict__ XHh, unsigned short* __restrict__ XHl,
    float* __restrict__ xa_s1, float* __restrict__ xa_d1,
    float* __restrict__ ew1, float* __restrict__ ew2){
  int blk = blockIdx.x, t = threadIdx.x;
  if (blk < 178){
    int tok = blk;
    for (int i = t; i < 1536; i += 256){
      float v = xh1[(size_t)tok*1536 + i];
      int h = i / 384, c = i - h*384;
      size_t off = (size_t)c*K1 + h*192 + tok;
      unsigned short hi = f2bf(v);
      XHh[off] = hi; XHl[off] = f2bf(v - bf2f(hi));
    }
  } else if (blk < 356){
    int r = blk - 178;
    int h = t >> 6, lane = t & 63;
    const float4* p0 = (const float4*)(xh1 + (size_t)r*1536 + h*384);
    const float4* s4 = (const float4*)(as1 + h*384);
    const float4* d4 = (const float4*)(ad1 + h*384);
    float s1, s2;
    {
      float4 u = p0[lane], sa = s4[lane], da = d4[lane];
      s1 = dot4(u, sa); s2 = dot4(u, da);
    }
    if (lane < 32){
      float4 u = p0[64+lane], sa = s4[64+lane], da = d4[64+lane];
      s1 += dot4(u, sa); s2 += dot4(u, da);
    }
    s1 = wsum(s1); s2 = wsum(s2);
    if (lane == 0){ xa_s1[r*4+h] = s1; xa_d1[r*4+h] = s2; }
  } else if (blk < 392){
    int id = (blk - 356)*4 + (t >> 6);
    int lane = t & 63;
    const float* wv = (id < 72) ? we_a1 : we_a2;
    float* o = (id < 72) ? ew1 : ew2;
    int id2 = (id < 72) ? id : (id - 72);
    int r = id2 >> 2, h = id2 & 3;
    const float* ar = e_emb + (size_t)r*EMBD;
    float acc = 0.f;
    for (int k = lane; k < EMBD; k += 64) acc += ar[k] * wv[k*4+h];
    acc = wsum(acc);
    if (lane == 0) o[r*4+h] = acc;
  } else {
    int i = (blk - 392)*256 + t;               // < 384*4*14 = 21504
    if (i < 21504){
      int c = i / 56, rem = i - c*56;
      int h = rem / 14, tp = 178 + rem - h*14;
      size_t off = (size_t)c*K1 + h*192 + tp;
      XHh[off] = 0; XHl[off] = 0;
    }
  }
}

// ---- layer-1 softmax + token-coefficient build -> Q bf16 hi/lo -------------
__global__ __launch_bounds__(256) void k_gat1sm(const int* __restrict__ offsets,
                      int* __restrict__ csr, const int* __restrict__ srcv,
                      const int* __restrict__ x, const int* __restrict__ ea,
                      const float* __restrict__ xa_s1, const float* __restrict__ xa_d1,
                      const float* __restrict__ ew1, float* __restrict__ spill,
                      unsigned short* __restrict__ Qh, unsigned short* __restrict__ Ql){
  __shared__ float wts[DCAP][5];
  __shared__ int   sE[DCAP];
  __shared__ int   sA[DCAP], sB[DCAP];
  __shared__ float coef[K1];
  int n = blockIdx.x, t = threadIdx.x;
  int w = t >> 6, lane = t & 63;
  int lo = offsets[n], hi = offsets[n+1];
  int deg = hi - lo;
  bool big = deg > DCAP;

  if (!big){
    if (deg <= 64){
      if (w == 0){
        int v = (lane < deg) ? csr[lo+lane] : 0x7fffffff;
#pragma unroll
        for (int k = 2; k <= 64; k <<= 1){
#pragma unroll
          for (int j2 = k >> 1; j2 > 0; j2 >>= 1){
            int o = __shfl_xor(v, j2, 64);
            bool lower = (lane & j2) == 0;
            bool asc   = (lane & k) == 0;
            v = (lower == asc) ? min(v, o) : max(v, o);
          }
        }
        sE[lane] = v;
        if (lane < deg) csr[lo+lane] = v;
      }
    } else {
      int m = 1; while (m < deg) m <<= 1;
      for (int i = t; i < m; i += 256) sE[i] = (i < deg) ? csr[lo+i] : 0x7fffffff;
      __syncthreads();
      for (int k = 2; k <= m; k <<= 1){
        for (int j2 = k >> 1; j2 > 0; j2 >>= 1){
          for (int i = t; i < m; i += 256){
            int ixj = i ^ j2;
            if (ixj > i){
              int a = sE[i], b = sE[ixj];
              bool up = ((i & k) == 0);
              if ((a > b) == up){ sE[i] = b; sE[ixj] = a; }
            }
          }
          __syncthreads();
        }
      }
      for (int i = t; i < deg; i += 256) csr[lo+i] = sE[i];
    }
  } else {
    if (t == 0){
      for (int i = lo+1; i < hi; ++i){
        int v = csr[i], j = i-1;
        while (j >= lo && csr[j] > v){ csr[j+1] = csr[j]; --j; }
        csr[j+1] = v;
      }
    }
  }
  for (int i = t; i < K1; i += 256) coef[i] = 0.f;
  __syncthreads();

  int xn0 = x[2*n], xn1 = x[2*n+1];
  float ad_n = xa_d1[xn0*4+w] + xa_d1[xn1*4+w];
  float as_n = xa_s1[xn0*4+w] + xa_s1[xn1*4+w];
  float mx = -3.4e38f, sae = 0.f;
  float wlv;
  if (!big){
    for (int j = lane; j < deg; j += 64){
      int e = sE[j]; int s = srcv[e];
      int a = x[2*s], b = x[2*s+1];
      if (w == 0){ sA[j] = a; sB[j] = b; }
      float ae = ew1[ea[2*e]*4+w] + ew1[ea[2*e+1]*4+w];
      float al = (xa_s1[a*4+w] + xa_s1[b*4+w]) + ad_n + ae;
      al = (al > 0.f) ? al : NEG * al;
      wts[j][w] = al;
      sae += ae; mx = fmaxf(mx, al);
    }
    mx = wmax(mx); sae = wsum(sae);
    float all_ = as_n + ad_n + sae / fmaxf((float)deg, 1.f);
    all_ = (all_ > 0.f) ? all_ : NEG * all_;
    mx = fmaxf(mx, all_);
    float den = 0.f;
    for (int j = lane; j < deg; j += 64){
      float xx = expf(wts[j][w] - mx);
      wts[j][w] = xx; den += xx;
    }
    den = wsum(den);
    float exl = expf(all_ - mx);
    den += exl;
    float inv = 1.f / den;
    for (int j = lane; j < deg; j += 64) wts[j][w] *= inv;
    wlv = exl * inv;
  } else {
    for (int p = lo + lane; p < hi; p += 64){
      int e = csr[p]; int s = srcv[e];
      int a = x[2*s], b = x[2*s+1];
      float ae = ew1[ea[2*e]*4+w] + ew1[ea[2*e+1]*4+w];
      float al = (xa_s1[a*4+w] + xa_s1[b*4+w]) + ad_n + ae;
      al = (al > 0.f) ? al : NEG * al;
      spill[e*4 + w] = al;
      sae += ae; mx = fmaxf(mx, al);
    }
    mx = wmax(mx); sae = wsum(sae);
    float all_ = as_n + ad_n + sae / fmaxf((float)deg, 1.f);
    all_ = (all_ > 0.f) ? all_ : NEG * all_;
    mx = fmaxf(mx, all_);
    float den = 0.f;
    for (int p = lo + lane; p < hi; p += 64){
      int e = csr[p];
      float xx = expf(spill[e*4 + w] - mx);
      spill[e*4 + w] = xx; den += xx;
    }
    den = wsum(den);
    float exl = expf(all_ - mx);
    den += exl;
    float inv = 1.f / den;
    for (int p = lo + lane; p < hi; p += 64) spill[csr[p]*4 + w] *= inv;
    wlv = exl * inv;
  }
  __syncthreads();

  if (lane == 0){
    float* cf = coef + w*192;
    if (!big){
      for (int j = 0; j < deg; ++j){
        float wj = wts[j][w];
        cf[sA[j]] += wj; cf[sB[j]] += wj;
      }
    } else {
      for (int p = lo; p < hi; ++p){
        int e = csr[p]; int s = srcv[e];
        float wj = spill[e*4 + w];
        cf[x[2*s]] += wj; cf[x[2*s+1]] += wj;
      }
    }
    cf[xn0] += wlv; cf[xn1] += wlv;
  }
  __syncthreads();

  for (int i = t; i < K1; i += 256){
    float v = coef[i];
    unsigned short hi16 = f2bf(v);
    Qh[(size_t)n*K1 + i] = hi16;
    Ql[(size_t)n*K1 + i] = f2bf(v - bf2f(hi16));
  }
}

// ---- mm1: hact = relu(0.25*(Q @ XHt^T) + b1), bf16 3-product MFMA ----------
__global__ __launch_bounds__(256) void k_mm1(const unsigned short* __restrict__ Qh,
                                             const unsigned short* __restrict__ Ql,
                                             const unsigned short* __restrict__ XHh,
                                             const unsigned short* __restrict__ XHl,
                                             const float* __restrict__ b1,
                                             float* __restrict__ hact){
  __shared__ __align__(16) unsigned short lds[2][4][64][64];
  int b = blockIdx.x;
  int xcd = b & 7, idx = b >> 3;            // idx in [0,24)
  int bm = xcd*4 + idx/6, bn = idx % 6;
  int wave = threadIdx.x >> 6, lane = threadIdx.x & 63;
  int wm = wave >> 1, wn = wave & 1;
  int rl = lane & 15, kq = lane >> 4;

  int rt   = lane >> 3;
  int kswz = ((lane & 7) ^ rt) * 8;
  const unsigned short* sbase;
  int rowbase;
  if (wave == 0){ sbase = Qh; rowbase = bm*64; }
  else if (wave == 1){ sbase = Ql; rowbase = bm*64; }
  else if (wave == 2){ sbase = XHh; rowbase = bn*64; }
  else { sbase = XHl; rowbase = bn*64; }
  bool isA = wave < 2;

  f32x4 acc[2][2] = {};

#pragma unroll
  for (int i = 0; i < 8; ++i){
    int row = rowbase + i*8 + rt;
    if (isA) row = (row < GM) ? row : (GM-1);
    gload16(sbase + (size_t)row*K1 + kswz, &lds[0][wave][i*8][0]);
  }
  __syncthreads();

  for (int t = 0; t < 12; ++t){
    int cur = t & 1;
    if (t < 11){
      int k0 = (t+1)*64;
#pragma unroll
      for (int i = 0; i < 8; ++i){
        int row = rowbase + i*8 + rt;
        if (isA) row = (row < GM) ? row : (GM-1);
        gload16(sbase + (size_t)row*K1 + k0 + kswz, &lds[cur^1][wave][i*8][0]);
      }
    }
#pragma unroll
    for (int ks = 0; ks < 2; ++ks){
      bf16x8 ah[2], al2[2], bh2[2], bl2[2];
#pragma unroll
      for (int i = 0; i < 2; ++i){
        int r = wm*32 + i*16 + rl;
        int sl = (ks*4 + kq) ^ (r & 7);
        ah[i]  = *(const bf16x8*)&lds[cur][0][r][sl*8];
        al2[i] = *(const bf16x8*)&lds[cur][1][r][sl*8];
      }
#pragma unroll
      for (int j = 0; j < 2; ++j){
        int cdx = wn*32 + j*16 + rl;
        int sl = (ks*4 + kq) ^ (cdx & 7);
        bh2[j] = *(const bf16x8*)&lds[cur][2][cdx][sl*8];
        bl2[j] = *(const bf16x8*)&lds[cur][3][cdx][sl*8];
      }
#pragma unroll
      for (int i = 0; i < 2; ++i){
#pragma unroll
        for (int j = 0; j < 2; ++j){
          acc[i][j] = __builtin_amdgcn_mfma_f32_16x16x32_bf16(ah[i],  bh2[j], acc[i][j], 0, 0, 0);
          acc[i][j] = __builtin_amdgcn_mfma_f32_16x16x32_bf16(ah[i],  bl2[j], acc[i][j], 0, 0, 0);
          acc[i][j] = __builtin_amdgcn_mfma_f32_16x16x32_bf16(al2[i], bh2[j], acc[i][j], 0, 0, 0);
        }
      }
    }
    __syncthreads();
  }

#pragma unroll
  for (int i = 0; i < 2; ++i){
#pragma unroll
    for (int j = 0; j < 2; ++j){
      int col = bn*64 + wn*32 + j*16 + rl;
      float bb = b1[col];
#pragma unroll
      for (int r = 0; r < 4; ++r){
        int row = bm*64 + wm*32 + i*16 + kq*4 + r;
        if (row < GM) hact[(size_t)row*HID + col] = fmaxf(0.25f*acc[i][j][r] + bb, 0.f);
      }
    }
  }
}

// ---- k_dots: asrc2/adst2 = hact row-dots with wa_s2/wa_d2 ------------------
__global__ __launch_bounds__(256) void k_dots(const float* __restrict__ hact,
                      const float* __restrict__ wa_s2, const float* __restrict__ wa_d2,
                      float* __restrict__ asrc2, float* __restrict__ adst2){
  int w = threadIdx.x >> 6, lane = threadIdx.x & 63;
  int n = blockIdx.x*4 + w;
  float pr[8] = {};
#pragma unroll
  for (int i = 0; i < 6; ++i){
    int c = i*64 + lane;
    float v = hact[(size_t)n*HID + c];
#pragma unroll
    for (int h = 0; h < 4; ++h){
      pr[h]   += v * wa_s2[c*4+h];
      pr[4+h] += v * wa_d2[c*4+h];
    }
  }
#pragma unroll
  for (int o = 32; o > 0; o >>= 1){
#pragma unroll
    for (int q = 0; q < 8; ++q) pr[q] += __shfl_xor(pr[q], o, 64);
  }
  if (lane == 0){
#pragma unroll
    for (int h = 0; h < 4; ++h){ asrc2[n*4+h] = pr[h]; adst2[n*4+h] = pr[4+h]; }
  }
}

// ---- layer-2 fused: on-the-fly alphas + softmax + pipelined agg -> G -------
__global__ __launch_bounds__(384) void k_gat2(const int* __restrict__ offsets,
                      const int* __restrict__ csr, const int* __restrict__ srcv,
                      const int* __restrict__ ea,
                      const float* __restrict__ asrc, const float* __restrict__ adst,
                      const float* __restrict__ ew2,
                      const float* __restrict__ hact, float* __restrict__ spill,
                      unsigned short* __restrict__ Gh, unsigned short* __restrict__ Gl){
  __shared__ float wts[DCAP][5];
  __shared__ int   ssrc[DCAP];
  __shared__ float wl[4];
  int n = blockIdx.x, t = threadIdx.x;
  int w = t >> 6, lane = t & 63;
  int lo = offsets[n], hi = offsets[n+1];
  int deg = hi - lo;
  bool big = deg > DCAP;
  if (w < 4){
    float ad_n = adst[n*NH + w];
    float as_n = asrc[n*NH + w];
    float mx = -3.4e38f, sae = 0.f;
    if (!big){
      for (int p = lo + lane; p < hi; p += 64){
        int e = csr[p]; int s = srcv[e];
        if (w == 0) ssrc[p - lo] = s;
        float ae = ew2[ea[2*e]*4+w] + ew2[ea[2*e+1]*4+w];
        float al = asrc[s*NH + w] + ad_n + ae;
        al = (al > 0.f) ? al : NEG * al;
        wts[p - lo][w] = al;
        sae += ae; mx = fmaxf(mx, al);
      }
      mx = wmax(mx); sae = wsum(sae);
      float all_ = as_n + ad_n + sae / fmaxf((float)deg, 1.f);
      all_ = (all_ > 0.f) ? all_ : NEG * all_;
      mx = fmaxf(mx, all_);
      float den = 0.f;
      for (int p = lo + lane; p < hi; p += 64){
        float xx = expf(wts[p - lo][w] - mx);
        wts[p - lo][w] = xx; den += xx;
      }
      den = wsum(den);
      float exl = expf(all_ - mx);
      den += exl;
      float inv = 1.f / den;
      for (int p = lo + lane; p < hi; p += 64) wts[p - lo][w] *= inv;
      if (lane == 0) wl[w] = exl * inv;
    } else {
      for (int p = lo + lane; p < hi; p += 64){
        int e = csr[p];
        float ae = ew2[ea[2*e]*4+w] + ew2[ea[2*e+1]*4+w];
        float al = asrc[srcv[e]*NH + w] + ad_n + ae;
        al = (al > 0.f) ? al : NEG * al;
        spill[e*4 + w] = al;
        sae += ae; mx = fmaxf(mx, al);
      }
      mx = wmax(mx); sae = wsum(sae);
      float all_ = as_n + ad_n + sae / fmaxf((float)deg, 1.f);
      all_ = (all_ > 0.f) ? all_ : NEG * all_;
      mx = fmaxf(mx, all_);
      float den = 0.f;
      for (int p = lo + lane; p < hi; p += 64){
        int e = csr[p];
        float xx = expf(spill[e*4 + w] - mx);
        spill[e*4 + w] = xx; den += xx;
      }
      den = wsum(den);
      float exl = expf(all_ - mx);
      den += exl;
      float inv = 1.f / den;
      for (int p = lo + lane; p < hi; p += 64) spill[csr[p]*4 + w] *= inv;
      if (lane == 0) wl[w] = exl * inv;
    }
  }
  __syncthreads();

  int c = t;
  float a0 = 0.f, a1 = 0.f, a2 = 0.f, a3 = 0.f;
  if (!big){
    float vnext = 0.f;
    if (deg > 0) vnext = hact[(size_t)ssrc[0]*HID + c];
    for (int j = 0; j < deg; ++j){
      float vc = vnext;
      if (j+1 < deg) vnext = hact[(size_t)ssrc[j+1]*HID + c];
      float w0=wts[j][0], w1=wts[j][1], w2=wts[j][2], w3=wts[j][3];
      a0 += w0*vc; a1 += w1*vc; a2 += w2*vc; a3 += w3*vc;
    }
  } else {
    for (int j = 0; j < deg; ++j){
      int e = csr[lo+j]; int s = srcv[e];
      float w0 = spill[e*4+0], w1 = spill[e*4+1], w2 = spill[e*4+2], w3 = spill[e*4+3];
      float vc = hact[(size_t)s*HID + c];
      a0 += w0*vc; a1 += w1*vc; a2 += w2*vc; a3 += w3*vc;
    }
  }
  {
    float vc = hact[(size_t)n*HID + c];
    a0 += wl[0]*vc; a1 += wl[1]*vc; a2 += wl[2]*vc; a3 += wl[3]*vc;
  }
  size_t base = (size_t)n*GK + c;
  float vv[4] = {a0, a1, a2, a3};
#pragma unroll
  for (int h = 0; h < 4; ++h){
    unsigned short hi16 = f2bf(vv[h]);
    unsigned short lo16 = f2bf(vv[h] - bf2f(hi16));
    Gh[base + h*384] = hi16;
    Gl[base + h*384] = lo16;
  }
}

// ---- layer-2 MFMA GEMM: LDS-staged, double-buffered, XOR-swizzled ----------
__global__ __launch_bounds__(256) void k_mm2(const unsigned short* __restrict__ Gh,
                                             const unsigned short* __restrict__ Gl,
                                             const unsigned short* __restrict__ Bh,
                                             const unsigned short* __restrict__ Bl,
                                             const float* __restrict__ b2,
                                             float* __restrict__ out){
  __shared__ __align__(16) unsigned short lds[2][4][64][64];
  int b = blockIdx.x;
  int xcd = b & 7, idx = b >> 3;
  int bm = xcd*4 + idx/12, bn = idx % 12;
  int wave = threadIdx.x >> 6, lane = threadIdx.x & 63;
  int wm = wave >> 1, wn = wave & 1;
  int rl = lane & 15, kq = lane >> 4;

  int rt   = lane >> 3;
  int kswz = ((lane & 7) ^ rt) * 8;
  const unsigned short* sbase;
  int rowbase;
  if (wave == 0){ sbase = Gh; rowbase = bm*64; }
  else if (wave == 1){ sbase = Gl; rowbase = bm*64; }
  else if (wave == 2){ sbase = Bh; rowbase = bn*64; }
  else { sbase = Bl; rowbase = bn*64; }
  bool isA = wave < 2;

  f32x4 acc[2][2] = {};

#pragma unroll
  for (int i = 0; i < 8; ++i){
    int row = rowbase + i*8 + rt;
    if (isA) row = (row < GM) ? row : (GM-1);
    gload16(sbase + (size_t)row*GK + kswz, &lds[0][wave][i*8][0]);
  }
  __syncthreads();

  for (int t = 0; t < 24; ++t){
    int cur = t & 1;
    if (t < 23){
      int k0 = (t+1)*64;
#pragma unroll
      for (int i = 0; i < 8; ++i){
        int row = rowbase + i*8 + rt;
        if (isA) row = (row < GM) ? row : (GM-1);
        gload16(sbase + (size_t)row*GK + k0 + kswz, &lds[cur^1][wave][i*8][0]);
      }
    }
#pragma unroll
    for (int ks = 0; ks < 2; ++ks){
      bf16x8 ah[2], al2[2], bh2[2], bl2[2];
#pragma unroll
      for (int i = 0; i < 2; ++i){
        int r = wm*32 + i*16 + rl;
        int sl = (ks*4 + kq) ^ (r & 7);
        ah[i]  = *(const bf16x8*)&lds[cur][0][r][sl*8];
        al2[i] = *(const bf16x8*)&lds[cur][1][r][sl*8];
      }
#pragma unroll
      for (int j = 0; j < 2; ++j){
        int cdx = wn*32 + j*16 + rl;
        int sl = (ks*4 + kq) ^ (cdx & 7);
        bh2[j] = *(const bf16x8*)&lds[cur][2][cdx][sl*8];
        bl2[j] = *(const bf16x8*)&lds[cur][3][cdx][sl*8];
      }
#pragma unroll
      for (int i = 0; i < 2; ++i){
#pragma unroll
        for (int j = 0; j < 2; ++j){
          acc[i][j] = __builtin_amdgcn_mfma_f32_16x16x32_bf16(ah[i],  bh2[j], acc[i][j], 0, 0, 0);
          acc[i][j] = __builtin_amdgcn_mfma_f32_16x16x32_bf16(ah[i],  bl2[j], acc[i][j], 0, 0, 0);
          acc[i][j] = __builtin_amdgcn_mfma_f32_16x16x32_bf16(al2[i], bh2[j], acc[i][j], 0, 0, 0);
        }
      }
    }
    __syncthreads();
  }

#pragma unroll
  for (int i = 0; i < 2; ++i){
#pragma unroll
    for (int j = 0; j < 2; ++j){
      int col = bn*64 + wn*32 + j*16 + rl;
      float bb = b2[col];
#pragma unroll
      for (int r = 0; r < 4; ++r){
        int row = bm*64 + wm*32 + i*16 + kq*4 + r;
        if (row < GM) out[(size_t)row*GN + col] = 0.25f*acc[i][j][r] + bb;
      }
    }
  }
}

// ---------------------------------------------------------------------------
extern "C" void kernel_launch(void* const* d_in, const int* in_sizes, int n_in,
                              void* d_out, int out_size, void* d_ws, size_t ws_size,
                              hipStream_t stream){
  const int*   x     = (const int*)d_in[0];
  const int*   ei    = (const int*)d_in[1];
  const int*   ea    = (const int*)d_in[2];
  const float* x_emb = (const float*)d_in[3];
  const float* e_emb = (const float*)d_in[4];
  const float* W1    = (const float*)d_in[5];
  const float* as1   = (const float*)d_in[6];
  const float* ad1   = (const float*)d_in[7];
  const float* We1   = (const float*)d_in[8];
  const float* ae1   = (const float*)d_in[9];
  const float* b1    = (const float*)d_in[10];
  const float* W2    = (const float*)d_in[11];
  const float* as2   = (const float*)d_in[12];
  const float* ad2   = (const float*)d_in[13];
  const float* We2   = (const float*)d_in[14];
  const float* ae2   = (const float*)d_in[15];
  const float* b2    = (const float*)d_in[16];
  const int* srcv = ei;
  const int* dstv = ei + NE;
  float* out = (float*)d_out;

  char* p = (char*)d_ws;
  auto take = [&](size_t n){ void* q = (void*)p; p += (n + 255) & ~(size_t)255; return q; };
  int*   cursor  = (int*)take(NN*4);
  int*   offsets = (int*)take((NN+1)*4);
  int*   csr     = (int*)take(NE*4);
  float* we_a1   = (float*)take(EMBD*NH*4);
  float* wa_s2   = (float*)take(HID*NH*4);
  float* wa_d2   = (float*)take(HID*NH*4);
  float* we_a2   = (float*)take(EMBD*NH*4);
  float* xa_s1   = (float*)take(178*NH*4);
  float* xa_d1   = (float*)take(178*NH*4);
  float* ew1     = (float*)take(18*NH*4);
  float* ew2     = (float*)take(18*NH*4);
  float* xh1     = (float*)take((size_t)178*1536*4);
  unsigned short* Xeh  = (unsigned short*)take((size_t)178*768*2);
  unsigned short* Xel  = (unsigned short*)take((size_t)178*768*2);
  unsigned short* W1th = (unsigned short*)take((size_t)1536*768*2);
  unsigned short* W1tl = (unsigned short*)take((size_t)1536*768*2);
  unsigned short* XHh  = (unsigned short*)take((size_t)HID*K1*2);
  unsigned short* XHl  = (unsigned short*)take((size_t)HID*K1*2);
  unsigned short* Qh   = (unsigned short*)take((size_t)NN*K1*2);
  unsigned short* Ql   = (unsigned short*)take((size_t)NN*K1*2);
  unsigned short* Bth  = (unsigned short*)take((size_t)GN*GK*2);
  unsigned short* Btl  = (unsigned short*)take((size_t)GN*GK*2);
  unsigned short* Gh   = (unsigned short*)take((size_t)GM*GK*2);
  unsigned short* Gl   = (unsigned short*)take((size_t)GM*GK*2);
  float* spill   = (float*)take((size_t)NE*NH*4);
  float* hact    = (float*)take((size_t)NN*HID*4);
  float* asrc2   = (float*)take(NN*NH*4);
  float* adst2   = (float*)take(NN*NH*4);

  // CSR count/scan (1 block, 1024 thr)
  k_cnt<<<1, 1024, 0, stream>>>(dstv, offsets, cursor);

  // prep (fused uniform roles) + CSR fill role (cursor ready from k_cnt)
  k_prepA<<<1219, 256, 0, stream>>>(We1, ae1, W2, as2, ad2, We2, ae2, W1,
                                    x_emb, dstv, we_a1, wa_s2, wa_d2, we_a2,
                                    Bth, Btl, W1th, W1tl, Xeh, Xel,
                                    cursor, csr);
  k_mmX<<<72, 256, 0, stream>>>(Xeh, Xel, W1th, W1tl, xh1);
  k_prepB<<<476, 256, 0, stream>>>(xh1, as1, ad1, e_emb, we_a1, we_a2,
                                   XHh, XHl, xa_s1, xa_d1, ew1, ew2);

  // layer 1: softmax + token-coefficient build -> Q; hact via MFMA; dots
  k_gat1sm<<<NN, 256, 0, stream>>>(offsets, csr, srcv, x, ea, xa_s1, xa_d1,
                                   ew1, spill, Qh, Ql);
  k_mm1<<<192, 256, 0, stream>>>(Qh, Ql, XHh, XHl, b1, hact);
  k_dots<<<500, 256, 0, stream>>>(hact, wa_s2, wa_d2, asrc2, adst2);

  // layer 2 fused agg-first -> G (bf16 hi/lo)
  k_gat2<<<NN, 384, 0, stream>>>(offsets, csr, srcv, ea, asrc2, adst2, ew2,
                                 hact, spill, Gh, Gl);

  // out = 0.25*(G @ Bt^T) + b2 via LDS-staged bf16 3-product MFMA
  k_mm2<<<384, 256, 0, stream>>>(Gh, Gl, Bth, Btl, b2, out);
}

// Round 19
// 112.179 us; speedup vs baseline: 1.2206x; 1.0430x over previous
//
#include <hip/hip_runtime.h>
#include <hip/hip_bf16.h>

#define NN   2000
#define NE   32000
#define EMBD 768
#define NH   4
#define HID  384
#define NEG  0.2f
#define DCAP 128

#define GM 2000
#define GN 768
#define GK 1536
#define K1 768          // mm1/mmX K

typedef __bf16 bf16x8 __attribute__((ext_vector_type(8)));
typedef float  f32x4  __attribute__((ext_vector_type(4)));

__device__ inline float wsum(float v){
#pragma unroll
  for (int o = 32; o > 0; o >>= 1) v += __shfl_xor(v, o, 64);
  return v;
}
__device__ inline float wmax(float v){
#pragma unroll
  for (int o = 32; o > 0; o >>= 1) v = fmaxf(v, __shfl_xor(v, o, 64));
  return v;
}

__device__ inline unsigned short f2bf(float f){
  unsigned u = __float_as_uint(f);
  unsigned r = (u + 0x7FFFu + ((u >> 16) & 1u)) >> 16;
  return (unsigned short)r;
}
__device__ inline float bf2f(unsigned short h){
  return __uint_as_float(((unsigned)h) << 16);
}

__device__ inline void gload16(const void* g, void* l){
  __builtin_amdgcn_global_load_lds((const __attribute__((address_space(1))) void*)g,
                                   (__attribute__((address_space(3))) void*)l, 16, 0, 0);
}
__device__ inline float dot4(float4 a, float4 b){
  return a.x*b.x + a.y*b.y + a.z*b.z + a.w*b.w;
}

// ---- CSR: zero+count+scan fused (single block, 1024 threads) ---------------
__global__ __launch_bounds__(1024) void k_cnt(const int* __restrict__ dst,
                                              int* __restrict__ offsets,
                                              int* __restrict__ cursor){
  __shared__ int cnt[NN];
  __shared__ int s[1024];
  int t = threadIdx.x;
  for (int i = t; i < NN; i += 1024) cnt[i] = 0;
  __syncthreads();
  for (int e = t; e < NE; e += 1024) atomicAdd(&cnt[dst[e]], 1);
  __syncthreads();
  int a = (2*t   < NN) ? cnt[2*t  ] : 0;
  int b = (2*t+1 < NN) ? cnt[2*t+1] : 0;
  s[t] = a + b;
  __syncthreads();
  for (int off = 1; off < 1024; off <<= 1){
    int v = (t >= off) ? s[t-off] : 0;
    __syncthreads();
    s[t] += v;
    __syncthreads();
  }
  int base = (t > 0) ? s[t-1] : 0;
  if (2*t < NN){ offsets[2*t] = base; cursor[2*t] = base; }
  if (2*t+1 < NN){ offsets[2*t+1] = base + a; cursor[2*t+1] = base + a; }
  if (2*t == NN) offsets[NN] = base;
}

// ---- prepA: collapses [0,384) | W1 dual collapse [384,480) |
//   W2->Bt [480,768) | W1->W1t [768,1056) | x_emb split [1056,1190) |
//   XH pad-zero [1190,1274) | CSR fill [1274,1399) --------------------------
__global__ __launch_bounds__(256) void k_prepA(
    const float* __restrict__ We1, const float* __restrict__ ae1,
    const float* __restrict__ W2,  const float* __restrict__ as2,
    const float* __restrict__ ad2, const float* __restrict__ We2,
    const float* __restrict__ ae2, const float* __restrict__ W1,
    const float* __restrict__ as1, const float* __restrict__ ad1,
    const float* __restrict__ x_emb, const int* __restrict__ dst,
    float* __restrict__ we_a1, float* __restrict__ wa_s2,
    float* __restrict__ wa_d2, float* __restrict__ we_a2,
    float* __restrict__ wa_s1, float* __restrict__ wa_d1,
    unsigned short* __restrict__ Bh, unsigned short* __restrict__ Bl,
    unsigned short* __restrict__ W1th, unsigned short* __restrict__ W1tl,
    unsigned short* __restrict__ Xeh, unsigned short* __restrict__ Xel,
    unsigned short* __restrict__ XHh, unsigned short* __restrict__ XHl,
    int* __restrict__ cursor, int* __restrict__ csr){
  __shared__ __align__(16) float tile[64][65];
  int blk = blockIdx.x, t = threadIdx.x;
  if (blk < 384){
    int wid = blk*4 + (t >> 6);
    int lane = t & 63;
    bool lo32 = lane < 32;
    if (wid < 384){
      int kg = wid >> 2, h = wid & 3;
      int k0 = kg*8;
      const float4* ap = (const float4*)(ae1 + h*384);
      float4 a0 = ap[lane];
      float4 a1 = lo32 ? ap[64+lane] : make_float4(0,0,0,0);
      float res[8];
#pragma unroll
      for (int r = 0; r < 8; ++r){
        const float4* wr = (const float4*)(We1 + (size_t)(k0+r)*1536 + h*384);
        float s = dot4(wr[lane], a0);
        if (lo32) s += dot4(wr[64+lane], a1);
        res[r] = s;
      }
#pragma unroll
      for (int r = 0; r < 8; ++r) res[r] = wsum(res[r]);
      if (lane == 0){
#pragma unroll
        for (int r = 0; r < 8; ++r) we_a1[(k0+r)*4+h] = res[r];
      }
    } else if (wid < 768){
      int t2 = wid - 384;
      int kg = t2 >> 2, h = t2 & 3;
      int k0 = kg*4;
      const float4* s4 = (const float4*)(as2 + h*768);
      const float4* d4 = (const float4*)(ad2 + h*768);
      float4 sa[3], da[3];
#pragma unroll
      for (int i = 0; i < 3; ++i){ sa[i] = s4[i*64+lane]; da[i] = d4[i*64+lane]; }
      float r1[4], r2[4];
#pragma unroll
      for (int r = 0; r < 4; ++r){
        const float4* wr = (const float4*)(W2 + (size_t)(k0+r)*3072 + h*768);
        float s1 = 0.f, s2 = 0.f;
#pragma unroll
        for (int i = 0; i < 3; ++i){
          float4 w = wr[i*64+lane];
          s1 += dot4(w, sa[i]); s2 += dot4(w, da[i]);
        }
        r1[r] = s1; r2[r] = s2;
      }
#pragma unroll
      for (int r = 0; r < 4; ++r){ r1[r] = wsum(r1[r]); r2[r] = wsum(r2[r]); }
      if (lane == 0){
#pragma unroll
        for (int r = 0; r < 4; ++r){ wa_s2[(k0+r)*4+h] = r1[r]; wa_d2[(k0+r)*4+h] = r2[r]; }
      }
    } else {
      int t2 = wid - 768;
      int kg = t2 >> 2, h = t2 & 3;
      int k0 = kg*4;
      const float4* ap = (const float4*)(ae2 + h*768);
      float4 aa[3];
#pragma unroll
      for (int i = 0; i < 3; ++i) aa[i] = ap[i*64+lane];
      float res[4];
#pragma unroll
      for (int r = 0; r < 4; ++r){
        const float4* wr = (const float4*)(We2 + (size_t)(k0+r)*3072 + h*768);
        float s = 0.f;
#pragma unroll
        for (int i = 0; i < 3; ++i) s += dot4(wr[i*64+lane], aa[i]);
        res[r] = s;
      }
#pragma unroll
      for (int r = 0; r < 4; ++r) res[r] = wsum(res[r]);
      if (lane == 0){
#pragma unroll
        for (int r = 0; r < 4; ++r) we_a2[(k0+r)*4+h] = res[r];
      }
    }
  } else if (blk < 480){
    // W1 dual collapse: wa_s1[h][k] = sum_c W1[k][h*384+c]*as1[h*384+c]
    int wid = (blk-384)*4 + (t >> 6);     // 0..383
    int lane = t & 63;
    bool lo32 = lane < 32;
    int kg = wid >> 2, h = wid & 3;
    int k0 = kg*8;
    const float4* sp = (const float4*)(as1 + h*384);
    const float4* dp = (const float4*)(ad1 + h*384);
    float4 sa0 = sp[lane];
    float4 sa1 = lo32 ? sp[64+lane] : make_float4(0,0,0,0);
    float4 da0 = dp[lane];
    float4 da1 = lo32 ? dp[64+lane] : make_float4(0,0,0,0);
    float r1[8], r2[8];
#pragma unroll
    for (int r = 0; r < 8; ++r){
      const float4* wr = (const float4*)(W1 + (size_t)(k0+r)*1536 + h*384);
      float4 w0 = wr[lane];
      float s1 = dot4(w0, sa0);
      float s2 = dot4(w0, da0);
      if (lo32){
        float4 w1 = wr[64+lane];
        s1 += dot4(w1, sa1); s2 += dot4(w1, da1);
      }
      r1[r] = s1; r2[r] = s2;
    }
#pragma unroll
    for (int r = 0; r < 8; ++r){ r1[r] = wsum(r1[r]); r2[r] = wsum(r2[r]); }
    if (lane == 0){
#pragma unroll
      for (int r = 0; r < 8; ++r){
        wa_s1[h*768 + k0 + r] = r1[r];
        wa_d1[h*768 + k0 + r] = r2[r];
      }
    }
  } else if (blk < 768){
    int idx = blk - 480;
    int bk = (idx % 24) * 64;
    int bc = (idx / 24) * 64;
    int cc = t & 63, kk4 = t >> 6;
#pragma unroll
    for (int i = 0; i < 16; ++i){
      int kk = kk4*16 + i;
      int k = bk + kk;
      int h = k / 384, kp = k - h*384;
      tile[kk][cc] = W2[(size_t)kp*3072 + h*768 + bc + cc];
    }
    __syncthreads();
    int kk2 = t & 63, cc4 = t >> 6;
#pragma unroll
    for (int i = 0; i < 16; ++i){
      int c2 = cc4*16 + i;
      float v = tile[kk2][c2];
      unsigned short hi = f2bf(v);
      unsigned short lo = f2bf(v - bf2f(hi));
      size_t o = (size_t)(bc + c2)*GK + bk + kk2;
      Bh[o] = hi; Bl[o] = lo;
    }
  } else if (blk < 1056){
    int idx = blk - 768;
    int bkk = (idx % 12) * 64;
    int bcc = (idx / 12) * 64;
    int cc = t & 63, kk4 = t >> 6;
#pragma unroll
    for (int i = 0; i < 16; ++i){
      int kk = kk4*16 + i;
      tile[kk][cc] = W1[(size_t)(bkk+kk)*1536 + bcc + cc];
    }
    __syncthreads();
    int kk2 = t & 63, cc4 = t >> 6;
#pragma unroll
    for (int i = 0; i < 16; ++i){
      int c2 = cc4*16 + i;
      float v = tile[kk2][c2];
      unsigned short hi = f2bf(v);
      unsigned short lo = f2bf(v - bf2f(hi));
      size_t o = (size_t)(bcc + c2)*768 + bkk + kk2;
      W1th[o] = hi; W1tl[o] = lo;
    }
  } else if (blk < 1190){
    int i = (blk - 1056)*256 + t;          // < 178*768/4 = 34176
    if (i < 34176){
      float4 v = ((const float4*)x_emb)[i];
      unsigned short h0 = f2bf(v.x), h1 = f2bf(v.y), h2 = f2bf(v.z), h3 = f2bf(v.w);
      ushort4 hh; hh.x = h0; hh.y = h1; hh.z = h2; hh.w = h3;
      ushort4 ll; ll.x = f2bf(v.x - bf2f(h0)); ll.y = f2bf(v.y - bf2f(h1));
      ll.z = f2bf(v.z - bf2f(h2)); ll.w = f2bf(v.w - bf2f(h3));
      ((ushort4*)Xeh)[i] = hh;
      ((ushort4*)Xel)[i] = ll;
    }
  } else if (blk < 1274){
    // XH pad-zero: tokens 178..191 (disjoint from mmX's writes)
    int i = (blk - 1190)*256 + t;          // < 384*4*14 = 21504
    if (i < 21504){
      int c = i / 56, rem = i - c*56;
      int h = rem / 14, tp = 178 + rem - h*14;
      size_t off = (size_t)c*K1 + h*192 + tp;
      XHh[off] = 0; XHl[off] = 0;
    }
  } else {
    // CSR fill (cursor valid since k_cnt completed earlier)
    int e = (blk - 1274)*256 + t;
    if (e < NE){
      int pz = atomicAdd(&cursor[dst[e]], 1);
      csr[pz] = e;
    }
  }
}

// ---- k_mmX: XHt = (Xe @ W1t^T) transposed+split [0,72) |
//             xa dots [72,250) | ew dots [250,286) --------------------------
__global__ __launch_bounds__(256) void k_mmX(const unsigned short* __restrict__ Ah,
                                             const unsigned short* __restrict__ Al,
                                             const unsigned short* __restrict__ Bh,
                                             const unsigned short* __restrict__ Bl,
                                             const float* __restrict__ x_emb,
                                             const float* __restrict__ e_emb,
                                             const float* __restrict__ wa_s1,
                                             const float* __restrict__ wa_d1,
                                             const float* __restrict__ we_a1,
                                             const float* __restrict__ we_a2,
                                             unsigned short* __restrict__ XHh,
                                             unsigned short* __restrict__ XHl,
                                             float* __restrict__ xa_s1,
                                             float* __restrict__ xa_d1,
                                             float* __restrict__ ew1,
                                             float* __restrict__ ew2){
  __shared__ __align__(16) unsigned short lds[2][4][64][64];
  int blk = blockIdx.x;
  if (blk < 72){
    int b = blk;
    int bm = b / 24, bn = b % 24;
    int wave = threadIdx.x >> 6, lane = threadIdx.x & 63;
    int wm = wave >> 1, wn = wave & 1;
    int rl = lane & 15, kq = lane >> 4;

    int rt   = lane >> 3;
    int kswz = ((lane & 7) ^ rt) * 8;
    const unsigned short* sbase;
    int rowbase;
    if (wave == 0){ sbase = Ah; rowbase = bm*64; }
    else if (wave == 1){ sbase = Al; rowbase = bm*64; }
    else if (wave == 2){ sbase = Bh; rowbase = bn*64; }
    else { sbase = Bl; rowbase = bn*64; }
    bool isA = wave < 2;

    f32x4 acc[2][2] = {};

#pragma unroll
    for (int i = 0; i < 8; ++i){
      int row = rowbase + i*8 + rt;
      if (isA) row = (row < 178) ? row : 177;
      gload16(sbase + (size_t)row*768 + kswz, &lds[0][wave][i*8][0]);
    }
    __syncthreads();

    for (int t = 0; t < 12; ++t){
      int cur = t & 1;
      if (t < 11){
        int k0 = (t+1)*64;
#pragma unroll
        for (int i = 0; i < 8; ++i){
          int row = rowbase + i*8 + rt;
          if (isA) row = (row < 178) ? row : 177;
          gload16(sbase + (size_t)row*768 + k0 + kswz, &lds[cur^1][wave][i*8][0]);
        }
      }
#pragma unroll
      for (int ks = 0; ks < 2; ++ks){
        bf16x8 ah[2], al2[2], bh2[2], bl2[2];
#pragma unroll
        for (int i = 0; i < 2; ++i){
          int r = wm*32 + i*16 + rl;
          int sl = (ks*4 + kq) ^ (r & 7);
          ah[i]  = *(const bf16x8*)&lds[cur][0][r][sl*8];
          al2[i] = *(const bf16x8*)&lds[cur][1][r][sl*8];
        }
#pragma unroll
        for (int j = 0; j < 2; ++j){
          int cdx = wn*32 + j*16 + rl;
          int sl = (ks*4 + kq) ^ (cdx & 7);
          bh2[j] = *(const bf16x8*)&lds[cur][2][cdx][sl*8];
          bl2[j] = *(const bf16x8*)&lds[cur][3][cdx][sl*8];
        }
#pragma unroll
        for (int i = 0; i < 2; ++i){
#pragma unroll
          for (int j = 0; j < 2; ++j){
            acc[i][j] = __builtin_amdgcn_mfma_f32_16x16x32_bf16(ah[i],  bh2[j], acc[i][j], 0, 0, 0);
            acc[i][j] = __builtin_amdgcn_mfma_f32_16x16x32_bf16(ah[i],  bl2[j], acc[i][j], 0, 0, 0);
            acc[i][j] = __builtin_amdgcn_mfma_f32_16x16x32_bf16(al2[i], bh2[j], acc[i][j], 0, 0, 0);
          }
        }
      }
      __syncthreads();
    }

    // epilogue: write XHt[c][h*192+row] = xh1[row][col], bf16 hi/lo
#pragma unroll
    for (int i = 0; i < 2; ++i){
#pragma unroll
      for (int j = 0; j < 2; ++j){
        int col = bn*64 + wn*32 + j*16 + rl;
        int h = col / 384, c = col - h*384;
        size_t cb = (size_t)c*K1 + h*192;
#pragma unroll
        for (int r = 0; r < 4; ++r){
          int row = bm*64 + wm*32 + i*16 + kq*4 + r;
          if (row < 178){
            float v = acc[i][j][r];
            unsigned short hi = f2bf(v);
            XHh[cb + row] = hi;
            XHl[cb + row] = f2bf(v - bf2f(hi));
          }
        }
      }
    }
  } else if (blk < 250){
    // xa dots: xa_s1[r,h] = x_emb[r] . wa_s1[h], dual
    int r = blk - 72;
    int h = threadIdx.x >> 6, lane = threadIdx.x & 63;
    const float4* xe = (const float4*)(x_emb + (size_t)r*768);
    const float4* ws = (const float4*)(wa_s1 + h*768);
    const float4* wd = (const float4*)(wa_d1 + h*768);
    float s1 = 0.f, s2 = 0.f;
#pragma unroll
    for (int i = 0; i < 3; ++i){
      float4 u = xe[i*64+lane];
      s1 += dot4(u, ws[i*64+lane]);
      s2 += dot4(u, wd[i*64+lane]);
    }
    s1 = wsum(s1); s2 = wsum(s2);
    if (lane == 0){ xa_s1[r*4+h] = s1; xa_d1[r*4+h] = s2; }
  } else {
    // ew dots
    int id = (blk - 250)*4 + (threadIdx.x >> 6);   // 0..143
    int lane = threadIdx.x & 63;
    const float* wv = (id < 72) ? we_a1 : we_a2;
    float* o = (id < 72) ? ew1 : ew2;
    int id2 = (id < 72) ? id : (id - 72);
    int r = id2 >> 2, h = id2 & 3;
    const float* ar = e_emb + (size_t)r*EMBD;
    float acc = 0.f;
    for (int k = lane; k < EMBD; k += 64) acc += ar[k] * wv[k*4+h];
    acc = wsum(acc);
    if (lane == 0) o[r*4+h] = acc;
  }
}

// ---- layer-1 softmax + token-coefficient build -> Q bf16 hi/lo -------------
__global__ __launch_bounds__(256) void k_gat1sm(const int* __restrict__ offsets,
                      int* __restrict__ csr, const int* __restrict__ srcv,
                      const int* __restrict__ x, const int* __restrict__ ea,
                      const float* __restrict__ xa_s1, const float* __restrict__ xa_d1,
                      const float* __restrict__ ew1, float* __restrict__ spill,
                      unsigned short* __restrict__ Qh, unsigned short* __restrict__ Ql){
  __shared__ float wts[DCAP][5];
  __shared__ int   sE[DCAP];
  __shared__ int   sA[DCAP], sB[DCAP];
  __shared__ float coef[K1];
  int n = blockIdx.x, t = threadIdx.x;
  int w = t >> 6, lane = t & 63;
  int lo = offsets[n], hi = offsets[n+1];
  int deg = hi - lo;
  bool big = deg > DCAP;

  if (!big){
    if (deg <= 64){
      if (w == 0){
        int v = (lane < deg) ? csr[lo+lane] : 0x7fffffff;
#pragma unroll
        for (int k = 2; k <= 64; k <<= 1){
#pragma unroll
          for (int j2 = k >> 1; j2 > 0; j2 >>= 1){
            int o = __shfl_xor(v, j2, 64);
            bool lower = (lane & j2) == 0;
            bool asc   = (lane & k) == 0;
            v = (lower == asc) ? min(v, o) : max(v, o);
          }
        }
        sE[lane] = v;
        if (lane < deg) csr[lo+lane] = v;
      }
    } else {
      int m = 1; while (m < deg) m <<= 1;
      for (int i = t; i < m; i += 256) sE[i] = (i < deg) ? csr[lo+i] : 0x7fffffff;
      __syncthreads();
      for (int k = 2; k <= m; k <<= 1){
        for (int j2 = k >> 1; j2 > 0; j2 >>= 1){
          for (int i = t; i < m; i += 256){
            int ixj = i ^ j2;
            if (ixj > i){
              int a = sE[i], b = sE[ixj];
              bool up = ((i & k) == 0);
              if ((a > b) == up){ sE[i] = b; sE[ixj] = a; }
            }
          }
          __syncthreads();
        }
      }
      for (int i = t; i < deg; i += 256) csr[lo+i] = sE[i];
    }
  } else {
    if (t == 0){
      for (int i = lo+1; i < hi; ++i){
        int v = csr[i], j = i-1;
        while (j >= lo && csr[j] > v){ csr[j+1] = csr[j]; --j; }
        csr[j+1] = v;
      }
    }
  }
  for (int i = t; i < K1; i += 256) coef[i] = 0.f;
  __syncthreads();

  int xn0 = x[2*n], xn1 = x[2*n+1];
  float ad_n = xa_d1[xn0*4+w] + xa_d1[xn1*4+w];
  float as_n = xa_s1[xn0*4+w] + xa_s1[xn1*4+w];
  float mx = -3.4e38f, sae = 0.f;
  float wlv;
  if (!big){
    for (int j = lane; j < deg; j += 64){
      int e = sE[j]; int s = srcv[e];
      int a = x[2*s], b = x[2*s+1];
      if (w == 0){ sA[j] = a; sB[j] = b; }
      float ae = ew1[ea[2*e]*4+w] + ew1[ea[2*e+1]*4+w];
      float al = (xa_s1[a*4+w] + xa_s1[b*4+w]) + ad_n + ae;
      al = (al > 0.f) ? al : NEG * al;
      wts[j][w] = al;
      sae += ae; mx = fmaxf(mx, al);
    }
    mx = wmax(mx); sae = wsum(sae);
    float all_ = as_n + ad_n + sae / fmaxf((float)deg, 1.f);
    all_ = (all_ > 0.f) ? all_ : NEG * all_;
    mx = fmaxf(mx, all_);
    float den = 0.f;
    for (int j = lane; j < deg; j += 64){
      float xx = expf(wts[j][w] - mx);
      wts[j][w] = xx; den += xx;
    }
    den = wsum(den);
    float exl = expf(all_ - mx);
    den += exl;
    float inv = 1.f / den;
    for (int j = lane; j < deg; j += 64) wts[j][w] *= inv;
    wlv = exl * inv;
  } else {
    for (int p = lo + lane; p < hi; p += 64){
      int e = csr[p]; int s = srcv[e];
      int a = x[2*s], b = x[2*s+1];
      float ae = ew1[ea[2*e]*4+w] + ew1[ea[2*e+1]*4+w];
      float al = (xa_s1[a*4+w] + xa_s1[b*4+w]) + ad_n + ae;
      al = (al > 0.f) ? al : NEG * al;
      spill[e*4 + w] = al;
      sae += ae; mx = fmaxf(mx, al);
    }
    mx = wmax(mx); sae = wsum(sae);
    float all_ = as_n + ad_n + sae / fmaxf((float)deg, 1.f);
    all_ = (all_ > 0.f) ? all_ : NEG * all_;
    mx = fmaxf(mx, all_);
    float den = 0.f;
    for (int p = lo + lane; p < hi; p += 64){
      int e = csr[p];
      float xx = expf(spill[e*4 + w] - mx);
      spill[e*4 + w] = xx; den += xx;
    }
    den = wsum(den);
    float exl = expf(all_ - mx);
    den += exl;
    float inv = 1.f / den;
    for (int p = lo + lane; p < hi; p += 64) spill[csr[p]*4 + w] *= inv;
    wlv = exl * inv;
  }
  __syncthreads();

  if (lane == 0){
    float* cf = coef + w*192;
    if (!big){
      for (int j = 0; j < deg; ++j){
        float wj = wts[j][w];
        cf[sA[j]] += wj; cf[sB[j]] += wj;
      }
    } else {
      for (int p = lo; p < hi; ++p){
        int e = csr[p]; int s = srcv[e];
        float wj = spill[e*4 + w];
        cf[x[2*s]] += wj; cf[x[2*s+1]] += wj;
      }
    }
    cf[xn0] += wlv; cf[xn1] += wlv;
  }
  __syncthreads();

  for (int i = t; i < K1; i += 256){
    float v = coef[i];
    unsigned short hi16 = f2bf(v);
    Qh[(size_t)n*K1 + i] = hi16;
    Ql[(size_t)n*K1 + i] = f2bf(v - bf2f(hi16));
  }
}

// ---- mm1: hact = relu(0.25*(Q @ XHt^T) + b1), bf16 3-product MFMA ----------
__global__ __launch_bounds__(256) void k_mm1(const unsigned short* __restrict__ Qh,
                                             const unsigned short* __restrict__ Ql,
                                             const unsigned short* __restrict__ XHh,
                                             const unsigned short* __restrict__ XHl,
                                             const float* __restrict__ b1,
                                             float* __restrict__ hact){
  __shared__ __align__(16) unsigned short lds[2][4][64][64];
  int b = blockIdx.x;
  int xcd = b & 7, idx = b >> 3;            // idx in [0,24)
  int bm = xcd*4 + idx/6, bn = idx % 6;
  int wave = threadIdx.x >> 6, lane = threadIdx.x & 63;
  int wm = wave >> 1, wn = wave & 1;
  int rl = lane & 15, kq = lane >> 4;

  int rt   = lane >> 3;
  int kswz = ((lane & 7) ^ rt) * 8;
  const unsigned short* sbase;
  int rowbase;
  if (wave == 0){ sbase = Qh; rowbase = bm*64; }
  else if (wave == 1){ sbase = Ql; rowbase = bm*64; }
  else if (wave == 2){ sbase = XHh; rowbase = bn*64; }
  else { sbase = XHl; rowbase = bn*64; }
  bool isA = wave < 2;

  f32x4 acc[2][2] = {};

#pragma unroll
  for (int i = 0; i < 8; ++i){
    int row = rowbase + i*8 + rt;
    if (isA) row = (row < GM) ? row : (GM-1);
    gload16(sbase + (size_t)row*K1 + kswz, &lds[0][wave][i*8][0]);
  }
  __syncthreads();

  for (int t = 0; t < 12; ++t){
    int cur = t & 1;
    if (t < 11){
      int k0 = (t+1)*64;
#pragma unroll
      for (int i = 0; i < 8; ++i){
        int row = rowbase + i*8 + rt;
        if (isA) row = (row < GM) ? row : (GM-1);
        gload16(sbase + (size_t)row*K1 + k0 + kswz, &lds[cur^1][wave][i*8][0]);
      }
    }
#pragma unroll
    for (int ks = 0; ks < 2; ++ks){
      bf16x8 ah[2], al2[2], bh2[2], bl2[2];
#pragma unroll
      for (int i = 0; i < 2; ++i){
        int r = wm*32 + i*16 + rl;
        int sl = (ks*4 + kq) ^ (r & 7);
        ah[i]  = *(const bf16x8*)&lds[cur][0][r][sl*8];
        al2[i] = *(const bf16x8*)&lds[cur][1][r][sl*8];
      }
#pragma unroll
      for (int j = 0; j < 2; ++j){
        int cdx = wn*32 + j*16 + rl;
        int sl = (ks*4 + kq) ^ (cdx & 7);
        bh2[j] = *(const bf16x8*)&lds[cur][2][cdx][sl*8];
        bl2[j] = *(const bf16x8*)&lds[cur][3][cdx][sl*8];
      }
#pragma unroll
      for (int i = 0; i < 2; ++i){
#pragma unroll
        for (int j = 0; j < 2; ++j){
          acc[i][j] = __builtin_amdgcn_mfma_f32_16x16x32_bf16(ah[i],  bh2[j], acc[i][j], 0, 0, 0);
          acc[i][j] = __builtin_amdgcn_mfma_f32_16x16x32_bf16(ah[i],  bl2[j], acc[i][j], 0, 0, 0);
          acc[i][j] = __builtin_amdgcn_mfma_f32_16x16x32_bf16(al2[i], bh2[j], acc[i][j], 0, 0, 0);
        }
      }
    }
    __syncthreads();
  }

#pragma unroll
  for (int i = 0; i < 2; ++i){
#pragma unroll
    for (int j = 0; j < 2; ++j){
      int col = bn*64 + wn*32 + j*16 + rl;
      float bb = b1[col];
#pragma unroll
      for (int r = 0; r < 4; ++r){
        int row = bm*64 + wm*32 + i*16 + kq*4 + r;
        if (row < GM) hact[(size_t)row*HID + col] = fmaxf(0.25f*acc[i][j][r] + bb, 0.f);
      }
    }
  }
}

// ---- k_dots: asrc2/adst2 = hact row-dots with wa_s2/wa_d2 ------------------
__global__ __launch_bounds__(256) void k_dots(const float* __restrict__ hact,
                      const float* __restrict__ wa_s2, const float* __restrict__ wa_d2,
                      float* __restrict__ asrc2, float* __restrict__ adst2){
  int w = threadIdx.x >> 6, lane = threadIdx.x & 63;
  int n = blockIdx.x*4 + w;
  float pr[8] = {};
#pragma unroll
  for (int i = 0; i < 6; ++i){
    int c = i*64 + lane;
    float v = hact[(size_t)n*HID + c];
#pragma unroll
    for (int h = 0; h < 4; ++h){
      pr[h]   += v * wa_s2[c*4+h];
      pr[4+h] += v * wa_d2[c*4+h];
    }
  }
#pragma unroll
  for (int o = 32; o > 0; o >>= 1){
#pragma unroll
    for (int q = 0; q < 8; ++q) pr[q] += __shfl_xor(pr[q], o, 64);
  }
  if (lane == 0){
#pragma unroll
    for (int h = 0; h < 4; ++h){ asrc2[n*4+h] = pr[h]; adst2[n*4+h] = pr[4+h]; }
  }
}

// ---- layer-2 fused: on-the-fly alphas + softmax + pipelined agg -> G -------
__global__ __launch_bounds__(384) void k_gat2(const int* __restrict__ offsets,
                      const int* __restrict__ csr, const int* __restrict__ srcv,
                      const int* __restrict__ ea,
                      const float* __restrict__ asrc, const float* __restrict__ adst,
                      const float* __restrict__ ew2,
                      const float* __restrict__ hact, float* __restrict__ spill,
                      unsigned short* __restrict__ Gh, unsigned short* __restrict__ Gl){
  __shared__ float wts[DCAP][5];
  __shared__ int   ssrc[DCAP];
  __shared__ float wl[4];
  int n = blockIdx.x, t = threadIdx.x;
  int w = t >> 6, lane = t & 63;
  int lo = offsets[n], hi = offsets[n+1];
  int deg = hi - lo;
  bool big = deg > DCAP;
  if (w < 4){
    float ad_n = adst[n*NH + w];
    float as_n = asrc[n*NH + w];
    float mx = -3.4e38f, sae = 0.f;
    if (!big){
      for (int p = lo + lane; p < hi; p += 64){
        int e = csr[p]; int s = srcv[e];
        if (w == 0) ssrc[p - lo] = s;
        float ae = ew2[ea[2*e]*4+w] + ew2[ea[2*e+1]*4+w];
        float al = asrc[s*NH + w] + ad_n + ae;
        al = (al > 0.f) ? al : NEG * al;
        wts[p - lo][w] = al;
        sae += ae; mx = fmaxf(mx, al);
      }
      mx = wmax(mx); sae = wsum(sae);
      float all_ = as_n + ad_n + sae / fmaxf((float)deg, 1.f);
      all_ = (all_ > 0.f) ? all_ : NEG * all_;
      mx = fmaxf(mx, all_);
      float den = 0.f;
      for (int p = lo + lane; p < hi; p += 64){
        float xx = expf(wts[p - lo][w] - mx);
        wts[p - lo][w] = xx; den += xx;
      }
      den = wsum(den);
      float exl = expf(all_ - mx);
      den += exl;
      float inv = 1.f / den;
      for (int p = lo + lane; p < hi; p += 64) wts[p - lo][w] *= inv;
      if (lane == 0) wl[w] = exl * inv;
    } else {
      for (int p = lo + lane; p < hi; p += 64){
        int e = csr[p];
        float ae = ew2[ea[2*e]*4+w] + ew2[ea[2*e+1]*4+w];
        float al = asrc[srcv[e]*NH + w] + ad_n + ae;
        al = (al > 0.f) ? al : NEG * al;
        spill[e*4 + w] = al;
        sae += ae; mx = fmaxf(mx, al);
      }
      mx = wmax(mx); sae = wsum(sae);
      float all_ = as_n + ad_n + sae / fmaxf((float)deg, 1.f);
      all_ = (all_ > 0.f) ? all_ : NEG * all_;
      mx = fmaxf(mx, all_);
      float den = 0.f;
      for (int p = lo + lane; p < hi; p += 64){
        int e = csr[p];
        float xx = expf(spill[e*4 + w] - mx);
        spill[e*4 + w] = xx; den += xx;
      }
      den = wsum(den);
      float exl = expf(all_ - mx);
      den += exl;
      float inv = 1.f / den;
      for (int p = lo + lane; p < hi; p += 64) spill[csr[p]*4 + w] *= inv;
      if (lane == 0) wl[w] = exl * inv;
    }
  }
  __syncthreads();

  int c = t;
  float a0 = 0.f, a1 = 0.f, a2 = 0.f, a3 = 0.f;
  if (!big){
    float vnext = 0.f;
    if (deg > 0) vnext = hact[(size_t)ssrc[0]*HID + c];
    for (int j = 0; j < deg; ++j){
      float vc = vnext;
      if (j+1 < deg) vnext = hact[(size_t)ssrc[j+1]*HID + c];
      float w0=wts[j][0], w1=wts[j][1], w2=wts[j][2], w3=wts[j][3];
      a0 += w0*vc; a1 += w1*vc; a2 += w2*vc; a3 += w3*vc;
    }
  } else {
    for (int j = 0; j < deg; ++j){
      int e = csr[lo+j]; int s = srcv[e];
      float w0 = spill[e*4+0], w1 = spill[e*4+1], w2 = spill[e*4+2], w3 = spill[e*4+3];
      float vc = hact[(size_t)s*HID + c];
      a0 += w0*vc; a1 += w1*vc; a2 += w2*vc; a3 += w3*vc;
    }
  }
  {
    float vc = hact[(size_t)n*HID + c];
    a0 += wl[0]*vc; a1 += wl[1]*vc; a2 += wl[2]*vc; a3 += wl[3]*vc;
  }
  size_t base = (size_t)n*GK + c;
  float vv[4] = {a0, a1, a2, a3};
#pragma unroll
  for (int h = 0; h < 4; ++h){
    unsigned short hi16 = f2bf(vv[h]);
    unsigned short lo16 = f2bf(vv[h] - bf2f(hi16));
    Gh[base + h*384] = hi16;
    Gl[base + h*384] = lo16;
  }
}

// ---- layer-2 MFMA GEMM: LDS-staged, double-buffered, XOR-swizzled ----------
__global__ __launch_bounds__(256) void k_mm2(const unsigned short* __restrict__ Gh,
                                             const unsigned short* __restrict__ Gl,
                                             const unsigned short* __restrict__ Bh,
                                             const unsigned short* __restrict__ Bl,
                                             const float* __restrict__ b2,
                                             float* __restrict__ out){
  __shared__ __align__(16) unsigned short lds[2][4][64][64];
  int b = blockIdx.x;
  int xcd = b & 7, idx = b >> 3;
  int bm = xcd*4 + idx/12, bn = idx % 12;
  int wave = threadIdx.x >> 6, lane = threadIdx.x & 63;
  int wm = wave >> 1, wn = wave & 1;
  int rl = lane & 15, kq = lane >> 4;

  int rt   = lane >> 3;
  int kswz = ((lane & 7) ^ rt) * 8;
  const unsigned short* sbase;
  int rowbase;
  if (wave == 0){ sbase = Gh; rowbase = bm*64; }
  else if (wave == 1){ sbase = Gl; rowbase = bm*64; }
  else if (wave == 2){ sbase = Bh; rowbase = bn*64; }
  else { sbase = Bl; rowbase = bn*64; }
  bool isA = wave < 2;

  f32x4 acc[2][2] = {};

#pragma unroll
  for (int i = 0; i < 8; ++i){
    int row = rowbase + i*8 + rt;
    if (isA) row = (row < GM) ? row : (GM-1);
    gload16(sbase + (size_t)row*GK + kswz, &lds[0][wave][i*8][0]);
  }
  __syncthreads();

  for (int t = 0; t < 24; ++t){
    int cur = t & 1;
    if (t < 23){
      int k0 = (t+1)*64;
#pragma unroll
      for (int i = 0; i < 8; ++i){
        int row = rowbase + i*8 + rt;
        if (isA) row = (row < GM) ? row : (GM-1);
        gload16(sbase + (size_t)row*GK + k0 + kswz, &lds[cur^1][wave][i*8][0]);
      }
    }
#pragma unroll
    for (int ks = 0; ks < 2; ++ks){
      bf16x8 ah[2], al2[2], bh2[2], bl2[2];
#pragma unroll
      for (int i = 0; i < 2; ++i){
        int r = wm*32 + i*16 + rl;
        int sl = (ks*4 + kq) ^ (r & 7);
        ah[i]  = *(const bf16x8*)&lds[cur][0][r][sl*8];
        al2[i] = *(const bf16x8*)&lds[cur][1][r][sl*8];
      }
#pragma unroll
      for (int j = 0; j < 2; ++j){
        int cdx = wn*32 + j*16 + rl;
        int sl = (ks*4 + kq) ^ (cdx & 7);
        bh2[j] = *(const bf16x8*)&lds[cur][2][cdx][sl*8];
        bl2[j] = *(const bf16x8*)&lds[cur][3][cdx][sl*8];
      }
#pragma unroll
      for (int i = 0; i < 2; ++i){
#pragma unroll
        for (int j = 0; j < 2; ++j){
          acc[i][j] = __builtin_amdgcn_mfma_f32_16x16x32_bf16(ah[i],  bh2[j], acc[i][j], 0, 0, 0);
          acc[i][j] = __builtin_amdgcn_mfma_f32_16x16x32_bf16(ah[i],  bl2[j], acc[i][j], 0, 0, 0);
          acc[i][j] = __builtin_amdgcn_mfma_f32_16x16x32_bf16(al2[i], bh2[j], acc[i][j], 0, 0, 0);
        }
      }
    }
    __syncthreads();
  }

#pragma unroll
  for (int i = 0; i < 2; ++i){
#pragma unroll
    for (int j = 0; j < 2; ++j){
      int col = bn*64 + wn*32 + j*16 + rl;
      float bb = b2[col];
#pragma unroll
      for (int r = 0; r < 4; ++r){
        int row = bm*64 + wm*32 + i*16 + kq*4 + r;
        if (row < GM) out[(size_t)row*GN + col] = 0.25f*acc[i][j][r] + bb;
      }
    }
  }
}

// ---------------------------------------------------------------------------
extern "C" void kernel_launch(void* const* d_in, const int* in_sizes, int n_in,
                              void* d_out, int out_size, void* d_ws, size_t ws_size,
                              hipStream_t stream){
  const int*   x     = (const int*)d_in[0];
  const int*   ei    = (const int*)d_in[1];
  const int*   ea    = (const int*)d_in[2];
  const float* x_emb = (const float*)d_in[3];
  const float* e_emb = (const float*)d_in[4];
  const float* W1    = (const float*)d_in[5];
  const float* as1   = (const float*)d_in[6];
  const float* ad1   = (const float*)d_in[7];
  const float* We1   = (const float*)d_in[8];
  const float* ae1   = (const float*)d_in[9];
  const float* b1    = (const float*)d_in[10];
  const float* W2    = (const float*)d_in[11];
  const float* as2   = (const float*)d_in[12];
  const float* ad2   = (const float*)d_in[13];
  const float* We2   = (const float*)d_in[14];
  const float* ae2   = (const float*)d_in[15];
  const float* b2    = (const float*)d_in[16];
  const int* srcv = ei;
  const int* dstv = ei + NE;
  float* out = (float*)d_out;

  char* p = (char*)d_ws;
  auto take = [&](size_t n){ void* q = (void*)p; p += (n + 255) & ~(size_t)255; return q; };
  int*   cursor  = (int*)take(NN*4);
  int*   offsets = (int*)take((NN+1)*4);
  int*   csr     = (int*)take(NE*4);
  float* we_a1   = (float*)take(EMBD*NH*4);
  float* wa_s2   = (float*)take(HID*NH*4);
  float* wa_d2   = (float*)take(HID*NH*4);
  float* we_a2   = (float*)take(EMBD*NH*4);
  float* wa_s1   = (float*)take(NH*EMBD*4);
  float* wa_d1   = (float*)take(NH*EMBD*4);
  float* xa_s1   = (float*)take(178*NH*4);
  float* xa_d1   = (float*)take(178*NH*4);
  float* ew1     = (float*)take(18*NH*4);
  float* ew2     = (float*)take(18*NH*4);
  unsigned short* Xeh  = (unsigned short*)take((size_t)178*768*2);
  unsigned short* Xel  = (unsigned short*)take((size_t)178*768*2);
  unsigned short* W1th = (unsigned short*)take((size_t)1536*768*2);
  unsigned short* W1tl = (unsigned short*)take((size_t)1536*768*2);
  unsigned short* XHh  = (unsigned short*)take((size_t)HID*K1*2);
  unsigned short* XHl  = (unsigned short*)take((size_t)HID*K1*2);
  unsigned short* Qh   = (unsigned short*)take((size_t)NN*K1*2);
  unsigned short* Ql   = (unsigned short*)take((size_t)NN*K1*2);
  unsigned short* Bth  = (unsigned short*)take((size_t)GN*GK*2);
  unsigned short* Btl  = (unsigned short*)take((size_t)GN*GK*2);
  unsigned short* Gh   = (unsigned short*)take((size_t)GM*GK*2);
  unsigned short* Gl   = (unsigned short*)take((size_t)GM*GK*2);
  float* spill   = (float*)take((size_t)NE*NH*4);
  float* hact    = (float*)take((size_t)NN*HID*4);
  float* asrc2   = (float*)take(NN*NH*4);
  float* adst2   = (float*)take(NN*NH*4);

  // CSR count/scan (1 block, 1024 thr)
  k_cnt<<<1, 1024, 0, stream>>>(dstv, offsets, cursor);

  // prep (fused uniform roles incl. W1 dual collapse, XH pad, CSR fill)
  k_prepA<<<1399, 256, 0, stream>>>(We1, ae1, W2, as2, ad2, We2, ae2, W1,
                                    as1, ad1, x_emb, dstv,
                                    we_a1, wa_s2, wa_d2, we_a2, wa_s1, wa_d1,
                                    Bth, Btl, W1th, W1tl, Xeh, Xel,
                                    XHh, XHl, cursor, csr);

  // XHt via MFMA (direct transposed+split write) + xa dots + ew dots
  k_mmX<<<286, 256, 0, stream>>>(Xeh, Xel, W1th, W1tl, x_emb, e_emb,
                                 wa_s1, wa_d1, we_a1, we_a2,
                                 XHh, XHl, xa_s1, xa_d1, ew1, ew2);

  // layer 1: softmax + token-coefficient build -> Q; hact via MFMA; dots
  k_gat1sm<<<NN, 256, 0, stream>>>(offsets, csr, srcv, x, ea, xa_s1, xa_d1,
                                   ew1, spill, Qh, Ql);
  k_mm1<<<192, 256, 0, stream>>>(Qh, Ql, XHh, XHl, b1, hact);
  k_dots<<<500, 256, 0, stream>>>(hact, wa_s2, wa_d2, asrc2, adst2);

  // layer 2 fused agg-first -> G (bf16 hi/lo)
  k_gat2<<<NN, 384, 0, stream>>>(offsets, csr, srcv, ea, asrc2, adst2, ew2,
                                 hact, spill, Gh, Gl);

  // out = 0.25*(G @ Bt^T) + b2 via LDS-staged bf16 3-product MFMA
  k_mm2<<<384, 256, 0, stream>>>(Gh, Gl, Bth, Btl, b2, out);
}